// Round 1
// baseline (3080.678 us; speedup 1.0000x reference)
//
#include <hip/hip_runtime.h>
#include <math.h>

#define B_   2
#define TQ_  512
#define TK_  8192
#define D_   1024
#define NH_  16
#define HD_  64

// ---------------- GEMM config: C[M,N] = A[M,K] @ W[N,K]^T (+bias) ----------------
#define BM   64
#define BN   64
#define BKT  32
#define LDP  68   // padded LDS row stride (floats): 272B keeps float4 alignment, ~2-way banks

#define NEG_BIG (-3.0e38f)

__device__ __forceinline__ float wave_max64(float v) {
#pragma unroll
    for (int m = 32; m >= 1; m >>= 1) v = fmaxf(v, __shfl_xor(v, m, 64));
    return v;
}
__device__ __forceinline__ float wave_sum64(float v) {
#pragma unroll
    for (int m = 32; m >= 1; m >>= 1) v += __shfl_xor(v, m, 64);
    return v;
}

// ---------------- Q projection: C = (A @ Wq^T + bq) * 1/(64*temp) ----------------
__global__ __launch_bounds__(256)
void sdpca_gemm_q(const float* __restrict__ A, const float* __restrict__ W,
                  const float* __restrict__ bias, const float* __restrict__ log_temp,
                  float* __restrict__ C)
{
    __shared__ float As[BKT][LDP];
    __shared__ float Ws[BKT][LDP];
    const int tid  = threadIdx.x;
    const int brow = blockIdx.y * BM;
    const int bcol = blockIdx.x * BN;
    const int tr   = (tid >> 4) << 2;   // 0..60, output rows tr..tr+3
    const int tc   = (tid & 15) << 2;   // 0..60, output cols tc..tc+3

    float acc[4][4] = {};
    for (int k0 = 0; k0 < D_; k0 += BKT) {
#pragma unroll
        for (int i = 0; i < 2; ++i) {
            int idx = (i << 8) + tid;         // 0..511
            int r   = idx >> 3;               // 0..63
            int c   = (idx & 7) << 2;         // 0..28
            float4 av = *(const float4*)(A + (size_t)(brow + r) * D_ + (k0 + c));
            As[c + 0][r] = av.x; As[c + 1][r] = av.y; As[c + 2][r] = av.z; As[c + 3][r] = av.w;
            float4 wv = *(const float4*)(W + (size_t)(bcol + r) * D_ + (k0 + c));
            Ws[c + 0][r] = wv.x; Ws[c + 1][r] = wv.y; Ws[c + 2][r] = wv.z; Ws[c + 3][r] = wv.w;
        }
        __syncthreads();
#pragma unroll
        for (int kk = 0; kk < BKT; ++kk) {
            float4 a = *(const float4*)&As[kk][tr];
            float4 w = *(const float4*)&Ws[kk][tc];
            float aa[4] = {a.x, a.y, a.z, a.w};
            float ww[4] = {w.x, w.y, w.z, w.w};
#pragma unroll
            for (int i2 = 0; i2 < 4; ++i2)
#pragma unroll
                for (int j2 = 0; j2 < 4; ++j2)
                    acc[i2][j2] = fmaf(aa[i2], ww[j2], acc[i2][j2]);
        }
        __syncthreads();
    }

    float lt    = *log_temp;
    float temp  = fminf(fmaxf(expf(lt), 0.1f), 10.0f);
    float scale = 1.0f / (64.0f * temp);

#pragma unroll
    for (int i = 0; i < 4; ++i) {
        int r = brow + tr + i;
        float4 bv = *(const float4*)(bias + bcol + tc);
        float4 o;
        o.x = (acc[i][0] + bv.x) * scale;
        o.y = (acc[i][1] + bv.y) * scale;
        o.z = (acc[i][2] + bv.z) * scale;
        o.w = (acc[i][3] + bv.w) * scale;
        *(float4*)(C + (size_t)r * D_ + bcol + tc) = o;
    }
}

// ------------- K/V projection with per-group input bias, dual output -------------
__global__ __launch_bounds__(256)
void sdpca_gemm_kv(const float* __restrict__ A,
                   const float* __restrict__ Wk, const float* __restrict__ bk,
                   const float* __restrict__ Wv, const float* __restrict__ bv,
                   const float* __restrict__ abias, const float* __restrict__ ibias,
                   const int* __restrict__ nactp,
                   float* __restrict__ K, float* __restrict__ V)
{
    __shared__ float As [BKT][LDP];
    __shared__ float Wks[BKT][LDP];
    __shared__ float Wvs[BKT][LDP];
    const int tid  = threadIdx.x;
    const int brow = blockIdx.y * BM;
    const int bcol = blockIdx.x * BN;
    const int tr   = (tid >> 4) << 2;
    const int tc   = (tid & 15) << 2;
    const int Na   = *nactp;

    float acck[4][4] = {};
    float accv[4][4] = {};
    for (int k0 = 0; k0 < D_; k0 += BKT) {
#pragma unroll
        for (int i = 0; i < 2; ++i) {
            int idx = (i << 8) + tid;
            int r   = idx >> 3;
            int c   = (idx & 7) << 2;
            int gr  = brow + r;
            int t   = gr & (TK_ - 1);
            const float* bp = (t < Na) ? abias : ibias;
            float4 av = *(const float4*)(A + (size_t)gr * D_ + (k0 + c));
            float4 bb = *(const float4*)(bp + (k0 + c));
            As[c + 0][r] = av.x + bb.x; As[c + 1][r] = av.y + bb.y;
            As[c + 2][r] = av.z + bb.z; As[c + 3][r] = av.w + bb.w;
            float4 wk = *(const float4*)(Wk + (size_t)(bcol + r) * D_ + (k0 + c));
            Wks[c + 0][r] = wk.x; Wks[c + 1][r] = wk.y; Wks[c + 2][r] = wk.z; Wks[c + 3][r] = wk.w;
            float4 wv = *(const float4*)(Wv + (size_t)(bcol + r) * D_ + (k0 + c));
            Wvs[c + 0][r] = wv.x; Wvs[c + 1][r] = wv.y; Wvs[c + 2][r] = wv.z; Wvs[c + 3][r] = wv.w;
        }
        __syncthreads();
#pragma unroll
        for (int kk = 0; kk < BKT; ++kk) {
            float4 a  = *(const float4*)&As [kk][tr];
            float4 wk = *(const float4*)&Wks[kk][tc];
            float4 wv = *(const float4*)&Wvs[kk][tc];
            float aa[4] = {a.x, a.y, a.z, a.w};
            float kk4[4] = {wk.x, wk.y, wk.z, wk.w};
            float vv4[4] = {wv.x, wv.y, wv.z, wv.w};
#pragma unroll
            for (int i2 = 0; i2 < 4; ++i2)
#pragma unroll
                for (int j2 = 0; j2 < 4; ++j2) {
                    acck[i2][j2] = fmaf(aa[i2], kk4[j2], acck[i2][j2]);
                    accv[i2][j2] = fmaf(aa[i2], vv4[j2], accv[i2][j2]);
                }
        }
        __syncthreads();
    }

#pragma unroll
    for (int i = 0; i < 4; ++i) {
        int r = brow + tr + i;
        float4 bkv = *(const float4*)(bk + bcol + tc);
        float4 bvv = *(const float4*)(bv + bcol + tc);
        float4 ok, ov;
        ok.x = acck[i][0] + bkv.x; ok.y = acck[i][1] + bkv.y;
        ok.z = acck[i][2] + bkv.z; ok.w = acck[i][3] + bkv.w;
        ov.x = accv[i][0] + bvv.x; ov.y = accv[i][1] + bvv.y;
        ov.z = accv[i][2] + bvv.z; ov.w = accv[i][3] + bvv.w;
        *(float4*)(K + (size_t)r * D_ + bcol + tc) = ok;
        *(float4*)(V + (size_t)r * D_ + bcol + tc) = ov;
    }
}

// ---------------- two-group flash attention ----------------
// grid: (TQ/16, B*NH). block: 256 = 4 waves; wave w owns q-rows w*4..w*4+3,
// lane = key index in score phase, lane = head-dim in PV/output phase.
#define QT 16
#define KT 64

__global__ __launch_bounds__(256)
void sdpca_attn(const float* __restrict__ Q,  // (B*TQ, D), pre-scaled
                const float* __restrict__ K,  // (B*TK, D)
                const float* __restrict__ V,  // (B*TK, D)
                const int* __restrict__ nactp,
                float* __restrict__ O)        // (B*TQ, D)
{
    __shared__ float Kb[KT][HD_ + 1];
    __shared__ float Vb[KT][HD_ + 1];
    __shared__ float Qs[QT][HD_ + 1];
    __shared__ float Pl[4][4][KT];

    const int tid  = threadIdx.x;
    const int lane = tid & 63;
    const int w    = tid >> 6;          // 0..3
    const int bh   = blockIdx.y;
    const int b    = bh / NH_;
    const int h    = bh - b * NH_;
    const int q0   = blockIdx.x * QT;
    const int Na   = *nactp;
    const int Ni   = TK_ - Na;

    {   // stage the Q tile (16 x 64)
        int r = tid >> 4;
        int c = (tid & 15) << 2;
        float4 qv = *(const float4*)(Q + (size_t)(b * TQ_ + q0 + r) * D_ + h * HD_ + c);
        Qs[r][c + 0] = qv.x; Qs[r][c + 1] = qv.y; Qs[r][c + 2] = qv.z; Qs[r][c + 3] = qv.w;
    }

    float mA[4], lA[4], oA[4], mI[4], lI[4], oI[4];
#pragma unroll
    for (int i = 0; i < 4; ++i) {
        mA[i] = NEG_BIG; lA[i] = 0.f; oA[i] = 0.f;
        mI[i] = NEG_BIG; lI[i] = 0.f; oI[i] = 0.f;
    }

    for (int j0 = 0; j0 < TK_; j0 += KT) {
        __syncthreads();   // protect Kb/Vb/Pl from previous iteration readers (also covers Qs once)
#pragma unroll
        for (int i = 0; i < 4; ++i) {
            int idx = (i << 8) + tid;       // 0..1023
            int r   = idx >> 4;             // 0..63
            int c   = (idx & 15) << 2;      // 0..60
            const float* ks = K + (size_t)(b * TK_ + j0 + r) * D_ + h * HD_ + c;
            float4 k4 = *(const float4*)ks;
            Kb[r][c + 0] = k4.x; Kb[r][c + 1] = k4.y; Kb[r][c + 2] = k4.z; Kb[r][c + 3] = k4.w;
            const float* vs = V + (size_t)(b * TK_ + j0 + r) * D_ + h * HD_ + c;
            float4 v4 = *(const float4*)vs;
            Vb[r][c + 0] = v4.x; Vb[r][c + 1] = v4.y; Vb[r][c + 2] = v4.z; Vb[r][c + 3] = v4.w;
        }
        __syncthreads();

        // scores: s[i] = Q[q0+w*4+i] . K[j0+lane]
        float s[4] = {0.f, 0.f, 0.f, 0.f};
        for (int d = 0; d < HD_; ++d) {
            float kd = Kb[lane][d];
#pragma unroll
            for (int i = 0; i < 4; ++i) s[i] = fmaf(Qs[(w << 2) + i][d], kd, s[i]);
        }

        const int  key       = j0 + lane;
        const bool isA       = key < Na;
        const bool blockHasA = (j0 < Na);
        const bool blockHasI = (j0 + KT > Na);

        if (blockHasA) {
#pragma unroll
            for (int i = 0; i < 4; ++i) {
                float sv   = isA ? s[i] : NEG_BIG;
                float mmax = wave_max64(sv);
                float mnew = fmaxf(mA[i], mmax);
                float pv   = isA ? __expf(s[i] - mnew) : 0.f;
                float ps   = wave_sum64(pv);
                float corr = __expf(mA[i] - mnew);
                lA[i] = lA[i] * corr + ps;
                oA[i] *= corr;
                mA[i] = mnew;
                Pl[w][i][lane] = pv;
            }
            __syncthreads();
            for (int k = 0; k < KT; ++k) {
                float vv = Vb[k][lane];
#pragma unroll
                for (int i = 0; i < 4; ++i) oA[i] = fmaf(Pl[w][i][k], vv, oA[i]);
            }
            __syncthreads();   // WAR: Pl reused below / next iteration
        }
        if (blockHasI) {
#pragma unroll
            for (int i = 0; i < 4; ++i) {
                float sv   = (!isA) ? s[i] : NEG_BIG;
                float mmax = wave_max64(sv);
                float mnew = fmaxf(mI[i], mmax);
                float pv   = (!isA) ? __expf(s[i] - mnew) : 0.f;
                float ps   = wave_sum64(pv);
                float corr = __expf(mI[i] - mnew);
                lI[i] = lI[i] * corr + ps;
                oI[i] *= corr;
                mI[i] = mnew;
                Pl[w][i][lane] = pv;
            }
            __syncthreads();
            for (int k = 0; k < KT; ++k) {
                float vv = Vb[k][lane];
#pragma unroll
                for (int i = 0; i < 4; ++i) oI[i] = fmaf(Pl[w][i][k], vv, oI[i]);
            }
            __syncthreads();
        }
    }

    const float rsA = (Na > 0) ? rsqrtf((float)Na) : 0.f;
    const float rsI = (Ni > 0) ? rsqrtf((float)Ni) : 0.f;
#pragma unroll
    for (int i = 0; i < 4; ++i) {
        float res = 0.f;
        if (Na > 0) res += (oA[i] / lA[i]) * rsA;
        if (Ni > 0) res -= (oI[i] / lI[i]) * rsI;
        O[(size_t)(b * TQ_ + q0 + (w << 2) + i) * D_ + h * HD_ + lane] = res;
    }
}

// ---------------- output projection: d_out = Ao @ Wo^T + bo ----------------
__global__ __launch_bounds__(256)
void sdpca_gemm_o(const float* __restrict__ A, const float* __restrict__ W,
                  const float* __restrict__ bias, float* __restrict__ C)
{
    __shared__ float As[BKT][LDP];
    __shared__ float Ws[BKT][LDP];
    const int tid  = threadIdx.x;
    const int brow = blockIdx.y * BM;
    const int bcol = blockIdx.x * BN;
    const int tr   = (tid >> 4) << 2;
    const int tc   = (tid & 15) << 2;

    float acc[4][4] = {};
    for (int k0 = 0; k0 < D_; k0 += BKT) {
#pragma unroll
        for (int i = 0; i < 2; ++i) {
            int idx = (i << 8) + tid;
            int r   = idx >> 3;
            int c   = (idx & 7) << 2;
            float4 av = *(const float4*)(A + (size_t)(brow + r) * D_ + (k0 + c));
            As[c + 0][r] = av.x; As[c + 1][r] = av.y; As[c + 2][r] = av.z; As[c + 3][r] = av.w;
            float4 wv = *(const float4*)(W + (size_t)(bcol + r) * D_ + (k0 + c));
            Ws[c + 0][r] = wv.x; Ws[c + 1][r] = wv.y; Ws[c + 2][r] = wv.z; Ws[c + 3][r] = wv.w;
        }
        __syncthreads();
#pragma unroll
        for (int kk = 0; kk < BKT; ++kk) {
            float4 a = *(const float4*)&As[kk][tr];
            float4 w = *(const float4*)&Ws[kk][tc];
            float aa[4] = {a.x, a.y, a.z, a.w};
            float ww[4] = {w.x, w.y, w.z, w.w};
#pragma unroll
            for (int i2 = 0; i2 < 4; ++i2)
#pragma unroll
                for (int j2 = 0; j2 < 4; ++j2)
                    acc[i2][j2] = fmaf(aa[i2], ww[j2], acc[i2][j2]);
        }
        __syncthreads();
    }

#pragma unroll
    for (int i = 0; i < 4; ++i) {
        int r = brow + tr + i;
        float4 bv = *(const float4*)(bias + bcol + tc);
        float4 o;
        o.x = acc[i][0] + bv.x; o.y = acc[i][1] + bv.y;
        o.z = acc[i][2] + bv.z; o.w = acc[i][3] + bv.w;
        *(float4*)(C + (size_t)r * D_ + bcol + tc) = o;
    }
}

extern "C" void kernel_launch(void* const* d_in, const int* in_sizes, int n_in,
                              void* d_out, int out_size, void* d_ws, size_t ws_size,
                              hipStream_t stream) {
    (void)in_sizes; (void)n_in; (void)out_size; (void)ws_size;
    const float* q   = (const float*)d_in[0];
    const float* kv  = (const float*)d_in[1];
    const float* Wq  = (const float*)d_in[2];
    const float* bq  = (const float*)d_in[3];
    const float* Wk  = (const float*)d_in[4];
    const float* bk  = (const float*)d_in[5];
    const float* Wv  = (const float*)d_in[6];
    const float* bv  = (const float*)d_in[7];
    const float* Wo  = (const float*)d_in[8];
    const float* bo  = (const float*)d_in[9];
    const float* ab  = (const float*)d_in[10];
    const float* ib  = (const float*)d_in[11];
    const float* lt  = (const float*)d_in[12];
    const int*   na  = (const int*)d_in[13];

    float* ws   = (float*)d_ws;
    const size_t nQ  = (size_t)B_ * TQ_ * D_;   // 1,048,576
    const size_t nKV = (size_t)B_ * TK_ * D_;   // 16,777,216
    float* Qp = ws;
    float* Kp = Qp + nQ;
    float* Vp = Kp + nKV;
    float* Ao = Vp + nKV;                        // total ~142.6 MB of d_ws

    dim3 blk(256);
    sdpca_gemm_q <<<dim3(D_ / BN, (B_ * TQ_) / BM), blk, 0, stream>>>(q, Wq, bq, lt, Qp);
    sdpca_gemm_kv<<<dim3(D_ / BN, (B_ * TK_) / BM), blk, 0, stream>>>(kv, Wk, bk, Wv, bv, ab, ib, na, Kp, Vp);
    sdpca_attn   <<<dim3(TQ_ / QT, B_ * NH_),       blk, 0, stream>>>(Qp, Kp, Vp, na, Ao);
    sdpca_gemm_o <<<dim3(D_ / BN, (B_ * TQ_) / BM), blk, 0, stream>>>(Ao, Wo, bo, (float*)d_out);
}

// Round 2
// 1519.178 us; speedup vs baseline: 2.0279x; 2.0279x over previous
//
#include <hip/hip_runtime.h>
#include <math.h>

#define B_   2
#define TQ_  512
#define TK_  8192
#define D_   1024
#define NH_  16
#define HD_  64

// ---------------- GEMM config: C[M,N] = A[M,K] @ W[N,K]^T (+bias) ----------------
#define BM   64
#define BN   64
#define BKT  32
#define LDP  68   // padded LDS row stride (floats): 272B keeps float4 alignment

#define NEG_BIG (-3.0e38f)

// ---------------- Q projection: C = (A @ Wq^T + bq) * 1/(64*temp) ----------------
__global__ __launch_bounds__(256)
void sdpca_gemm_q(const float* __restrict__ A, const float* __restrict__ W,
                  const float* __restrict__ bias, const float* __restrict__ log_temp,
                  float* __restrict__ C)
{
    __shared__ float As[BKT][LDP];
    __shared__ float Ws[BKT][LDP];
    const int tid  = threadIdx.x;
    const int brow = blockIdx.y * BM;
    const int bcol = blockIdx.x * BN;
    const int tr   = (tid >> 4) << 2;
    const int tc   = (tid & 15) << 2;

    float acc[4][4] = {};
    for (int k0 = 0; k0 < D_; k0 += BKT) {
#pragma unroll
        for (int i = 0; i < 2; ++i) {
            int idx = (i << 8) + tid;
            int r   = idx >> 3;
            int c   = (idx & 7) << 2;
            float4 av = *(const float4*)(A + (size_t)(brow + r) * D_ + (k0 + c));
            As[c + 0][r] = av.x; As[c + 1][r] = av.y; As[c + 2][r] = av.z; As[c + 3][r] = av.w;
            float4 wv = *(const float4*)(W + (size_t)(bcol + r) * D_ + (k0 + c));
            Ws[c + 0][r] = wv.x; Ws[c + 1][r] = wv.y; Ws[c + 2][r] = wv.z; Ws[c + 3][r] = wv.w;
        }
        __syncthreads();
#pragma unroll
        for (int kk = 0; kk < BKT; ++kk) {
            float4 a = *(const float4*)&As[kk][tr];
            float4 w = *(const float4*)&Ws[kk][tc];
            float aa[4] = {a.x, a.y, a.z, a.w};
            float ww[4] = {w.x, w.y, w.z, w.w};
#pragma unroll
            for (int i2 = 0; i2 < 4; ++i2)
#pragma unroll
                for (int j2 = 0; j2 < 4; ++j2)
                    acc[i2][j2] = fmaf(aa[i2], ww[j2], acc[i2][j2]);
        }
        __syncthreads();
    }

    float lt    = *log_temp;
    float temp  = fminf(fmaxf(expf(lt), 0.1f), 10.0f);
    float scale = 1.0f / (64.0f * temp);

#pragma unroll
    for (int i = 0; i < 4; ++i) {
        int r = brow + tr + i;
        float4 bv = *(const float4*)(bias + bcol + tc);
        float4 o;
        o.x = (acc[i][0] + bv.x) * scale;
        o.y = (acc[i][1] + bv.y) * scale;
        o.z = (acc[i][2] + bv.z) * scale;
        o.w = (acc[i][3] + bv.w) * scale;
        *(float4*)(C + (size_t)r * D_ + bcol + tc) = o;
    }
}

// ------------- K/V projection with per-group input bias, dual output -------------
__global__ __launch_bounds__(256)
void sdpca_gemm_kv(const float* __restrict__ A,
                   const float* __restrict__ Wk, const float* __restrict__ bk,
                   const float* __restrict__ Wv, const float* __restrict__ bv,
                   const float* __restrict__ abias, const float* __restrict__ ibias,
                   const int* __restrict__ nactp,
                   float* __restrict__ K, float* __restrict__ V)
{
    __shared__ float As [BKT][LDP];
    __shared__ float Wks[BKT][LDP];
    __shared__ float Wvs[BKT][LDP];
    const int tid  = threadIdx.x;
    const int brow = blockIdx.y * BM;
    const int bcol = blockIdx.x * BN;
    const int tr   = (tid >> 4) << 2;
    const int tc   = (tid & 15) << 2;
    const int Na   = *nactp;

    float acck[4][4] = {};
    float accv[4][4] = {};
    for (int k0 = 0; k0 < D_; k0 += BKT) {
#pragma unroll
        for (int i = 0; i < 2; ++i) {
            int idx = (i << 8) + tid;
            int r   = idx >> 3;
            int c   = (idx & 7) << 2;
            int gr  = brow + r;
            int t   = gr & (TK_ - 1);
            const float* bp = (t < Na) ? abias : ibias;
            float4 av = *(const float4*)(A + (size_t)gr * D_ + (k0 + c));
            float4 bb = *(const float4*)(bp + (k0 + c));
            As[c + 0][r] = av.x + bb.x; As[c + 1][r] = av.y + bb.y;
            As[c + 2][r] = av.z + bb.z; As[c + 3][r] = av.w + bb.w;
            float4 wk = *(const float4*)(Wk + (size_t)(bcol + r) * D_ + (k0 + c));
            Wks[c + 0][r] = wk.x; Wks[c + 1][r] = wk.y; Wks[c + 2][r] = wk.z; Wks[c + 3][r] = wk.w;
            float4 wv = *(const float4*)(Wv + (size_t)(bcol + r) * D_ + (k0 + c));
            Wvs[c + 0][r] = wv.x; Wvs[c + 1][r] = wv.y; Wvs[c + 2][r] = wv.z; Wvs[c + 3][r] = wv.w;
        }
        __syncthreads();
#pragma unroll
        for (int kk = 0; kk < BKT; ++kk) {
            float4 a  = *(const float4*)&As [kk][tr];
            float4 wk = *(const float4*)&Wks[kk][tc];
            float4 wv = *(const float4*)&Wvs[kk][tc];
            float aa[4] = {a.x, a.y, a.z, a.w};
            float kk4[4] = {wk.x, wk.y, wk.z, wk.w};
            float vv4[4] = {wv.x, wv.y, wv.z, wv.w};
#pragma unroll
            for (int i2 = 0; i2 < 4; ++i2)
#pragma unroll
                for (int j2 = 0; j2 < 4; ++j2) {
                    acck[i2][j2] = fmaf(aa[i2], kk4[j2], acck[i2][j2]);
                    accv[i2][j2] = fmaf(aa[i2], vv4[j2], accv[i2][j2]);
                }
        }
        __syncthreads();
    }

#pragma unroll
    for (int i = 0; i < 4; ++i) {
        int r = brow + tr + i;
        float4 bkv = *(const float4*)(bk + bcol + tc);
        float4 bvv = *(const float4*)(bv + bcol + tc);
        float4 ok, ov;
        ok.x = acck[i][0] + bkv.x; ok.y = acck[i][1] + bkv.y;
        ok.z = acck[i][2] + bkv.z; ok.w = acck[i][3] + bkv.w;
        ov.x = accv[i][0] + bvv.x; ov.y = accv[i][1] + bvv.y;
        ov.z = accv[i][2] + bvv.z; ov.w = accv[i][3] + bvv.w;
        *(float4*)(K + (size_t)r * D_ + bcol + tc) = ok;
        *(float4*)(V + (size_t)r * D_ + bcol + tc) = ov;
    }
}

// ---------------- two-group flash attention, GEMM-style tiles ----------------
// grid: (TQ/64, B*NH, SPLIT). block 256 = 4 waves.
// Score phase computes S^T[key][q] with 4x4 micro-tiles:
//   key rows = 4*(lane&15)+i (16 distinct/wave), q cols = 16*w + 4*(lane>>4)+j.
// Softmax reduce over keys = shfl_xor 8,4,2,1 (within the 16 key-groups).
// P^T written back into the K^T LDS buffer (float4, aligned); PV is a plain
// GEMM O[q][hd] += P^T[k][q(bcast)] * V[k][hd], with m/l/corr thread-local.
#define QT    64
#define KT    64
#define S_    68            // LDS row stride (floats); 272B = 16B-aligned rows
#define SPLIT 2

__device__ __forceinline__ void attn_group(
    const float sT[4][4], const bool rin[4],
    float m[4], float lsum[4], float o[4][4],
    float (*KPt)[S_], const float (*Vb)[S_],
    int qcol, int kx)
{
    float mnew[4], corr[4];
#pragma unroll
    for (int j = 0; j < 4; ++j) {
        float v = NEG_BIG;
#pragma unroll
        for (int i = 0; i < 4; ++i) if (rin[i]) v = fmaxf(v, sT[i][j]);
#pragma unroll
        for (int msk = 8; msk >= 1; msk >>= 1) v = fmaxf(v, __shfl_xor(v, msk, 64));
        mnew[j] = fmaxf(m[j], v);
        corr[j] = __expf(m[j] - mnew[j]);
    }
    float p[4][4];
#pragma unroll
    for (int j = 0; j < 4; ++j) {
        float ssum = 0.f;
#pragma unroll
        for (int i = 0; i < 4; ++i) {
            float pv = rin[i] ? __expf(sT[i][j] - mnew[j]) : 0.f;
            p[i][j] = pv; ssum += pv;
        }
#pragma unroll
        for (int msk = 8; msk >= 1; msk >>= 1) ssum += __shfl_xor(ssum, msk, 64);
        lsum[j] = lsum[j] * corr[j] + ssum;
        m[j] = mnew[j];
    }
#pragma unroll
    for (int i = 0; i < 4; ++i) {
        float c = corr[i];
#pragma unroll
        for (int j = 0; j < 4; ++j) o[i][j] *= c;
    }
    __syncthreads();                       // all score reads of KPt done
#pragma unroll
    for (int i = 0; i < 4; ++i)
        *(float4*)&KPt[kx + i][qcol] = make_float4(p[i][0], p[i][1], p[i][2], p[i][3]);
    __syncthreads();                       // P^T visible
#pragma unroll 8
    for (int kk = 0; kk < KT; ++kk) {
        float4 pa = *(const float4*)&KPt[kk][qcol];
        float4 vb = *(const float4*)&Vb[kk][kx];
        float paa[4] = {pa.x, pa.y, pa.z, pa.w};
        float vbb[4] = {vb.x, vb.y, vb.z, vb.w};
#pragma unroll
        for (int i = 0; i < 4; ++i)
#pragma unroll
            for (int j = 0; j < 4; ++j)
                o[i][j] = fmaf(paa[i], vbb[j], o[i][j]);
    }
}

__global__ __launch_bounds__(256, 2)
void sdpca_attn(const float* __restrict__ Q,  // (B*TQ, D), pre-scaled
                const float* __restrict__ K,  // (B*TK, D)
                const float* __restrict__ V,  // (B*TK, D)
                const int* __restrict__ nactp,
                float* __restrict__ pO,       // [SPLIT][2][BH][TQ][HD]
                float* __restrict__ pM,       // [SPLIT][2][BH][TQ]
                float* __restrict__ pL)       // [SPLIT][2][BH][TQ]
{
    __shared__ float Qt [HD_][S_];   // Q^T: [d][q]
    __shared__ float KPt[KT ][S_];   // K^T [d][k] in score phase; P^T [k][q] in PV
    __shared__ float Vb [KT ][S_];   // V   [k][d]

    const int tid = threadIdx.x;
    const int l   = tid & 63;
    const int w   = tid >> 6;
    const int bh  = blockIdx.y;
    const int b   = bh >> 4;
    const int h   = bh & 15;
    const int q0  = blockIdx.x * QT;
    const int s   = blockIdx.z;
    const int Na  = *nactp;
    const int ks0 = s * (TK_ / SPLIT);

    const int qcol = (w << 4) + ((l >> 4) << 2);  // q-column base (0..60)
    const int kx   = (l & 15) << 2;               // key-row base / hd base (0..60)

    {   // stage Q^T once
        int qr = tid & 63, d0 = (tid >> 6) << 4;
        const float* qp = Q + (size_t)(b * TQ_ + q0 + qr) * D_ + h * HD_ + d0;
#pragma unroll
        for (int u = 0; u < 4; ++u) {
            float4 v4 = *(const float4*)(qp + 4 * u);
            Qt[d0 + 4*u + 0][qr] = v4.x;
            Qt[d0 + 4*u + 1][qr] = v4.y;
            Qt[d0 + 4*u + 2][qr] = v4.z;
            Qt[d0 + 4*u + 3][qr] = v4.w;
        }
    }

    float mA[4], lA[4], oA[4][4], mI[4], lI[4], oI[4][4];
#pragma unroll
    for (int j = 0; j < 4; ++j) { mA[j] = NEG_BIG; lA[j] = 0.f; mI[j] = NEG_BIG; lI[j] = 0.f; }
#pragma unroll
    for (int i = 0; i < 4; ++i)
#pragma unroll
        for (int j = 0; j < 4; ++j) { oA[i][j] = 0.f; oI[i][j] = 0.f; }

    for (int t = 0; t < TK_ / SPLIT / KT; ++t) {
        const int jb = ks0 + t * KT;
        __syncthreads();                   // prev PV reads done before restage
        {   // stage K^T (transposed) and V (direct)
            int kr = tid & 63, d0 = (tid >> 6) << 4;
            const float* kp = K + (size_t)(b * TK_ + jb + kr) * D_ + h * HD_ + d0;
            const float* vp = V + (size_t)(b * TK_ + jb + kr) * D_ + h * HD_ + d0;
#pragma unroll
            for (int u = 0; u < 4; ++u) {
                float4 k4 = *(const float4*)(kp + 4 * u);
                KPt[d0 + 4*u + 0][kr] = k4.x;
                KPt[d0 + 4*u + 1][kr] = k4.y;
                KPt[d0 + 4*u + 2][kr] = k4.z;
                KPt[d0 + 4*u + 3][kr] = k4.w;
                float4 v4 = *(const float4*)(vp + 4 * u);
                *(float4*)&Vb[kr][d0 + 4*u] = v4;
            }
        }
        __syncthreads();

        // score GEMM: S^T[key][q]
        float sT[4][4] = {};
#pragma unroll 8
        for (int d = 0; d < HD_; ++d) {
            float4 ka = *(const float4*)&KPt[d][kx];
            float4 qa = *(const float4*)&Qt[d][qcol];
            float kk4[4] = {ka.x, ka.y, ka.z, ka.w};
            float qq4[4] = {qa.x, qa.y, qa.z, qa.w};
#pragma unroll
            for (int i = 0; i < 4; ++i)
#pragma unroll
                for (int j = 0; j < 4; ++j)
                    sT[i][j] = fmaf(kk4[i], qq4[j], sT[i][j]);
        }

        const bool hasA = (jb < Na);
        const bool hasI = (jb + KT > Na);
        if (hasA) {
            bool rin[4];
#pragma unroll
            for (int i = 0; i < 4; ++i) rin[i] = (jb + kx + i) < Na;
            attn_group(sT, rin, mA, lA, oA, KPt, Vb, qcol, kx);
        }
        if (hasI) {
            bool rin[4];
#pragma unroll
            for (int i = 0; i < 4; ++i) rin[i] = (jb + kx + i) >= Na;
            attn_group(sT, rin, mI, lI, oI, KPt, Vb, qcol, kx);
        }
    }

    // epilogue: unnormalized partials + (m,l)
    const size_t baseA = ((size_t)((s * 2 + 0) * (B_ * NH_) + bh)) * TQ_;
    const size_t baseI = ((size_t)((s * 2 + 1) * (B_ * NH_) + bh)) * TQ_;
#pragma unroll
    for (int i = 0; i < 4; ++i) {
        int q = q0 + qcol + i;
        *(float4*)&pO[(baseA + q) * HD_ + kx] = make_float4(oA[i][0], oA[i][1], oA[i][2], oA[i][3]);
        *(float4*)&pO[(baseI + q) * HD_ + kx] = make_float4(oI[i][0], oI[i][1], oI[i][2], oI[i][3]);
    }
    if ((l & 15) == 0) {
#pragma unroll
        for (int j = 0; j < 4; ++j) {
            int q = q0 + qcol + j;
            pM[baseA + q] = mA[j]; pL[baseA + q] = lA[j];
            pM[baseI + q] = mI[j]; pL[baseI + q] = lI[j];
        }
    }
}

// ---------------- split-K merge: Ao = mergeA/sqrt(Na) - mergeI/sqrt(Ni) ----------------
__global__ __launch_bounds__(256)
void sdpca_combine(const float* __restrict__ pO, const float* __restrict__ pM,
                   const float* __restrict__ pL, const int* __restrict__ nactp,
                   float* __restrict__ Ao)
{
    int idx = blockIdx.x * 256 + threadIdx.x;      // < B*TQ*D
    int d   = idx & (HD_ - 1);
    int q   = (idx >> 6) & (TQ_ - 1);
    int bh  = idx >> 15;
    int b   = bh >> 4, h = bh & 15;
    int Na  = *nactp;
    int Ni  = TK_ - Na;

    float res = 0.f;
#pragma unroll
    for (int g = 0; g < 2; ++g) {
        size_t i0 = ((size_t)((0 * 2 + g) * (B_ * NH_) + bh)) * TQ_ + q;
        size_t i1 = ((size_t)((1 * 2 + g) * (B_ * NH_) + bh)) * TQ_ + q;
        float m0 = pM[i0], m1 = pM[i1];
        float l0 = pL[i0], l1 = pL[i1];
        float o0 = pO[i0 * HD_ + d], o1 = pO[i1 * HD_ + d];
        float M  = fmaxf(m0, m1);
        float w0 = __expf(m0 - M), w1 = __expf(m1 - M);
        float L  = l0 * w0 + l1 * w1;
        float O  = o0 * w0 + o1 * w1;
        float r  = (L > 0.f) ? (O / L) : 0.f;
        int   cnt = (g == 0) ? Na : Ni;
        float sc  = (cnt > 0) ? rsqrtf((float)cnt) : 0.f;
        res += (g == 0) ? (sc * r) : (-sc * r);
    }
    Ao[((size_t)(b * TQ_ + q)) * D_ + h * HD_ + d] = res;
}

// ---------------- output projection: d_out = Ao @ Wo^T + bo ----------------
__global__ __launch_bounds__(256)
void sdpca_gemm_o(const float* __restrict__ A, const float* __restrict__ W,
                  const float* __restrict__ bias, float* __restrict__ C)
{
    __shared__ float As[BKT][LDP];
    __shared__ float Ws[BKT][LDP];
    const int tid  = threadIdx.x;
    const int brow = blockIdx.y * BM;
    const int bcol = blockIdx.x * BN;
    const int tr   = (tid >> 4) << 2;
    const int tc   = (tid & 15) << 2;

    float acc[4][4] = {};
    for (int k0 = 0; k0 < D_; k0 += BKT) {
#pragma unroll
        for (int i = 0; i < 2; ++i) {
            int idx = (i << 8) + tid;
            int r   = idx >> 3;
            int c   = (idx & 7) << 2;
            float4 av = *(const float4*)(A + (size_t)(brow + r) * D_ + (k0 + c));
            As[c + 0][r] = av.x; As[c + 1][r] = av.y; As[c + 2][r] = av.z; As[c + 3][r] = av.w;
            float4 wv = *(const float4*)(W + (size_t)(bcol + r) * D_ + (k0 + c));
            Ws[c + 0][r] = wv.x; Ws[c + 1][r] = wv.y; Ws[c + 2][r] = wv.z; Ws[c + 3][r] = wv.w;
        }
        __syncthreads();
#pragma unroll
        for (int kk = 0; kk < BKT; ++kk) {
            float4 a = *(const float4*)&As[kk][tr];
            float4 w = *(const float4*)&Ws[kk][tc];
            float aa[4] = {a.x, a.y, a.z, a.w};
            float ww[4] = {w.x, w.y, w.z, w.w};
#pragma unroll
            for (int i2 = 0; i2 < 4; ++i2)
#pragma unroll
                for (int j2 = 0; j2 < 4; ++j2)
                    acc[i2][j2] = fmaf(aa[i2], ww[j2], acc[i2][j2]);
        }
        __syncthreads();
    }

#pragma unroll
    for (int i = 0; i < 4; ++i) {
        int r = brow + tr + i;
        float4 bv = *(const float4*)(bias + bcol + tc);
        float4 o;
        o.x = acc[i][0] + bv.x; o.y = acc[i][1] + bv.y;
        o.z = acc[i][2] + bv.z; o.w = acc[i][3] + bv.w;
        *(float4*)(C + (size_t)r * D_ + bcol + tc) = o;
    }
}

extern "C" void kernel_launch(void* const* d_in, const int* in_sizes, int n_in,
                              void* d_out, int out_size, void* d_ws, size_t ws_size,
                              hipStream_t stream) {
    (void)in_sizes; (void)n_in; (void)out_size; (void)ws_size;
    const float* q   = (const float*)d_in[0];
    const float* kv  = (const float*)d_in[1];
    const float* Wq  = (const float*)d_in[2];
    const float* bq  = (const float*)d_in[3];
    const float* Wk  = (const float*)d_in[4];
    const float* bk  = (const float*)d_in[5];
    const float* Wv  = (const float*)d_in[6];
    const float* bv  = (const float*)d_in[7];
    const float* Wo  = (const float*)d_in[8];
    const float* bo  = (const float*)d_in[9];
    const float* ab  = (const float*)d_in[10];
    const float* ib  = (const float*)d_in[11];
    const float* lt  = (const float*)d_in[12];
    const int*   na  = (const int*)d_in[13];

    float* ws = (float*)d_ws;
    const size_t nQ   = (size_t)B_ * TQ_ * D_;       // 1,048,576
    const size_t nKV  = (size_t)B_ * TK_ * D_;       // 16,777,216
    const size_t nML  = (size_t)SPLIT * 2 * B_ * NH_ * TQ_;  // 65,536
    float* Qp = ws;
    float* Kp = Qp + nQ;
    float* Vp = Kp + nKV;
    float* pO = Vp + nKV;            // SPLIT*2*nQ = 4*nQ floats
    float* pM = pO + (size_t)SPLIT * 2 * nQ;
    float* pL = pM + nML;
    float* Ao = Qp;                  // Qp dead after attn; reuse for attention output
    // total ws: ~155.7 MB

    dim3 blk(256);
    sdpca_gemm_q  <<<dim3(D_ / BN, (B_ * TQ_) / BM), blk, 0, stream>>>(q, Wq, bq, lt, Qp);
    sdpca_gemm_kv <<<dim3(D_ / BN, (B_ * TK_) / BM), blk, 0, stream>>>(kv, Wk, bk, Wv, bv, ab, ib, na, Kp, Vp);
    sdpca_attn    <<<dim3(TQ_ / QT, B_ * NH_, SPLIT), blk, 0, stream>>>(Qp, Kp, Vp, na, pO, pM, pL);
    sdpca_combine <<<dim3((B_ * TQ_ * D_) / 256),     blk, 0, stream>>>(pO, pM, pL, na, Ao);
    sdpca_gemm_o  <<<dim3(D_ / BN, (B_ * TQ_) / BM), blk, 0, stream>>>(Ao, Wo, bo, (float*)d_out);
}

// Round 3
// 908.866 us; speedup vs baseline: 3.3896x; 1.6715x over previous
//
#include <hip/hip_runtime.h>
#include <math.h>
#include <stdint.h>

#define B_   2
#define TQ_  512
#define TK_  8192
#define D_   1024
#define NH_  16
#define HD_  64

#define NEG_BIG (-3.0e38f)

typedef __attribute__((ext_vector_type(8))) short short8;
typedef __attribute__((ext_vector_type(4))) float f32x4;

// ---------------- bf16 helpers (RNE, bit-exact, no API deps) ----------------
__device__ __forceinline__ unsigned short f2bf(float x) {
    unsigned u = __float_as_uint(x);
    unsigned r = u + 0x7FFFu + ((u >> 16) & 1u);
    return (unsigned short)(r >> 16);
}
__device__ __forceinline__ float bf2f(unsigned short h) {
    return __uint_as_float(((unsigned)h) << 16);
}

// direct-to-LDS async copy, 16B per lane; lds base must be wave-uniform
#define GLD16(gp, lp)                                                              \
    __builtin_amdgcn_global_load_lds(                                              \
        (const __attribute__((address_space(1))) unsigned int*)(gp),               \
        (__attribute__((address_space(3))) unsigned int*)(lp), 16, 0, 0)

// ---------------- fp32 GEMM config (q/o projections) ----------------
#define BM   64
#define BN   64
#define BKT  32
#define LDP  68

// ---------------- Q projection: C = (A @ Wq^T + bq) * 1/(64*temp) ----------------
__global__ __launch_bounds__(256)
void sdpca_gemm_q(const float* __restrict__ A, const float* __restrict__ W,
                  const float* __restrict__ bias, const float* __restrict__ log_temp,
                  float* __restrict__ C)
{
    __shared__ float As[BKT][LDP];
    __shared__ float Ws[BKT][LDP];
    const int tid  = threadIdx.x;
    const int brow = blockIdx.y * BM;
    const int bcol = blockIdx.x * BN;
    const int tr   = (tid >> 4) << 2;
    const int tc   = (tid & 15) << 2;

    float acc[4][4] = {};
    for (int k0 = 0; k0 < D_; k0 += BKT) {
#pragma unroll
        for (int i = 0; i < 2; ++i) {
            int idx = (i << 8) + tid;
            int r   = idx >> 3;
            int c   = (idx & 7) << 2;
            float4 av = *(const float4*)(A + (size_t)(brow + r) * D_ + (k0 + c));
            As[c + 0][r] = av.x; As[c + 1][r] = av.y; As[c + 2][r] = av.z; As[c + 3][r] = av.w;
            float4 wv = *(const float4*)(W + (size_t)(bcol + r) * D_ + (k0 + c));
            Ws[c + 0][r] = wv.x; Ws[c + 1][r] = wv.y; Ws[c + 2][r] = wv.z; Ws[c + 3][r] = wv.w;
        }
        __syncthreads();
#pragma unroll
        for (int kk = 0; kk < BKT; ++kk) {
            float4 a = *(const float4*)&As[kk][tr];
            float4 w = *(const float4*)&Ws[kk][tc];
            float aa[4] = {a.x, a.y, a.z, a.w};
            float ww[4] = {w.x, w.y, w.z, w.w};
#pragma unroll
            for (int i2 = 0; i2 < 4; ++i2)
#pragma unroll
                for (int j2 = 0; j2 < 4; ++j2)
                    acc[i2][j2] = fmaf(aa[i2], ww[j2], acc[i2][j2]);
        }
        __syncthreads();
    }

    float lt    = *log_temp;
    float temp  = fminf(fmaxf(expf(lt), 0.1f), 10.0f);
    float scale = 1.0f / (64.0f * temp);

#pragma unroll
    for (int i = 0; i < 4; ++i) {
        int r = brow + tr + i;
        float4 bv = *(const float4*)(bias + bcol + tc);
        float4 o;
        o.x = (acc[i][0] + bv.x) * scale;
        o.y = (acc[i][1] + bv.y) * scale;
        o.z = (acc[i][2] + bv.z) * scale;
        o.w = (acc[i][3] + bv.w) * scale;
        *(float4*)(C + (size_t)r * D_ + bcol + tc) = o;
    }
}

// ---------------- hi/lo bf16 split of (kv + group bias) ----------------
__global__ __launch_bounds__(256)
void split_kv(const float* __restrict__ kv, const float* __restrict__ ab,
              const float* __restrict__ ib, const int* __restrict__ nactp,
              unsigned short* __restrict__ Ah, unsigned short* __restrict__ Al)
{
    const int Na = *nactp;
    size_t i = ((size_t)blockIdx.x * 256 + threadIdx.x) * 8;   // 16M elems total
    int row = (int)(i >> 10);
    int col = (int)(i & (D_ - 1));
    const float* bp = ((row & (TK_ - 1)) < Na) ? ab : ib;
    float4 x0 = *(const float4*)(kv + i);
    float4 x1 = *(const float4*)(kv + i + 4);
    float4 b0 = *(const float4*)(bp + col);
    float4 b1 = *(const float4*)(bp + col + 4);
    float a[8] = {x0.x + b0.x, x0.y + b0.y, x0.z + b0.z, x0.w + b0.w,
                  x1.x + b1.x, x1.y + b1.y, x1.z + b1.z, x1.w + b1.w};
    union { short8 v; unsigned short u[8]; } H, L;
#pragma unroll
    for (int j = 0; j < 8; ++j) {
        unsigned short h = f2bf(a[j]);
        H.u[j] = h;
        L.u[j] = f2bf(a[j] - bf2f(h));
    }
    *(short8*)(Ah + i) = H.v;
    *(short8*)(Al + i) = L.v;
}

// ---------------- hi/lo bf16 split of a weight matrix ----------------
__global__ __launch_bounds__(256)
void split_w(const float* __restrict__ W,
             unsigned short* __restrict__ Wh, unsigned short* __restrict__ Wl)
{
    size_t i = ((size_t)blockIdx.x * 256 + threadIdx.x) * 8;   // 1M elems total
    float4 x0 = *(const float4*)(W + i);
    float4 x1 = *(const float4*)(W + i + 4);
    float a[8] = {x0.x, x0.y, x0.z, x0.w, x1.x, x1.y, x1.z, x1.w};
    union { short8 v; unsigned short u[8]; } H, L;
#pragma unroll
    for (int j = 0; j < 8; ++j) {
        unsigned short h = f2bf(a[j]);
        H.u[j] = h;
        L.u[j] = f2bf(a[j] - bf2f(h));
    }
    *(short8*)(Wh + i) = H.v;
    *(short8*)(Wl + i) = L.v;
}

// ---------------- K/V projection via bf16x3 MFMA ----------------
// C[M=16384, N=1024] = A @ W^T + bias, fp32-equivalent via Ah*Wh + Ah*Wl + Al*Wh.
// grid (N/128, M/128, 2): z picks (Wk->Kp) or (Wv->Vp). block 256 = 4 waves,
// wave (wr,wc) owns the 64x64 sub-tile; 16x16x32 MFMA, 4x4 fragments.
__global__ __launch_bounds__(256)
void sdpca_gemm_kv_mfma(const unsigned short* __restrict__ Ah, const unsigned short* __restrict__ Al,
                        const unsigned short* __restrict__ Whk, const unsigned short* __restrict__ Wlk,
                        const unsigned short* __restrict__ Whv, const unsigned short* __restrict__ Wlv,
                        const float* __restrict__ bk, const float* __restrict__ bv,
                        float* __restrict__ Kp, float* __restrict__ Vp)
{
    __shared__ unsigned short AhT[128 * 32];
    __shared__ unsigned short AlT[128 * 32];
    __shared__ unsigned short BhT[128 * 32];
    __shared__ unsigned short BlT[128 * 32];

    const int tid  = threadIdx.x;
    const int lane = tid & 63;
    const int w    = tid >> 6;
    const int brow = blockIdx.y * 128;
    const int bcol = blockIdx.x * 128;

    const unsigned short* Wh; const unsigned short* Wl; const float* bias; float* C;
    if (blockIdx.z == 0) { Wh = Whk; Wl = Wlk; bias = bk; C = Kp; }
    else                 { Wh = Whv; Wl = Wlv; bias = bv; C = Vp; }

    const int wr = w >> 1, wc = w & 1;

    // staging geometry: wave w stages rows [w*32, w*32+32) of each 128x32 tile,
    // as two 16-row halves; HW scatters lds_base + lane*16B == our linear layout.
    const int   srow = lane >> 2;
    const int   scol = (lane & 3) * 8;
    const size_t gA0 = (size_t)(brow + w * 32 + srow) * D_ + scol;
    const size_t gA1 = gA0 + (size_t)16 * D_;
    const size_t gB0 = (size_t)(bcol + w * 32 + srow) * D_ + scol;
    const size_t gB1 = gB0 + (size_t)16 * D_;
    const int   l0   = (w * 32 +  0) * 32;
    const int   l1   = (w * 32 + 16) * 32;

    f32x4 acc[4][4];
#pragma unroll
    for (int m = 0; m < 4; ++m)
#pragma unroll
        for (int n = 0; n < 4; ++n) acc[m][n] = (f32x4){0.f, 0.f, 0.f, 0.f};

    const int frow = lane & 15;
    const int fko  = (lane >> 4) * 8;

    for (int k0 = 0; k0 < D_; k0 += 32) {
        GLD16(Ah + gA0 + k0, &AhT[l0]);
        GLD16(Ah + gA1 + k0, &AhT[l1]);
        GLD16(Al + gA0 + k0, &AlT[l0]);
        GLD16(Al + gA1 + k0, &AlT[l1]);
        GLD16(Wh + gB0 + k0, &BhT[l0]);
        GLD16(Wh + gB1 + k0, &BhT[l1]);
        GLD16(Wl + gB0 + k0, &BlT[l0]);
        GLD16(Wl + gB1 + k0, &BlT[l1]);
        __syncthreads();

        short8 bh[4], bl[4];
#pragma unroll
        for (int n = 0; n < 4; ++n) {
            int r = wc * 64 + n * 16 + frow;
            bh[n] = *(const short8*)&BhT[r * 32 + fko];
            bl[n] = *(const short8*)&BlT[r * 32 + fko];
        }
#pragma unroll
        for (int m = 0; m < 4; ++m) {
            int r = wr * 64 + m * 16 + frow;
            short8 amh = *(const short8*)&AhT[r * 32 + fko];
            short8 aml = *(const short8*)&AlT[r * 32 + fko];
#pragma unroll
            for (int n = 0; n < 4; ++n) {
                acc[m][n] = __builtin_amdgcn_mfma_f32_16x16x32_bf16(amh, bh[n], acc[m][n], 0, 0, 0);
                acc[m][n] = __builtin_amdgcn_mfma_f32_16x16x32_bf16(amh, bl[n], acc[m][n], 0, 0, 0);
                acc[m][n] = __builtin_amdgcn_mfma_f32_16x16x32_bf16(aml, bh[n], acc[m][n], 0, 0, 0);
            }
        }
        __syncthreads();
    }

    // C/D layout: col = lane&15, row = (lane>>4)*4 + reg
#pragma unroll
    for (int n = 0; n < 4; ++n) {
        int col = bcol + wc * 64 + n * 16 + frow;
        float bsv = bias[col];
#pragma unroll
        for (int m = 0; m < 4; ++m) {
            int rbase = brow + wr * 64 + m * 16 + (lane >> 4) * 4;
#pragma unroll
            for (int r = 0; r < 4; ++r)
                C[(size_t)(rbase + r) * D_ + col] = acc[m][n][r] + bsv;
        }
    }
}

// ---------------- two-group flash attention, GEMM-style tiles ----------------
#define QT    64
#define KT    64
#define S_    68
#define SPLIT 2

__device__ __forceinline__ void attn_group(
    const float sT[4][4], const bool rin[4],
    float m[4], float lsum[4], float o[4][4],
    float (*KPt)[S_], const float (*Vb)[S_],
    int qcol, int kx)
{
    float mnew[4], corr[4];
#pragma unroll
    for (int j = 0; j < 4; ++j) {
        float v = NEG_BIG;
#pragma unroll
        for (int i = 0; i < 4; ++i) if (rin[i]) v = fmaxf(v, sT[i][j]);
#pragma unroll
        for (int msk = 8; msk >= 1; msk >>= 1) v = fmaxf(v, __shfl_xor(v, msk, 64));
        mnew[j] = fmaxf(m[j], v);
        corr[j] = __expf(m[j] - mnew[j]);
    }
    float p[4][4];
#pragma unroll
    for (int j = 0; j < 4; ++j) {
        float ssum = 0.f;
#pragma unroll
        for (int i = 0; i < 4; ++i) {
            float pv = rin[i] ? __expf(sT[i][j] - mnew[j]) : 0.f;
            p[i][j] = pv; ssum += pv;
        }
#pragma unroll
        for (int msk = 8; msk >= 1; msk >>= 1) ssum += __shfl_xor(ssum, msk, 64);
        lsum[j] = lsum[j] * corr[j] + ssum;
        m[j] = mnew[j];
    }
#pragma unroll
    for (int i = 0; i < 4; ++i) {
        float c = corr[i];
#pragma unroll
        for (int j = 0; j < 4; ++j) o[i][j] *= c;
    }
    __syncthreads();
#pragma unroll
    for (int i = 0; i < 4; ++i)
        *(float4*)&KPt[kx + i][qcol] = make_float4(p[i][0], p[i][1], p[i][2], p[i][3]);
    __syncthreads();
#pragma unroll 8
    for (int kk = 0; kk < KT; ++kk) {
        float4 pa = *(const float4*)&KPt[kk][qcol];
        float4 vb = *(const float4*)&Vb[kk][kx];
        float paa[4] = {pa.x, pa.y, pa.z, pa.w};
        float vbb[4] = {vb.x, vb.y, vb.z, vb.w};
#pragma unroll
        for (int i = 0; i < 4; ++i)
#pragma unroll
            for (int j = 0; j < 4; ++j)
                o[i][j] = fmaf(paa[i], vbb[j], o[i][j]);
    }
}

__global__ __launch_bounds__(256, 2)
void sdpca_attn(const float* __restrict__ Q,
                const float* __restrict__ K,
                const float* __restrict__ V,
                const int* __restrict__ nactp,
                float* __restrict__ pO,
                float* __restrict__ pM,
                float* __restrict__ pL)
{
    __shared__ float Qt [HD_][S_];
    __shared__ float KPt[KT ][S_];
    __shared__ float Vb [KT ][S_];

    const int tid = threadIdx.x;
    const int l   = tid & 63;
    const int w   = tid >> 6;
    const int bh  = blockIdx.y;
    const int b   = bh >> 4;
    const int h   = bh & 15;
    const int q0  = blockIdx.x * QT;
    const int s   = blockIdx.z;
    const int Na  = *nactp;
    const int ks0 = s * (TK_ / SPLIT);

    const int qcol = (w << 4) + ((l >> 4) << 2);
    const int kx   = (l & 15) << 2;

    {
        int qr = tid & 63, d0 = (tid >> 6) << 4;
        const float* qp = Q + (size_t)(b * TQ_ + q0 + qr) * D_ + h * HD_ + d0;
#pragma unroll
        for (int u = 0; u < 4; ++u) {
            float4 v4 = *(const float4*)(qp + 4 * u);
            Qt[d0 + 4*u + 0][qr] = v4.x;
            Qt[d0 + 4*u + 1][qr] = v4.y;
            Qt[d0 + 4*u + 2][qr] = v4.z;
            Qt[d0 + 4*u + 3][qr] = v4.w;
        }
    }

    float mA[4], lA[4], oA[4][4], mI[4], lI[4], oI[4][4];
#pragma unroll
    for (int j = 0; j < 4; ++j) { mA[j] = NEG_BIG; lA[j] = 0.f; mI[j] = NEG_BIG; lI[j] = 0.f; }
#pragma unroll
    for (int i = 0; i < 4; ++i)
#pragma unroll
        for (int j = 0; j < 4; ++j) { oA[i][j] = 0.f; oI[i][j] = 0.f; }

    for (int t = 0; t < TK_ / SPLIT / KT; ++t) {
        const int jb = ks0 + t * KT;
        __syncthreads();
        {
            int kr = tid & 63, d0 = (tid >> 6) << 4;
            const float* kp = K + (size_t)(b * TK_ + jb + kr) * D_ + h * HD_ + d0;
            const float* vp = V + (size_t)(b * TK_ + jb + kr) * D_ + h * HD_ + d0;
#pragma unroll
            for (int u = 0; u < 4; ++u) {
                float4 k4 = *(const float4*)(kp + 4 * u);
                KPt[d0 + 4*u + 0][kr] = k4.x;
                KPt[d0 + 4*u + 1][kr] = k4.y;
                KPt[d0 + 4*u + 2][kr] = k4.z;
                KPt[d0 + 4*u + 3][kr] = k4.w;
                float4 v4 = *(const float4*)(vp + 4 * u);
                *(float4*)&Vb[kr][d0 + 4*u] = v4;
            }
        }
        __syncthreads();

        float sT[4][4] = {};
#pragma unroll 8
        for (int d = 0; d < HD_; ++d) {
            float4 ka = *(const float4*)&KPt[d][kx];
            float4 qa = *(const float4*)&Qt[d][qcol];
            float kk4[4] = {ka.x, ka.y, ka.z, ka.w};
            float qq4[4] = {qa.x, qa.y, qa.z, qa.w};
#pragma unroll
            for (int i = 0; i < 4; ++i)
#pragma unroll
                for (int j = 0; j < 4; ++j)
                    sT[i][j] = fmaf(kk4[i], qq4[j], sT[i][j]);
        }

        const bool hasA = (jb < Na);
        const bool hasI = (jb + KT > Na);
        if (hasA) {
            bool rin[4];
#pragma unroll
            for (int i = 0; i < 4; ++i) rin[i] = (jb + kx + i) < Na;
            attn_group(sT, rin, mA, lA, oA, KPt, Vb, qcol, kx);
        }
        if (hasI) {
            bool rin[4];
#pragma unroll
            for (int i = 0; i < 4; ++i) rin[i] = (jb + kx + i) >= Na;
            attn_group(sT, rin, mI, lI, oI, KPt, Vb, qcol, kx);
        }
    }

    const size_t baseA = ((size_t)((s * 2 + 0) * (B_ * NH_) + bh)) * TQ_;
    const size_t baseI = ((size_t)((s * 2 + 1) * (B_ * NH_) + bh)) * TQ_;
#pragma unroll
    for (int i = 0; i < 4; ++i) {
        int q = q0 + qcol + i;
        *(float4*)&pO[(baseA + q) * HD_ + kx] = make_float4(oA[i][0], oA[i][1], oA[i][2], oA[i][3]);
        *(float4*)&pO[(baseI + q) * HD_ + kx] = make_float4(oI[i][0], oI[i][1], oI[i][2], oI[i][3]);
    }
    if ((l & 15) == 0) {
#pragma unroll
        for (int j = 0; j < 4; ++j) {
            int q = q0 + qcol + j;
            pM[baseA + q] = mA[j]; pL[baseA + q] = lA[j];
            pM[baseI + q] = mI[j]; pL[baseI + q] = lI[j];
        }
    }
}

// ---------------- split-K merge ----------------
__global__ __launch_bounds__(256)
void sdpca_combine(const float* __restrict__ pO, const float* __restrict__ pM,
                   const float* __restrict__ pL, const int* __restrict__ nactp,
                   float* __restrict__ Ao)
{
    int idx = blockIdx.x * 256 + threadIdx.x;
    int d   = idx & (HD_ - 1);
    int q   = (idx >> 6) & (TQ_ - 1);
    int bh  = idx >> 15;
    int b   = bh >> 4, h = bh & 15;
    int Na  = *nactp;
    int Ni  = TK_ - Na;

    float res = 0.f;
#pragma unroll
    for (int g = 0; g < 2; ++g) {
        size_t i0 = ((size_t)((0 * 2 + g) * (B_ * NH_) + bh)) * TQ_ + q;
        size_t i1 = ((size_t)((1 * 2 + g) * (B_ * NH_) + bh)) * TQ_ + q;
        float m0 = pM[i0], m1 = pM[i1];
        float l0 = pL[i0], l1 = pL[i1];
        float o0 = pO[i0 * HD_ + d], o1 = pO[i1 * HD_ + d];
        float M  = fmaxf(m0, m1);
        float w0 = __expf(m0 - M), w1 = __expf(m1 - M);
        float L  = l0 * w0 + l1 * w1;
        float O  = o0 * w0 + o1 * w1;
        float r  = (L > 0.f) ? (O / L) : 0.f;
        int   cnt = (g == 0) ? Na : Ni;
        float sc  = (cnt > 0) ? rsqrtf((float)cnt) : 0.f;
        res += (g == 0) ? (sc * r) : (-sc * r);
    }
    Ao[((size_t)(b * TQ_ + q)) * D_ + h * HD_ + d] = res;
}

// ---------------- output projection ----------------
__global__ __launch_bounds__(256)
void sdpca_gemm_o(const float* __restrict__ A, const float* __restrict__ W,
                  const float* __restrict__ bias, float* __restrict__ C)
{
    __shared__ float As[BKT][LDP];
    __shared__ float Ws[BKT][LDP];
    const int tid  = threadIdx.x;
    const int brow = blockIdx.y * BM;
    const int bcol = blockIdx.x * BN;
    const int tr   = (tid >> 4) << 2;
    const int tc   = (tid & 15) << 2;

    float acc[4][4] = {};
    for (int k0 = 0; k0 < D_; k0 += BKT) {
#pragma unroll
        for (int i = 0; i < 2; ++i) {
            int idx = (i << 8) + tid;
            int r   = idx >> 3;
            int c   = (idx & 7) << 2;
            float4 av = *(const float4*)(A + (size_t)(brow + r) * D_ + (k0 + c));
            As[c + 0][r] = av.x; As[c + 1][r] = av.y; As[c + 2][r] = av.z; As[c + 3][r] = av.w;
            float4 wv = *(const float4*)(W + (size_t)(bcol + r) * D_ + (k0 + c));
            Ws[c + 0][r] = wv.x; Ws[c + 1][r] = wv.y; Ws[c + 2][r] = wv.z; Ws[c + 3][r] = wv.w;
        }
        __syncthreads();
#pragma unroll
        for (int kk = 0; kk < BKT; ++kk) {
            float4 a = *(const float4*)&As[kk][tr];
            float4 w = *(const float4*)&Ws[kk][tc];
            float aa[4] = {a.x, a.y, a.z, a.w};
            float ww[4] = {w.x, w.y, w.z, w.w};
#pragma unroll
            for (int i2 = 0; i2 < 4; ++i2)
#pragma unroll
                for (int j2 = 0; j2 < 4; ++j2)
                    acc[i2][j2] = fmaf(aa[i2], ww[j2], acc[i2][j2]);
        }
        __syncthreads();
    }

#pragma unroll
    for (int i = 0; i < 4; ++i) {
        int r = brow + tr + i;
        float4 bv = *(const float4*)(bias + bcol + tc);
        float4 o;
        o.x = acc[i][0] + bv.x; o.y = acc[i][1] + bv.y;
        o.z = acc[i][2] + bv.z; o.w = acc[i][3] + bv.w;
        *(float4*)(C + (size_t)r * D_ + bcol + tc) = o;
    }
}

extern "C" void kernel_launch(void* const* d_in, const int* in_sizes, int n_in,
                              void* d_out, int out_size, void* d_ws, size_t ws_size,
                              hipStream_t stream) {
    (void)in_sizes; (void)n_in; (void)out_size; (void)ws_size;
    const float* q   = (const float*)d_in[0];
    const float* kv  = (const float*)d_in[1];
    const float* Wq  = (const float*)d_in[2];
    const float* bq  = (const float*)d_in[3];
    const float* Wk  = (const float*)d_in[4];
    const float* bk  = (const float*)d_in[5];
    const float* Wv  = (const float*)d_in[6];
    const float* bv  = (const float*)d_in[7];
    const float* Wo  = (const float*)d_in[8];
    const float* bo  = (const float*)d_in[9];
    const float* ab  = (const float*)d_in[10];
    const float* ib  = (const float*)d_in[11];
    const float* lt  = (const float*)d_in[12];
    const int*   na  = (const int*)d_in[13];

    float* ws = (float*)d_ws;
    const size_t nQ  = (size_t)B_ * TQ_ * D_;    // 1,048,576
    const size_t nKV = (size_t)B_ * TK_ * D_;    // 16,777,216
    const size_t nW  = (size_t)D_ * D_;          // 1,048,576
    const size_t nML = (size_t)SPLIT * 2 * B_ * NH_ * TQ_;

    float* Qp = ws;                              // 4 MB
    float* Kp = Qp + nQ;                         // 67 MB
    float* Vp = Kp + nKV;                        // 67 MB
    unsigned short* Ah  = (unsigned short*)(Vp + nKV);   // 33.5 MB
    unsigned short* Al  = Ah + nKV;                      // 33.5 MB
    unsigned short* Whk = Al + nKV;                      // 2 MB x4
    unsigned short* Wlk = Whk + nW;
    unsigned short* Whv = Wlk + nW;
    unsigned short* Wlv = Whv + nW;
    // Ah/Al dead after the MFMA GEMM -> reuse for attention partials
    float* pO = (float*)Ah;                      // 4*nQ floats (16.8 MB)
    float* pM = pO + (size_t)SPLIT * 2 * nQ;
    float* pL = pM + nML;
    float* Ao = Qp;                              // reuse after attention

    dim3 blk(256);
    sdpca_gemm_q      <<<dim3(D_ / BN, (B_ * TQ_) / BM), blk, 0, stream>>>(q, Wq, bq, lt, Qp);
    split_kv          <<<dim3((int)(nKV / 8 / 256)),     blk, 0, stream>>>(kv, ab, ib, na, Ah, Al);
    split_w           <<<dim3((int)(nW / 8 / 256)),      blk, 0, stream>>>(Wk, Whk, Wlk);
    split_w           <<<dim3((int)(nW / 8 / 256)),      blk, 0, stream>>>(Wv, Whv, Wlv);
    sdpca_gemm_kv_mfma<<<dim3(D_ / 128, (B_ * TK_) / 128, 2), blk, 0, stream>>>(
        Ah, Al, Whk, Wlk, Whv, Wlv, bk, bv, Kp, Vp);
    sdpca_attn        <<<dim3(TQ_ / QT, B_ * NH_, SPLIT), blk, 0, stream>>>(Qp, Kp, Vp, na, pO, pM, pL);
    sdpca_combine     <<<dim3((B_ * TQ_ * D_) / 256),     blk, 0, stream>>>(pO, pM, pL, na, Ao);
    sdpca_gemm_o      <<<dim3(D_ / BN, (B_ * TQ_) / BM),  blk, 0, stream>>>(Ao, Wo, bo, (float*)d_out);
}

// Round 4
// 489.509 us; speedup vs baseline: 6.2934x; 1.8567x over previous
//
#include <hip/hip_runtime.h>
#include <math.h>
#include <stdint.h>

#define B_   2
#define TQ_  512
#define TK_  8192
#define D_   1024
#define NH_  16
#define HD_  64

#define NEG_BIG (-3.0e38f)
#define ASPLIT 4

typedef __attribute__((ext_vector_type(8))) short short8;
typedef __attribute__((ext_vector_type(4))) float f32x4;

// ---------------- bf16 helpers (RNE) ----------------
__device__ __forceinline__ unsigned short f2bf(float x) {
    unsigned u = __float_as_uint(x);
    unsigned r = u + 0x7FFFu + ((u >> 16) & 1u);
    return (unsigned short)(r >> 16);
}
__device__ __forceinline__ float bf2f(unsigned short h) {
    return __uint_as_float(((unsigned)h) << 16);
}

#define GLD16(gp, lp)                                                              \
    __builtin_amdgcn_global_load_lds(                                              \
        (const __attribute__((address_space(1))) unsigned int*)(gp),               \
        (__attribute__((address_space(3))) unsigned int*)(lp), 16, 0, 0)

// ---------------- fp32 GEMM config (q/o projections) ----------------
#define BM   64
#define BN   64
#define BKT  32
#define LDP  68

// ---------------- Q projection: Qb = bf16((A @ Wq^T + bq) * 1/(64*temp)) ----------------
__global__ __launch_bounds__(256)
void sdpca_gemm_q(const float* __restrict__ A, const float* __restrict__ W,
                  const float* __restrict__ bias, const float* __restrict__ log_temp,
                  unsigned short* __restrict__ Qb)
{
    __shared__ float As[BKT][LDP];
    __shared__ float Ws[BKT][LDP];
    const int tid  = threadIdx.x;
    const int brow = blockIdx.y * BM;
    const int bcol = blockIdx.x * BN;
    const int tr   = (tid >> 4) << 2;
    const int tc   = (tid & 15) << 2;

    float acc[4][4] = {};
    for (int k0 = 0; k0 < D_; k0 += BKT) {
#pragma unroll
        for (int i = 0; i < 2; ++i) {
            int idx = (i << 8) + tid;
            int r   = idx >> 3;
            int c   = (idx & 7) << 2;
            float4 av = *(const float4*)(A + (size_t)(brow + r) * D_ + (k0 + c));
            As[c + 0][r] = av.x; As[c + 1][r] = av.y; As[c + 2][r] = av.z; As[c + 3][r] = av.w;
            float4 wv = *(const float4*)(W + (size_t)(bcol + r) * D_ + (k0 + c));
            Ws[c + 0][r] = wv.x; Ws[c + 1][r] = wv.y; Ws[c + 2][r] = wv.z; Ws[c + 3][r] = wv.w;
        }
        __syncthreads();
#pragma unroll
        for (int kk = 0; kk < BKT; ++kk) {
            float4 a = *(const float4*)&As[kk][tr];
            float4 w = *(const float4*)&Ws[kk][tc];
            float aa[4] = {a.x, a.y, a.z, a.w};
            float ww[4] = {w.x, w.y, w.z, w.w};
#pragma unroll
            for (int i2 = 0; i2 < 4; ++i2)
#pragma unroll
                for (int j2 = 0; j2 < 4; ++j2)
                    acc[i2][j2] = fmaf(aa[i2], ww[j2], acc[i2][j2]);
        }
        __syncthreads();
    }

    float lt    = *log_temp;
    float temp  = fminf(fmaxf(expf(lt), 0.1f), 10.0f);
    float scale = 1.0f / (64.0f * temp);

#pragma unroll
    for (int i = 0; i < 4; ++i) {
        int r = brow + tr + i;
        float4 bv = *(const float4*)(bias + bcol + tc);
        ushort4 o;
        o.x = f2bf((acc[i][0] + bv.x) * scale);
        o.y = f2bf((acc[i][1] + bv.y) * scale);
        o.z = f2bf((acc[i][2] + bv.z) * scale);
        o.w = f2bf((acc[i][3] + bv.w) * scale);
        *(ushort4*)(Qb + (size_t)r * D_ + bcol + tc) = o;
    }
}

// ---------------- hi/lo bf16 split of (kv + group bias) ----------------
__global__ __launch_bounds__(256)
void split_kv(const float* __restrict__ kv, const float* __restrict__ ab,
              const float* __restrict__ ib, const int* __restrict__ nactp,
              unsigned short* __restrict__ Ah, unsigned short* __restrict__ Al)
{
    const int Na = *nactp;
    size_t i = ((size_t)blockIdx.x * 256 + threadIdx.x) * 8;
    int row = (int)(i >> 10);
    int col = (int)(i & (D_ - 1));
    const float* bp = ((row & (TK_ - 1)) < Na) ? ab : ib;
    float4 x0 = *(const float4*)(kv + i);
    float4 x1 = *(const float4*)(kv + i + 4);
    float4 b0 = *(const float4*)(bp + col);
    float4 b1 = *(const float4*)(bp + col + 4);
    float a[8] = {x0.x + b0.x, x0.y + b0.y, x0.z + b0.z, x0.w + b0.w,
                  x1.x + b1.x, x1.y + b1.y, x1.z + b1.z, x1.w + b1.w};
    union { short8 v; unsigned short u[8]; } H, L;
#pragma unroll
    for (int j = 0; j < 8; ++j) {
        unsigned short h = f2bf(a[j]);
        H.u[j] = h;
        L.u[j] = f2bf(a[j] - bf2f(h));
    }
    *(short8*)(Ah + i) = H.v;
    *(short8*)(Al + i) = L.v;
}

// ---------------- hi/lo bf16 split of a weight matrix ----------------
__global__ __launch_bounds__(256)
void split_w(const float* __restrict__ W,
             unsigned short* __restrict__ Wh, unsigned short* __restrict__ Wl)
{
    size_t i = ((size_t)blockIdx.x * 256 + threadIdx.x) * 8;
    float4 x0 = *(const float4*)(W + i);
    float4 x1 = *(const float4*)(W + i + 4);
    float a[8] = {x0.x, x0.y, x0.z, x0.w, x1.x, x1.y, x1.z, x1.w};
    union { short8 v; unsigned short u[8]; } H, L;
#pragma unroll
    for (int j = 0; j < 8; ++j) {
        unsigned short h = f2bf(a[j]);
        H.u[j] = h;
        L.u[j] = f2bf(a[j] - bf2f(h));
    }
    *(short8*)(Wh + i) = H.v;
    *(short8*)(Wl + i) = L.v;
}

// ---------------- K/V projection via bf16x3 MFMA, bf16 output ----------------
__global__ __launch_bounds__(256)
void sdpca_gemm_kv_mfma(const unsigned short* __restrict__ Ah, const unsigned short* __restrict__ Al,
                        const unsigned short* __restrict__ Whk, const unsigned short* __restrict__ Wlk,
                        const unsigned short* __restrict__ Whv, const unsigned short* __restrict__ Wlv,
                        const float* __restrict__ bk, const float* __restrict__ bv,
                        unsigned short* __restrict__ Kb, unsigned short* __restrict__ Vb)
{
    __shared__ unsigned short AhT[128 * 32];
    __shared__ unsigned short AlT[128 * 32];
    __shared__ unsigned short BhT[128 * 32];
    __shared__ unsigned short BlT[128 * 32];

    const int tid  = threadIdx.x;
    const int lane = tid & 63;
    const int w    = tid >> 6;
    const int brow = blockIdx.y * 128;
    const int bcol = blockIdx.x * 128;

    const unsigned short* Wh; const unsigned short* Wl; const float* bias; unsigned short* C;
    if (blockIdx.z == 0) { Wh = Whk; Wl = Wlk; bias = bk; C = Kb; }
    else                 { Wh = Whv; Wl = Wlv; bias = bv; C = Vb; }

    const int wr = w >> 1, wc = w & 1;

    const int   srow = lane >> 2;
    const int   scol = (lane & 3) * 8;
    const size_t gA0 = (size_t)(brow + w * 32 + srow) * D_ + scol;
    const size_t gA1 = gA0 + (size_t)16 * D_;
    const size_t gB0 = (size_t)(bcol + w * 32 + srow) * D_ + scol;
    const size_t gB1 = gB0 + (size_t)16 * D_;
    const int   l0   = (w * 32 +  0) * 32;
    const int   l1   = (w * 32 + 16) * 32;

    f32x4 acc[4][4];
#pragma unroll
    for (int m = 0; m < 4; ++m)
#pragma unroll
        for (int n = 0; n < 4; ++n) acc[m][n] = (f32x4){0.f, 0.f, 0.f, 0.f};

    const int frow = lane & 15;
    const int fko  = (lane >> 4) * 8;

    for (int k0 = 0; k0 < D_; k0 += 32) {
        GLD16(Ah + gA0 + k0, &AhT[l0]);
        GLD16(Ah + gA1 + k0, &AhT[l1]);
        GLD16(Al + gA0 + k0, &AlT[l0]);
        GLD16(Al + gA1 + k0, &AlT[l1]);
        GLD16(Wh + gB0 + k0, &BhT[l0]);
        GLD16(Wh + gB1 + k0, &BhT[l1]);
        GLD16(Wl + gB0 + k0, &BlT[l0]);
        GLD16(Wl + gB1 + k0, &BlT[l1]);
        __syncthreads();

        short8 bh[4], bl[4];
#pragma unroll
        for (int n = 0; n < 4; ++n) {
            int r = wc * 64 + n * 16 + frow;
            bh[n] = *(const short8*)&BhT[r * 32 + fko];
            bl[n] = *(const short8*)&BlT[r * 32 + fko];
        }
#pragma unroll
        for (int m = 0; m < 4; ++m) {
            int r = wr * 64 + m * 16 + frow;
            short8 amh = *(const short8*)&AhT[r * 32 + fko];
            short8 aml = *(const short8*)&AlT[r * 32 + fko];
#pragma unroll
            for (int n = 0; n < 4; ++n) {
                acc[m][n] = __builtin_amdgcn_mfma_f32_16x16x32_bf16(amh, bh[n], acc[m][n], 0, 0, 0);
                acc[m][n] = __builtin_amdgcn_mfma_f32_16x16x32_bf16(amh, bl[n], acc[m][n], 0, 0, 0);
                acc[m][n] = __builtin_amdgcn_mfma_f32_16x16x32_bf16(aml, bh[n], acc[m][n], 0, 0, 0);
            }
        }
        __syncthreads();
    }

#pragma unroll
    for (int n = 0; n < 4; ++n) {
        int col = bcol + wc * 64 + n * 16 + frow;
        float bsv = bias[col];
#pragma unroll
        for (int m = 0; m < 4; ++m) {
            int rbase = brow + wr * 64 + m * 16 + (lane >> 4) * 4;
#pragma unroll
            for (int r = 0; r < 4; ++r)
                C[(size_t)(rbase + r) * D_ + col] = f2bf(acc[m][n][r] + bsv);
        }
    }
}

// ---------------- V transpose: Vb[b*TK+t][h*64+d] -> Vt[(bh*64+d)][t] ----------------
__global__ __launch_bounds__(256)
void transpose_v(const unsigned short* __restrict__ Vb, unsigned short* __restrict__ Vt)
{
    __shared__ unsigned short T[64][72];
    const int tid = threadIdx.x;
    const int t0  = blockIdx.x * 64;
    const int bh  = blockIdx.y, b = bh >> 4, h = bh & 15;
    {
        int tok = tid >> 2, dc = (tid & 3) * 16;
        const unsigned short* src = Vb + (size_t)(b * TK_ + t0 + tok) * D_ + h * HD_ + dc;
        *(short8*)&T[tok][dc]     = *(const short8*)(src);
        *(short8*)&T[tok][dc + 8] = *(const short8*)(src + 8);
    }
    __syncthreads();
    {
        int d = tid >> 2, tc = (tid & 3) * 16;
        unsigned short* dst = Vt + ((size_t)bh * HD_ + d) * TK_ + t0 + tc;
        union { short8 v; unsigned short u[8]; } o0, o1;
#pragma unroll
        for (int j = 0; j < 8; ++j) { o0.u[j] = T[tc + j][d]; o1.u[j] = T[tc + 8 + j][d]; }
        *(short8*)(dst)     = o0.v;
        *(short8*)(dst + 8) = o1.v;
    }
}

// ---------------- MFMA flash attention, two groups, split-K ----------------
// grid (TQ/64, B*NH, ASPLIT), block 256 = 4 waves. Wave w owns q-cols w*16..+16.
// S^T = mfma(K, Q): acc col = q (lane&15), row = key. Softmax state per-lane scalar.
// P -> bf16 -> wave-private LDS rows; PV: O^T = mfma(V^T, P) accumulated in regs.
__device__ __forceinline__ void attn_pass(
    const f32x4 st[4], int jb, int lo, int hi,
    float& mst, float& lst, f32x4 o[4],
    unsigned short* Ps, const unsigned short* Vs,
    int frow, int g, int w)
{
    const int q = w * 16 + frow;
    float pmax = NEG_BIG;
#pragma unroll
    for (int mt = 0; mt < 4; ++mt)
#pragma unroll
        for (int r = 0; r < 4; ++r) {
            int key = jb + mt * 16 + g * 4 + r;
            if (key >= lo && key < hi) pmax = fmaxf(pmax, st[mt][r]);
        }
    pmax = fmaxf(pmax, __shfl_xor(pmax, 16, 64));
    pmax = fmaxf(pmax, __shfl_xor(pmax, 32, 64));
    const float mnew = fmaxf(mst, pmax);
    const float corr = __expf(mst - mnew);

    float p[4][4];
    float psum = 0.f;
#pragma unroll
    for (int mt = 0; mt < 4; ++mt)
#pragma unroll
        for (int r = 0; r < 4; ++r) {
            int key = jb + mt * 16 + g * 4 + r;
            float pv = (key >= lo && key < hi) ? __expf(st[mt][r] - mnew) : 0.f;
            p[mt][r] = pv; psum += pv;
        }
    psum += __shfl_xor(psum, 16, 64);
    psum += __shfl_xor(psum, 32, 64);
    lst = lst * corr + psum;
    mst = mnew;
#pragma unroll
    for (int mt = 0; mt < 4; ++mt) {
        o[mt][0] *= corr; o[mt][1] *= corr; o[mt][2] *= corr; o[mt][3] *= corr;
    }
    // write P row q (wave-private), keys mt*16+g*4..+4, packed bf16
#pragma unroll
    for (int mt = 0; mt < 4; ++mt) {
        unsigned u0 = (unsigned)f2bf(p[mt][0]) | ((unsigned)f2bf(p[mt][1]) << 16);
        unsigned u1 = (unsigned)f2bf(p[mt][2]) | ((unsigned)f2bf(p[mt][3]) << 16);
        unsigned* dst = (unsigned*)((char*)Ps + q * 144 + (mt * 16 + g * 4) * 2);
        dst[0] = u0; dst[1] = u1;
    }
    __builtin_amdgcn_sched_barrier(0);   // keep PV reads after P writes
    // PV: O^T[d][q] += V^T[d][keys] * P[q][keys]^T
#pragma unroll
    for (int mt = 0; mt < 4; ++mt) {
        int row = mt * 16 + frow;
        int rs  = (row & 7) << 4;
#pragma unroll
        for (int ks = 0; ks < 2; ++ks) {
            short8 a = *(const short8*)((const char*)Vs + row * 128 + ((ks * 64 + g * 16) ^ rs));
            short8 bfr = *(const short8*)((const char*)Ps + q * 144 + ks * 64 + g * 16);
            o[mt] = __builtin_amdgcn_mfma_f32_16x16x32_bf16(a, bfr, o[mt], 0, 0, 0);
        }
    }
}

__global__ __launch_bounds__(256)
void sdpca_attn_mfma(const unsigned short* __restrict__ Qb,
                     const unsigned short* __restrict__ Kb,
                     const unsigned short* __restrict__ Vt,
                     const int* __restrict__ nactp,
                     float* __restrict__ pO, float* __restrict__ pM, float* __restrict__ pL)
{
    __shared__ char smem[25600];
    unsigned short* Ks = (unsigned short*)smem;            // [64][64] bf16, XOR-swizzled rows
    unsigned short* Vs = (unsigned short*)(smem + 8192);   // [64 d][64 keys] bf16, swizzled
    unsigned short* Ps = (unsigned short*)(smem + 16384);  // [64 q][72 keys] bf16
    float*          Ot = (float*)smem;                     // epilogue alias [64 q][68 d] fp32

    const int tid  = threadIdx.x;
    const int l    = tid & 63, w = tid >> 6;
    const int frow = l & 15,  g = l >> 4;
    const int bh   = blockIdx.y, b = bh >> 4, h = bh & 15;
    const int q0   = blockIdx.x * 64;
    const int s    = blockIdx.z;
    const int Na   = *nactp;
    const int ks0  = s * (TK_ / ASPLIT);
    const int nt   = TK_ / ASPLIT / 64;

    // Q b-fragments straight from global (fixed per block)
    short8 qf0, qf1;
    {
        const unsigned short* qp = Qb + (size_t)(b * TQ_ + q0 + w * 16 + frow) * D_ + h * HD_;
        qf0 = *(const short8*)(qp + g * 8);
        qf1 = *(const short8*)(qp + 32 + g * 8);
    }

    float mA = NEG_BIG, lA = 0.f, mI = NEG_BIG, lI = 0.f;
    f32x4 oA[4], oI[4];
#pragma unroll
    for (int mt = 0; mt < 4; ++mt) {
        oA[mt] = (f32x4){0.f, 0.f, 0.f, 0.f};
        oI[mt] = (f32x4){0.f, 0.f, 0.f, 0.f};
    }

    // staging: thread -> (row tid>>2, 32B chunk (tid&3)*32), swizzled write
    const int srow = tid >> 2;
    const int scb  = (tid & 3) * 32;
    const unsigned short* kg = Kb + (size_t)(b * TK_ + ks0 + srow) * D_ + h * HD_ + (tid & 3) * 16;
    const unsigned short* vg = Vt + ((size_t)bh * HD_ + srow) * TK_ + ks0 + (tid & 3) * 16;
    const int kswz0 = srow * 128 + ((scb +  0) ^ ((srow & 7) << 4));
    const int kswz1 = srow * 128 + ((scb + 16) ^ ((srow & 7) << 4));

    for (int t = 0; t < nt; ++t) {
        const int jb = ks0 + t * 64;
        short8 kr0 = *(const short8*)(kg);
        short8 kr1 = *(const short8*)(kg + 8);
        short8 vr0 = *(const short8*)(vg);
        short8 vr1 = *(const short8*)(vg + 8);
        kg += (size_t)64 * D_;
        vg += 64;
        __syncthreads();                      // previous tile fully consumed
        *(short8*)((char*)Ks + kswz0) = kr0;
        *(short8*)((char*)Ks + kswz1) = kr1;
        *(short8*)((char*)Vs + kswz0) = vr0;
        *(short8*)((char*)Vs + kswz1) = vr1;
        __syncthreads();

        // scores S^T: rows keys (4 tiles), cols q
        f32x4 st[4];
#pragma unroll
        for (int mt = 0; mt < 4; ++mt) {
            int row = mt * 16 + frow;
            int rs  = (row & 7) << 4;
            short8 a0 = *(const short8*)((const char*)Ks + row * 128 + ((g * 16) ^ rs));
            short8 a1 = *(const short8*)((const char*)Ks + row * 128 + ((64 + g * 16) ^ rs));
            f32x4 acc = (f32x4){0.f, 0.f, 0.f, 0.f};
            acc = __builtin_amdgcn_mfma_f32_16x16x32_bf16(a0, qf0, acc, 0, 0, 0);
            acc = __builtin_amdgcn_mfma_f32_16x16x32_bf16(a1, qf1, acc, 0, 0, 0);
            st[mt] = acc;
        }

        const bool hasA = (jb < Na);
        const bool hasI = (jb + 64 > Na);
        if (hasA) attn_pass(st, jb, 0,  Na,  mA, lA, oA, Ps, Vs, frow, g, w);
        if (hasI) attn_pass(st, jb, Na, TK_, mI, lI, oI, Ps, Vs, frow, g, w);
    }

    // epilogue: transpose O^T -> O via LDS, write partials
    const int q = w * 16 + frow;
#pragma unroll
    for (int grp = 0; grp < 2; ++grp) {
        __syncthreads();
        const f32x4* o = grp ? oI : oA;
#pragma unroll
        for (int mt = 0; mt < 4; ++mt)
            *(f32x4*)&Ot[q * 68 + mt * 16 + g * 4] = o[mt];
        if (g == 0) {
            size_t base = ((size_t)((s * 2 + grp) * (B_ * NH_) + bh)) * TQ_ + q0 + q;
            pM[base] = grp ? mI : mA;
            pL[base] = grp ? lI : lA;
        }
        __syncthreads();
        {
            int qr = tid >> 2, dc = (tid & 3) * 16;
            size_t rowbase = ((size_t)((s * 2 + grp) * (B_ * NH_) + bh)) * TQ_ + q0 + qr;
            float* dst = pO + rowbase * HD_ + dc;
#pragma unroll
            for (int u = 0; u < 4; ++u)
                *(float4*)(dst + 4 * u) = *(const float4*)&Ot[qr * 68 + dc + 4 * u];
        }
    }
}

// ---------------- split-K merge over ASPLIT partials ----------------
__global__ __launch_bounds__(256)
void sdpca_combine(const float* __restrict__ pO, const float* __restrict__ pM,
                   const float* __restrict__ pL, const int* __restrict__ nactp,
                   float* __restrict__ Ao)
{
    int idx = blockIdx.x * 256 + threadIdx.x;
    int d   = idx & (HD_ - 1);
    int q   = (idx >> 6) & (TQ_ - 1);
    int bh  = idx >> 15;
    int b   = bh >> 4, h = bh & 15;
    int Na  = *nactp;
    int Ni  = TK_ - Na;

    float res = 0.f;
#pragma unroll
    for (int gg = 0; gg < 2; ++gg) {
        float M = NEG_BIG;
#pragma unroll
        for (int ss = 0; ss < ASPLIT; ++ss) {
            size_t ii = ((size_t)((ss * 2 + gg) * (B_ * NH_) + bh)) * TQ_ + q;
            M = fmaxf(M, pM[ii]);
        }
        float L = 0.f, O = 0.f;
#pragma unroll
        for (int ss = 0; ss < ASPLIT; ++ss) {
            size_t ii = ((size_t)((ss * 2 + gg) * (B_ * NH_) + bh)) * TQ_ + q;
            float ww = __expf(pM[ii] - M);
            L += pL[ii] * ww;
            O += pO[ii * HD_ + d] * ww;
        }
        float r   = (L > 0.f) ? (O / L) : 0.f;
        int   cnt = (gg == 0) ? Na : Ni;
        float sc  = (cnt > 0) ? rsqrtf((float)cnt) : 0.f;
        res += (gg == 0) ? (sc * r) : (-sc * r);
    }
    Ao[((size_t)(b * TQ_ + q)) * D_ + h * HD_ + d] = res;
}

// ---------------- output projection ----------------
__global__ __launch_bounds__(256)
void sdpca_gemm_o(const float* __restrict__ A, const float* __restrict__ W,
                  const float* __restrict__ bias, float* __restrict__ C)
{
    __shared__ float As[BKT][LDP];
    __shared__ float Ws[BKT][LDP];
    const int tid  = threadIdx.x;
    const int brow = blockIdx.y * BM;
    const int bcol = blockIdx.x * BN;
    const int tr   = (tid >> 4) << 2;
    const int tc   = (tid & 15) << 2;

    float acc[4][4] = {};
    for (int k0 = 0; k0 < D_; k0 += BKT) {
#pragma unroll
        for (int i = 0; i < 2; ++i) {
            int idx = (i << 8) + tid;
            int r   = idx >> 3;
            int c   = (idx & 7) << 2;
            float4 av = *(const float4*)(A + (size_t)(brow + r) * D_ + (k0 + c));
            As[c + 0][r] = av.x; As[c + 1][r] = av.y; As[c + 2][r] = av.z; As[c + 3][r] = av.w;
            float4 wv = *(const float4*)(W + (size_t)(bcol + r) * D_ + (k0 + c));
            Ws[c + 0][r] = wv.x; Ws[c + 1][r] = wv.y; Ws[c + 2][r] = wv.z; Ws[c + 3][r] = wv.w;
        }
        __syncthreads();
#pragma unroll
        for (int kk = 0; kk < BKT; ++kk) {
            float4 a = *(const float4*)&As[kk][tr];
            float4 w = *(const float4*)&Ws[kk][tc];
            float aa[4] = {a.x, a.y, a.z, a.w};
            float ww[4] = {w.x, w.y, w.z, w.w};
#pragma unroll
            for (int i2 = 0; i2 < 4; ++i2)
#pragma unroll
                for (int j2 = 0; j2 < 4; ++j2)
                    acc[i2][j2] = fmaf(aa[i2], ww[j2], acc[i2][j2]);
        }
        __syncthreads();
    }

#pragma unroll
    for (int i = 0; i < 4; ++i) {
        int r = brow + tr + i;
        float4 bv = *(const float4*)(bias + bcol + tc);
        float4 o;
        o.x = acc[i][0] + bv.x; o.y = acc[i][1] + bv.y;
        o.z = acc[i][2] + bv.z; o.w = acc[i][3] + bv.w;
        *(float4*)(C + (size_t)r * D_ + bcol + tc) = o;
    }
}

extern "C" void kernel_launch(void* const* d_in, const int* in_sizes, int n_in,
                              void* d_out, int out_size, void* d_ws, size_t ws_size,
                              hipStream_t stream) {
    (void)in_sizes; (void)n_in; (void)out_size; (void)ws_size;
    const float* q   = (const float*)d_in[0];
    const float* kv  = (const float*)d_in[1];
    const float* Wq  = (const float*)d_in[2];
    const float* bq  = (const float*)d_in[3];
    const float* Wk  = (const float*)d_in[4];
    const float* bk  = (const float*)d_in[5];
    const float* Wv  = (const float*)d_in[6];
    const float* bv  = (const float*)d_in[7];
    const float* Wo  = (const float*)d_in[8];
    const float* bo  = (const float*)d_in[9];
    const float* ab  = (const float*)d_in[10];
    const float* ib  = (const float*)d_in[11];
    const float* lt  = (const float*)d_in[12];
    const int*   na  = (const int*)d_in[13];

    char* ws = (char*)d_ws;
    const size_t nQ  = (size_t)B_ * TQ_ * D_;    // 1,048,576
    const size_t nKV = (size_t)B_ * TK_ * D_;    // 16,777,216
    const size_t nW  = (size_t)D_ * D_;          // 1,048,576
    const size_t nML = (size_t)ASPLIT * 2 * B_ * NH_ * TQ_;  // 131,072

    unsigned short* Ah  = (unsigned short*)ws;                 // 33.5 MB
    unsigned short* Al  = Ah + nKV;                            // 33.5 MB
    unsigned short* Whk = Al + nKV;                            // 2 MB x4
    unsigned short* Wlk = Whk + nW;
    unsigned short* Whv = Wlk + nW;
    unsigned short* Wlv = Whv + nW;
    unsigned short* Kb  = Wlv + nW;                            // 33.5 MB
    unsigned short* Vb  = Kb + nKV;                            // 33.5 MB
    unsigned short* Vt  = Vb + nKV;                            // 33.5 MB
    unsigned short* Qb  = Vt + nKV;                            // 2 MB
    // aliases (dead regions):
    float* pO = (float*)Ah;                                    // ASPLIT*2*nQ fp32 = 33.5 MB
    float* pM = (float*)Al;
    float* pL = pM + nML;
    float* Ao = pL + nML;                                      // 4 MB, still inside Al region

    dim3 blk(256);
    sdpca_gemm_q      <<<dim3(D_ / BN, (B_ * TQ_) / BM), blk, 0, stream>>>(q, Wq, bq, lt, Qb);
    split_kv          <<<dim3((int)(nKV / 8 / 256)),     blk, 0, stream>>>(kv, ab, ib, na, Ah, Al);
    split_w           <<<dim3((int)(nW / 8 / 256)),      blk, 0, stream>>>(Wk, Whk, Wlk);
    split_w           <<<dim3((int)(nW / 8 / 256)),      blk, 0, stream>>>(Wv, Whv, Wlv);
    sdpca_gemm_kv_mfma<<<dim3(D_ / 128, (B_ * TK_) / 128, 2), blk, 0, stream>>>(
        Ah, Al, Whk, Wlk, Whv, Wlv, bk, bv, Kb, Vb);
    transpose_v       <<<dim3(TK_ / 64, B_ * NH_),       blk, 0, stream>>>(Vb, Vt);
    sdpca_attn_mfma   <<<dim3(TQ_ / 64, B_ * NH_, ASPLIT), blk, 0, stream>>>(Qb, Kb, Vt, na, pO, pM, pL);
    sdpca_combine     <<<dim3((B_ * TQ_ * D_) / 256),    blk, 0, stream>>>(pO, pM, pL, na, Ao);
    sdpca_gemm_o      <<<dim3(D_ / BN, (B_ * TQ_) / BM), blk, 0, stream>>>(Ao, Wo, bo, (float*)d_out);
}

// Round 5
// 412.449 us; speedup vs baseline: 7.4692x; 1.1868x over previous
//
#include <hip/hip_runtime.h>
#include <math.h>
#include <stdint.h>

#define B_   2
#define TQ_  512
#define TK_  8192
#define D_   1024
#define NH_  16
#define HD_  64

#define NEG_BIG (-3.0e38f)
#define ASPLIT 4

typedef __attribute__((ext_vector_type(8))) short short8;
typedef __attribute__((ext_vector_type(4))) float f32x4;

// ---------------- bf16 helpers (RNE) ----------------
__device__ __forceinline__ unsigned short f2bf(float x) {
    unsigned u = __float_as_uint(x);
    unsigned r = u + 0x7FFFu + ((u >> 16) & 1u);
    return (unsigned short)(r >> 16);
}
__device__ __forceinline__ float bf2f(unsigned short h) {
    return __uint_as_float(((unsigned)h) << 16);
}

#define GLD16(gp, lp)                                                              \
    __builtin_amdgcn_global_load_lds(                                              \
        (const __attribute__((address_space(1))) unsigned int*)(gp),               \
        (__attribute__((address_space(3))) unsigned int*)(lp), 16, 0, 0)

// ---------------- fp32 GEMM config (q/o projections) ----------------
#define BM   64
#define BN   64
#define BKT  32
#define LDP  68

// ---------------- Q projection: Qb = bf16((A @ Wq^T + bq) * 1/(64*temp)) ----------------
__global__ __launch_bounds__(256)
void sdpca_gemm_q(const float* __restrict__ A, const float* __restrict__ W,
                  const float* __restrict__ bias, const float* __restrict__ log_temp,
                  unsigned short* __restrict__ Qb)
{
    __shared__ float As[BKT][LDP];
    __shared__ float Ws[BKT][LDP];
    const int tid  = threadIdx.x;
    const int brow = blockIdx.y * BM;
    const int bcol = blockIdx.x * BN;
    const int tr   = (tid >> 4) << 2;
    const int tc   = (tid & 15) << 2;

    float acc[4][4] = {};
    for (int k0 = 0; k0 < D_; k0 += BKT) {
#pragma unroll
        for (int i = 0; i < 2; ++i) {
            int idx = (i << 8) + tid;
            int r   = idx >> 3;
            int c   = (idx & 7) << 2;
            float4 av = *(const float4*)(A + (size_t)(brow + r) * D_ + (k0 + c));
            As[c + 0][r] = av.x; As[c + 1][r] = av.y; As[c + 2][r] = av.z; As[c + 3][r] = av.w;
            float4 wv = *(const float4*)(W + (size_t)(bcol + r) * D_ + (k0 + c));
            Ws[c + 0][r] = wv.x; Ws[c + 1][r] = wv.y; Ws[c + 2][r] = wv.z; Ws[c + 3][r] = wv.w;
        }
        __syncthreads();
#pragma unroll
        for (int kk = 0; kk < BKT; ++kk) {
            float4 a = *(const float4*)&As[kk][tr];
            float4 w = *(const float4*)&Ws[kk][tc];
            float aa[4] = {a.x, a.y, a.z, a.w};
            float ww[4] = {w.x, w.y, w.z, w.w};
#pragma unroll
            for (int i2 = 0; i2 < 4; ++i2)
#pragma unroll
                for (int j2 = 0; j2 < 4; ++j2)
                    acc[i2][j2] = fmaf(aa[i2], ww[j2], acc[i2][j2]);
        }
        __syncthreads();
    }

    float lt    = *log_temp;
    float temp  = fminf(fmaxf(expf(lt), 0.1f), 10.0f);
    float scale = 1.0f / (64.0f * temp);

#pragma unroll
    for (int i = 0; i < 4; ++i) {
        int r = brow + tr + i;
        float4 bv = *(const float4*)(bias + bcol + tc);
        ushort4 o;
        o.x = f2bf((acc[i][0] + bv.x) * scale);
        o.y = f2bf((acc[i][1] + bv.y) * scale);
        o.z = f2bf((acc[i][2] + bv.z) * scale);
        o.w = f2bf((acc[i][3] + bv.w) * scale);
        *(ushort4*)(Qb + (size_t)r * D_ + bcol + tc) = o;
    }
}

// ---------------- bf16 conversion of (kv + group bias) ----------------
__global__ __launch_bounds__(256)
void split_kv(const float* __restrict__ kv, const float* __restrict__ ab,
              const float* __restrict__ ib, const int* __restrict__ nactp,
              unsigned short* __restrict__ Ah)
{
    const int Na = *nactp;
    size_t i = ((size_t)blockIdx.x * 256 + threadIdx.x) * 8;
    int row = (int)(i >> 10);
    int col = (int)(i & (D_ - 1));
    const float* bp = ((row & (TK_ - 1)) < Na) ? ab : ib;
    float4 x0 = *(const float4*)(kv + i);
    float4 x1 = *(const float4*)(kv + i + 4);
    float4 b0 = *(const float4*)(bp + col);
    float4 b1 = *(const float4*)(bp + col + 4);
    float a[8] = {x0.x + b0.x, x0.y + b0.y, x0.z + b0.z, x0.w + b0.w,
                  x1.x + b1.x, x1.y + b1.y, x1.z + b1.z, x1.w + b1.w};
    union { short8 v; unsigned short u[8]; } H;
#pragma unroll
    for (int j = 0; j < 8; ++j) H.u[j] = f2bf(a[j]);
    *(short8*)(Ah + i) = H.v;
}

// ---------------- bf16 conversion of a weight matrix ----------------
__global__ __launch_bounds__(256)
void split_w(const float* __restrict__ W, unsigned short* __restrict__ Wh)
{
    size_t i = ((size_t)blockIdx.x * 256 + threadIdx.x) * 8;
    float4 x0 = *(const float4*)(W + i);
    float4 x1 = *(const float4*)(W + i + 4);
    float a[8] = {x0.x, x0.y, x0.z, x0.w, x1.x, x1.y, x1.z, x1.w};
    union { short8 v; unsigned short u[8]; } H;
#pragma unroll
    for (int j = 0; j < 8; ++j) H.u[j] = f2bf(a[j]);
    *(short8*)(Wh + i) = H.v;
}

// ---------------- merged K+V projection via bf16 MFMA ----------------
// One 128x128 A-tile feeds both Wk and Wv streams: 32 MFMA : 12 ds_read per
// wave per BK=32 step. Grid = 1024 blocks (8 col-tiles x 128 row-tiles),
// XCD-swizzled so each XCD's L2 keeps one A row-panel hot across the 8
// column blocks that reuse it.
__global__ __launch_bounds__(256)
void sdpca_gemm_kv_mfma(const unsigned short* __restrict__ Ah,
                        const unsigned short* __restrict__ Whk,
                        const unsigned short* __restrict__ Whv,
                        const float* __restrict__ bk, const float* __restrict__ bv,
                        unsigned short* __restrict__ Kb, unsigned short* __restrict__ Vb)
{
    __shared__ unsigned short AT [128 * 32];
    __shared__ unsigned short BkT[128 * 32];
    __shared__ unsigned short BvT[128 * 32];

    const int tid  = threadIdx.x;
    const int lane = tid & 63;
    const int w    = tid >> 6;

    // XCD swizzle: xcd = bid % 8 owns contiguous row-tile chunk (1024 % 8 == 0)
    const int bid  = blockIdx.x;
    const int lid  = (bid & 7) * 128 + (bid >> 3);
    const int brow = (lid >> 3) * 128;
    const int bcol = (lid & 7) * 128;

    const int wr = w >> 1, wc = w & 1;

    const int   srow = lane >> 2;
    const int   scol = (lane & 3) * 8;
    const size_t gA0 = (size_t)(brow + w * 32 + srow) * D_ + scol;
    const size_t gA1 = gA0 + (size_t)16 * D_;
    const size_t gB0 = (size_t)(bcol + w * 32 + srow) * D_ + scol;
    const size_t gB1 = gB0 + (size_t)16 * D_;
    const int   l0   = (w * 32 +  0) * 32;
    const int   l1   = (w * 32 + 16) * 32;

    f32x4 acck[4][4], accv[4][4];
#pragma unroll
    for (int m = 0; m < 4; ++m)
#pragma unroll
        for (int n = 0; n < 4; ++n) {
            acck[m][n] = (f32x4){0.f, 0.f, 0.f, 0.f};
            accv[m][n] = (f32x4){0.f, 0.f, 0.f, 0.f};
        }

    const int frow = lane & 15;
    const int fko  = (lane >> 4) * 8;

    for (int k0 = 0; k0 < D_; k0 += 32) {
        GLD16(Ah  + gA0 + k0, &AT [l0]);
        GLD16(Ah  + gA1 + k0, &AT [l1]);
        GLD16(Whk + gB0 + k0, &BkT[l0]);
        GLD16(Whk + gB1 + k0, &BkT[l1]);
        GLD16(Whv + gB0 + k0, &BvT[l0]);
        GLD16(Whv + gB1 + k0, &BvT[l1]);
        __syncthreads();

        short8 bkf[4], bvf[4];
#pragma unroll
        for (int n = 0; n < 4; ++n) {
            int r = wc * 64 + n * 16 + frow;
            bkf[n] = *(const short8*)&BkT[r * 32 + fko];
            bvf[n] = *(const short8*)&BvT[r * 32 + fko];
        }
#pragma unroll
        for (int m = 0; m < 4; ++m) {
            int r = wr * 64 + m * 16 + frow;
            short8 a = *(const short8*)&AT[r * 32 + fko];
#pragma unroll
            for (int n = 0; n < 4; ++n) {
                acck[m][n] = __builtin_amdgcn_mfma_f32_16x16x32_bf16(a, bkf[n], acck[m][n], 0, 0, 0);
                accv[m][n] = __builtin_amdgcn_mfma_f32_16x16x32_bf16(a, bvf[n], accv[m][n], 0, 0, 0);
            }
        }
        __syncthreads();
    }

#pragma unroll
    for (int n = 0; n < 4; ++n) {
        int col = bcol + wc * 64 + n * 16 + frow;
        float bkv = bk[col];
        float bvv = bv[col];
#pragma unroll
        for (int m = 0; m < 4; ++m) {
            int rbase = brow + wr * 64 + m * 16 + (lane >> 4) * 4;
#pragma unroll
            for (int r = 0; r < 4; ++r) {
                Kb[(size_t)(rbase + r) * D_ + col] = f2bf(acck[m][n][r] + bkv);
                Vb[(size_t)(rbase + r) * D_ + col] = f2bf(accv[m][n][r] + bvv);
            }
        }
    }
}

// ---------------- V transpose: Vb[b*TK+t][h*64+d] -> Vt[(bh*64+d)][t] ----------------
__global__ __launch_bounds__(256)
void transpose_v(const unsigned short* __restrict__ Vb, unsigned short* __restrict__ Vt)
{
    __shared__ unsigned short T[64][72];
    const int tid = threadIdx.x;
    const int t0  = blockIdx.x * 64;
    const int bh  = blockIdx.y, b = bh >> 4, h = bh & 15;
    {
        int tok = tid >> 2, dc = (tid & 3) * 16;
        const unsigned short* src = Vb + (size_t)(b * TK_ + t0 + tok) * D_ + h * HD_ + dc;
        *(short8*)&T[tok][dc]     = *(const short8*)(src);
        *(short8*)&T[tok][dc + 8] = *(const short8*)(src + 8);
    }
    __syncthreads();
    {
        int d = tid >> 2, tc = (tid & 3) * 16;
        unsigned short* dst = Vt + ((size_t)bh * HD_ + d) * TK_ + t0 + tc;
        union { short8 v; unsigned short u[8]; } o0, o1;
#pragma unroll
        for (int j = 0; j < 8; ++j) { o0.u[j] = T[tc + j][d]; o1.u[j] = T[tc + 8 + j][d]; }
        *(short8*)(dst)     = o0.v;
        *(short8*)(dst + 8) = o1.v;
    }
}

// ---------------- MFMA flash attention, two groups, split-K ----------------
__device__ __forceinline__ void attn_pass(
    const f32x4 st[4], int jb, int lo, int hi,
    float& mst, float& lst, f32x4 o[4],
    unsigned short* Ps, const unsigned short* Vs,
    int frow, int g, int w)
{
    const int q = w * 16 + frow;
    float pmax = NEG_BIG;
#pragma unroll
    for (int mt = 0; mt < 4; ++mt)
#pragma unroll
        for (int r = 0; r < 4; ++r) {
            int key = jb + mt * 16 + g * 4 + r;
            if (key >= lo && key < hi) pmax = fmaxf(pmax, st[mt][r]);
        }
    pmax = fmaxf(pmax, __shfl_xor(pmax, 16, 64));
    pmax = fmaxf(pmax, __shfl_xor(pmax, 32, 64));
    const float mnew = fmaxf(mst, pmax);
    const float corr = __expf(mst - mnew);

    float p[4][4];
    float psum = 0.f;
#pragma unroll
    for (int mt = 0; mt < 4; ++mt)
#pragma unroll
        for (int r = 0; r < 4; ++r) {
            int key = jb + mt * 16 + g * 4 + r;
            float pv = (key >= lo && key < hi) ? __expf(st[mt][r] - mnew) : 0.f;
            p[mt][r] = pv; psum += pv;
        }
    psum += __shfl_xor(psum, 16, 64);
    psum += __shfl_xor(psum, 32, 64);
    lst = lst * corr + psum;
    mst = mnew;
#pragma unroll
    for (int mt = 0; mt < 4; ++mt) {
        o[mt][0] *= corr; o[mt][1] *= corr; o[mt][2] *= corr; o[mt][3] *= corr;
    }
#pragma unroll
    for (int mt = 0; mt < 4; ++mt) {
        unsigned u0 = (unsigned)f2bf(p[mt][0]) | ((unsigned)f2bf(p[mt][1]) << 16);
        unsigned u1 = (unsigned)f2bf(p[mt][2]) | ((unsigned)f2bf(p[mt][3]) << 16);
        unsigned* dst = (unsigned*)((char*)Ps + q * 144 + (mt * 16 + g * 4) * 2);
        dst[0] = u0; dst[1] = u1;
    }
    __builtin_amdgcn_sched_barrier(0);   // keep PV reads after P writes
#pragma unroll
    for (int mt = 0; mt < 4; ++mt) {
        int row = mt * 16 + frow;
        int rs  = (row & 7) << 4;
#pragma unroll
        for (int ks = 0; ks < 2; ++ks) {
            short8 a = *(const short8*)((const char*)Vs + row * 128 + ((ks * 64 + g * 16) ^ rs));
            short8 bfr = *(const short8*)((const char*)Ps + q * 144 + ks * 64 + g * 16);
            o[mt] = __builtin_amdgcn_mfma_f32_16x16x32_bf16(a, bfr, o[mt], 0, 0, 0);
        }
    }
}

__global__ __launch_bounds__(256)
void sdpca_attn_mfma(const unsigned short* __restrict__ Qb,
                     const unsigned short* __restrict__ Kb,
                     const unsigned short* __restrict__ Vt,
                     const int* __restrict__ nactp,
                     float* __restrict__ pO, float* __restrict__ pM, float* __restrict__ pL)
{
    __shared__ char smem[25600];
    unsigned short* Ks = (unsigned short*)smem;
    unsigned short* Vs = (unsigned short*)(smem + 8192);
    unsigned short* Ps = (unsigned short*)(smem + 16384);
    float*          Ot = (float*)smem;

    const int tid  = threadIdx.x;
    const int l    = tid & 63, w = tid >> 6;
    const int frow = l & 15,  g = l >> 4;
    const int bh   = blockIdx.y, b = bh >> 4, h = bh & 15;
    const int q0   = blockIdx.x * 64;
    const int s    = blockIdx.z;
    const int Na   = *nactp;
    const int ks0  = s * (TK_ / ASPLIT);
    const int nt   = TK_ / ASPLIT / 64;

    short8 qf0, qf1;
    {
        const unsigned short* qp = Qb + (size_t)(b * TQ_ + q0 + w * 16 + frow) * D_ + h * HD_;
        qf0 = *(const short8*)(qp + g * 8);
        qf1 = *(const short8*)(qp + 32 + g * 8);
    }

    float mA = NEG_BIG, lA = 0.f, mI = NEG_BIG, lI = 0.f;
    f32x4 oA[4], oI[4];
#pragma unroll
    for (int mt = 0; mt < 4; ++mt) {
        oA[mt] = (f32x4){0.f, 0.f, 0.f, 0.f};
        oI[mt] = (f32x4){0.f, 0.f, 0.f, 0.f};
    }

    const int srow = tid >> 2;
    const int scb  = (tid & 3) * 32;
    const unsigned short* kg = Kb + (size_t)(b * TK_ + ks0 + srow) * D_ + h * HD_ + (tid & 3) * 16;
    const unsigned short* vg = Vt + ((size_t)bh * HD_ + srow) * TK_ + ks0 + (tid & 3) * 16;
    const int kswz0 = srow * 128 + ((scb +  0) ^ ((srow & 7) << 4));
    const int kswz1 = srow * 128 + ((scb + 16) ^ ((srow & 7) << 4));

    for (int t = 0; t < nt; ++t) {
        const int jb = ks0 + t * 64;
        short8 kr0 = *(const short8*)(kg);
        short8 kr1 = *(const short8*)(kg + 8);
        short8 vr0 = *(const short8*)(vg);
        short8 vr1 = *(const short8*)(vg + 8);
        kg += (size_t)64 * D_;
        vg += 64;
        __syncthreads();
        *(short8*)((char*)Ks + kswz0) = kr0;
        *(short8*)((char*)Ks + kswz1) = kr1;
        *(short8*)((char*)Vs + kswz0) = vr0;
        *(short8*)((char*)Vs + kswz1) = vr1;
        __syncthreads();

        f32x4 st[4];
#pragma unroll
        for (int mt = 0; mt < 4; ++mt) {
            int row = mt * 16 + frow;
            int rs  = (row & 7) << 4;
            short8 a0 = *(const short8*)((const char*)Ks + row * 128 + ((g * 16) ^ rs));
            short8 a1 = *(const short8*)((const char*)Ks + row * 128 + ((64 + g * 16) ^ rs));
            f32x4 acc = (f32x4){0.f, 0.f, 0.f, 0.f};
            acc = __builtin_amdgcn_mfma_f32_16x16x32_bf16(a0, qf0, acc, 0, 0, 0);
            acc = __builtin_amdgcn_mfma_f32_16x16x32_bf16(a1, qf1, acc, 0, 0, 0);
            st[mt] = acc;
        }

        const bool hasA = (jb < Na);
        const bool hasI = (jb + 64 > Na);
        if (hasA) attn_pass(st, jb, 0,  Na,  mA, lA, oA, Ps, Vs, frow, g, w);
        if (hasI) attn_pass(st, jb, Na, TK_, mI, lI, oI, Ps, Vs, frow, g, w);
    }

    const int q = w * 16 + frow;
#pragma unroll
    for (int grp = 0; grp < 2; ++grp) {
        __syncthreads();
        const f32x4* o = grp ? oI : oA;
#pragma unroll
        for (int mt = 0; mt < 4; ++mt)
            *(f32x4*)&Ot[q * 68 + mt * 16 + g * 4] = o[mt];
        if (g == 0) {
            size_t base = ((size_t)((s * 2 + grp) * (B_ * NH_) + bh)) * TQ_ + q0 + q;
            pM[base] = grp ? mI : mA;
            pL[base] = grp ? lI : lA;
        }
        __syncthreads();
        {
            int qr = tid >> 2, dc = (tid & 3) * 16;
            size_t rowbase = ((size_t)((s * 2 + grp) * (B_ * NH_) + bh)) * TQ_ + q0 + qr;
            float* dst = pO + rowbase * HD_ + dc;
#pragma unroll
            for (int u = 0; u < 4; ++u)
                *(float4*)(dst + 4 * u) = *(const float4*)&Ot[qr * 68 + dc + 4 * u];
        }
    }
}

// ---------------- split-K merge over ASPLIT partials ----------------
__global__ __launch_bounds__(256)
void sdpca_combine(const float* __restrict__ pO, const float* __restrict__ pM,
                   const float* __restrict__ pL, const int* __restrict__ nactp,
                   float* __restrict__ Ao)
{
    int idx = blockIdx.x * 256 + threadIdx.x;
    int d   = idx & (HD_ - 1);
    int q   = (idx >> 6) & (TQ_ - 1);
    int bh  = idx >> 15;
    int b   = bh >> 4, h = bh & 15;
    int Na  = *nactp;
    int Ni  = TK_ - Na;

    float res = 0.f;
#pragma unroll
    for (int gg = 0; gg < 2; ++gg) {
        float M = NEG_BIG;
#pragma unroll
        for (int ss = 0; ss < ASPLIT; ++ss) {
            size_t ii = ((size_t)((ss * 2 + gg) * (B_ * NH_) + bh)) * TQ_ + q;
            M = fmaxf(M, pM[ii]);
        }
        float L = 0.f, O = 0.f;
#pragma unroll
        for (int ss = 0; ss < ASPLIT; ++ss) {
            size_t ii = ((size_t)((ss * 2 + gg) * (B_ * NH_) + bh)) * TQ_ + q;
            float ww = __expf(pM[ii] - M);
            L += pL[ii] * ww;
            O += pO[ii * HD_ + d] * ww;
        }
        float r   = (L > 0.f) ? (O / L) : 0.f;
        int   cnt = (gg == 0) ? Na : Ni;
        float sc  = (cnt > 0) ? rsqrtf((float)cnt) : 0.f;
        res += (gg == 0) ? (sc * r) : (-sc * r);
    }
    Ao[((size_t)(b * TQ_ + q)) * D_ + h * HD_ + d] = res;
}

// ---------------- output projection ----------------
__global__ __launch_bounds__(256)
void sdpca_gemm_o(const float* __restrict__ A, const float* __restrict__ W,
                  const float* __restrict__ bias, float* __restrict__ C)
{
    __shared__ float As[BKT][LDP];
    __shared__ float Ws[BKT][LDP];
    const int tid  = threadIdx.x;
    const int brow = blockIdx.y * BM;
    const int bcol = blockIdx.x * BN;
    const int tr   = (tid >> 4) << 2;
    const int tc   = (tid & 15) << 2;

    float acc[4][4] = {};
    for (int k0 = 0; k0 < D_; k0 += BKT) {
#pragma unroll
        for (int i = 0; i < 2; ++i) {
            int idx = (i << 8) + tid;
            int r   = idx >> 3;
            int c   = (idx & 7) << 2;
            float4 av = *(const float4*)(A + (size_t)(brow + r) * D_ + (k0 + c));
            As[c + 0][r] = av.x; As[c + 1][r] = av.y; As[c + 2][r] = av.z; As[c + 3][r] = av.w;
            float4 wv = *(const float4*)(W + (size_t)(bcol + r) * D_ + (k0 + c));
            Ws[c + 0][r] = wv.x; Ws[c + 1][r] = wv.y; Ws[c + 2][r] = wv.z; Ws[c + 3][r] = wv.w;
        }
        __syncthreads();
#pragma unroll
        for (int kk = 0; kk < BKT; ++kk) {
            float4 a = *(const float4*)&As[kk][tr];
            float4 w = *(const float4*)&Ws[kk][tc];
            float aa[4] = {a.x, a.y, a.z, a.w};
            float ww[4] = {w.x, w.y, w.z, w.w};
#pragma unroll
            for (int i2 = 0; i2 < 4; ++i2)
#pragma unroll
                for (int j2 = 0; j2 < 4; ++j2)
                    acc[i2][j2] = fmaf(aa[i2], ww[j2], acc[i2][j2]);
        }
        __syncthreads();
    }

#pragma unroll
    for (int i = 0; i < 4; ++i) {
        int r = brow + tr + i;
        float4 bv = *(const float4*)(bias + bcol + tc);
        float4 o;
        o.x = acc[i][0] + bv.x; o.y = acc[i][1] + bv.y;
        o.z = acc[i][2] + bv.z; o.w = acc[i][3] + bv.w;
        *(float4*)(C + (size_t)r * D_ + bcol + tc) = o;
    }
}

extern "C" void kernel_launch(void* const* d_in, const int* in_sizes, int n_in,
                              void* d_out, int out_size, void* d_ws, size_t ws_size,
                              hipStream_t stream) {
    (void)in_sizes; (void)n_in; (void)out_size; (void)ws_size;
    const float* q   = (const float*)d_in[0];
    const float* kv  = (const float*)d_in[1];
    const float* Wq  = (const float*)d_in[2];
    const float* bq  = (const float*)d_in[3];
    const float* Wk  = (const float*)d_in[4];
    const float* bk  = (const float*)d_in[5];
    const float* Wv  = (const float*)d_in[6];
    const float* bv  = (const float*)d_in[7];
    const float* Wo  = (const float*)d_in[8];
    const float* bo  = (const float*)d_in[9];
    const float* ab  = (const float*)d_in[10];
    const float* ib  = (const float*)d_in[11];
    const float* lt  = (const float*)d_in[12];
    const int*   na  = (const int*)d_in[13];

    char* ws = (char*)d_ws;
    const size_t nQ  = (size_t)B_ * TQ_ * D_;    // 1,048,576
    const size_t nKV = (size_t)B_ * TK_ * D_;    // 16,777,216
    const size_t nW  = (size_t)D_ * D_;          // 1,048,576
    const size_t nML = (size_t)ASPLIT * 2 * B_ * NH_ * TQ_;  // 131,072

    unsigned short* Ah  = (unsigned short*)ws;                 // 33.5 MB
    unsigned short* Whk = Ah + nKV;                            // 2 MB
    unsigned short* Whv = Whk + nW;                            // 2 MB
    unsigned short* Kb  = Whv + nW;                            // 33.5 MB
    unsigned short* Vb  = Kb + nKV;                            // 33.5 MB
    unsigned short* Vt  = Vb + nKV;                            // 33.5 MB
    unsigned short* Qb  = Vt + nKV;                            // 2 MB
    float* pM = (float*)(Qb + nQ);                             // 0.5 MB
    float* pL = pM + nML;                                      // 0.5 MB
    float* Ao = pL + nML;                                      // 4 MB
    // Ah dead after kv_mfma -> reuse for attention partials (needs 33.5 MB)
    float* pO = (float*)Ah;

    dim3 blk(256);
    sdpca_gemm_q      <<<dim3(D_ / BN, (B_ * TQ_) / BM), blk, 0, stream>>>(q, Wq, bq, lt, Qb);
    split_kv          <<<dim3((int)(nKV / 8 / 256)),     blk, 0, stream>>>(kv, ab, ib, na, Ah);
    split_w           <<<dim3((int)(nW / 8 / 256)),      blk, 0, stream>>>(Wk, Whk);
    split_w           <<<dim3((int)(nW / 8 / 256)),      blk, 0, stream>>>(Wv, Whv);
    sdpca_gemm_kv_mfma<<<dim3((D_ / 128) * ((B_ * TK_) / 128)), blk, 0, stream>>>(
        Ah, Whk, Whv, bk, bv, Kb, Vb);
    transpose_v       <<<dim3(TK_ / 64, B_ * NH_),       blk, 0, stream>>>(Vb, Vt);
    sdpca_attn_mfma   <<<dim3(TQ_ / 64, B_ * NH_, ASPLIT), blk, 0, stream>>>(Qb, Kb, Vt, na, pO, pM, pL);
    sdpca_combine     <<<dim3((B_ * TQ_ * D_) / 256),    blk, 0, stream>>>(pO, pM, pL, na, Ao);
    sdpca_gemm_o      <<<dim3(D_ / BN, (B_ * TQ_) / BM), blk, 0, stream>>>(Ao, Wo, bo, (float*)d_out);
}

// Round 6
// 306.002 us; speedup vs baseline: 10.0675x; 1.3479x over previous
//
#include <hip/hip_runtime.h>
#include <math.h>
#include <stdint.h>

#define B_   2
#define TQ_  512
#define TK_  8192
#define D_   1024
#define NH_  16
#define HD_  64

#define NEG_BIG (-3.0e38f)
#define ASPLIT 4

typedef __attribute__((ext_vector_type(8))) short short8;
typedef __attribute__((ext_vector_type(4))) float f32x4;

// ---------------- bf16 helpers (RNE) ----------------
__device__ __forceinline__ unsigned short f2bf(float x) {
    unsigned u = __float_as_uint(x);
    unsigned r = u + 0x7FFFu + ((u >> 16) & 1u);
    return (unsigned short)(r >> 16);
}

#define GLD16(gp, lp)                                                              \
    __builtin_amdgcn_global_load_lds(                                              \
        (const __attribute__((address_space(1))) unsigned int*)(gp),               \
        (__attribute__((address_space(3))) unsigned int*)(lp), 16, 0, 0)

// ---------------- fp32 -> bf16 conversion (generic, n = grid*256*8) ----------------
__global__ __launch_bounds__(256)
void split_w(const float* __restrict__ W, unsigned short* __restrict__ Wh)
{
    size_t i = ((size_t)blockIdx.x * 256 + threadIdx.x) * 8;
    float4 x0 = *(const float4*)(W + i);
    float4 x1 = *(const float4*)(W + i + 4);
    float a[8] = {x0.x, x0.y, x0.z, x0.w, x1.x, x1.y, x1.z, x1.w};
    union { short8 v; unsigned short u[8]; } H;
#pragma unroll
    for (int j = 0; j < 8; ++j) H.u[j] = f2bf(a[j]);
    *(short8*)(Wh + i) = H.v;
}

// ---------------- bf16 conversion of (kv + group bias) ----------------
__global__ __launch_bounds__(256)
void split_kv(const float* __restrict__ kv, const float* __restrict__ ab,
              const float* __restrict__ ib, const int* __restrict__ nactp,
              unsigned short* __restrict__ Ah)
{
    const int Na = *nactp;
    size_t i = ((size_t)blockIdx.x * 256 + threadIdx.x) * 8;
    int row = (int)(i >> 10);
    int col = (int)(i & (D_ - 1));
    const float* bp = ((row & (TK_ - 1)) < Na) ? ab : ib;
    float4 x0 = *(const float4*)(kv + i);
    float4 x1 = *(const float4*)(kv + i + 4);
    float4 b0 = *(const float4*)(bp + col);
    float4 b1 = *(const float4*)(bp + col + 4);
    float a[8] = {x0.x + b0.x, x0.y + b0.y, x0.z + b0.z, x0.w + b0.w,
                  x1.x + b1.x, x1.y + b1.y, x1.z + b1.z, x1.w + b1.w};
    union { short8 v; unsigned short u[8]; } H;
#pragma unroll
    for (int j = 0; j < 8; ++j) H.u[j] = f2bf(a[j]);
    *(short8*)(Ah + i) = H.v;
}

// ---------------- Q projection, bf16 MFMA: Qb = bf16((qb @ Wqb^T + bq)/(64*temp)) ----------------
__global__ __launch_bounds__(256)
void sdpca_gemm_q(const unsigned short* __restrict__ A, const unsigned short* __restrict__ W,
                  const float* __restrict__ bias, const float* __restrict__ log_temp,
                  unsigned short* __restrict__ Qb)
{
    __shared__ unsigned short AT[128 * 32];
    __shared__ unsigned short BT[128 * 32];
    const int tid  = threadIdx.x;
    const int lane = tid & 63;
    const int w    = tid >> 6;
    const int brow = blockIdx.y * 128;
    const int bcol = blockIdx.x * 128;
    const int wr = w >> 1, wc = w & 1;

    const int   srow = lane >> 2;
    const int   scol = (lane & 3) * 8;
    const size_t gA0 = (size_t)(brow + w * 32 + srow) * D_ + scol;
    const size_t gA1 = gA0 + (size_t)16 * D_;
    const size_t gB0 = (size_t)(bcol + w * 32 + srow) * D_ + scol;
    const size_t gB1 = gB0 + (size_t)16 * D_;
    const int   l0   = (w * 32 +  0) * 32;
    const int   l1   = (w * 32 + 16) * 32;

    f32x4 acc[4][4];
#pragma unroll
    for (int m = 0; m < 4; ++m)
#pragma unroll
        for (int n = 0; n < 4; ++n) acc[m][n] = (f32x4){0.f, 0.f, 0.f, 0.f};

    const int frow = lane & 15;
    const int fko  = (lane >> 4) * 8;

    for (int k0 = 0; k0 < D_; k0 += 32) {
        GLD16(A + gA0 + k0, &AT[l0]);
        GLD16(A + gA1 + k0, &AT[l1]);
        GLD16(W + gB0 + k0, &BT[l0]);
        GLD16(W + gB1 + k0, &BT[l1]);
        __syncthreads();
        short8 bf[4];
#pragma unroll
        for (int n = 0; n < 4; ++n)
            bf[n] = *(const short8*)&BT[(wc * 64 + n * 16 + frow) * 32 + fko];
#pragma unroll
        for (int m = 0; m < 4; ++m) {
            short8 a = *(const short8*)&AT[(wr * 64 + m * 16 + frow) * 32 + fko];
#pragma unroll
            for (int n = 0; n < 4; ++n)
                acc[m][n] = __builtin_amdgcn_mfma_f32_16x16x32_bf16(a, bf[n], acc[m][n], 0, 0, 0);
        }
        __syncthreads();
    }

    float lt    = *log_temp;
    float temp  = fminf(fmaxf(expf(lt), 0.1f), 10.0f);
    float scale = 1.0f / (64.0f * temp);

#pragma unroll
    for (int n = 0; n < 4; ++n) {
        int col = bcol + wc * 64 + n * 16 + frow;
        float bsv = bias[col];
#pragma unroll
        for (int m = 0; m < 4; ++m) {
            int rbase = brow + wr * 64 + m * 16 + (lane >> 4) * 4;
#pragma unroll
            for (int r = 0; r < 4; ++r)
                Qb[(size_t)(rbase + r) * D_ + col] = f2bf((acc[m][n][r] + bsv) * scale);
        }
    }
}

// ---------------- K/V projection via bf16 MFMA, z picks K or V; V written transposed ----------------
// grid (1024, 2). XCD swizzle: xcd = bid%8 owns a contiguous row-tile chunk.
__global__ __launch_bounds__(256)
void sdpca_gemm_kv_mfma(const unsigned short* __restrict__ Ah,
                        const unsigned short* __restrict__ Whk,
                        const unsigned short* __restrict__ Whv,
                        const float* __restrict__ bk, const float* __restrict__ bv,
                        unsigned short* __restrict__ Kb, unsigned short* __restrict__ Vt)
{
    __shared__ unsigned short AT[128 * 32];
    __shared__ unsigned short BT[128 * 32];

    const int tid  = threadIdx.x;
    const int lane = tid & 63;
    const int w    = tid >> 6;
    const int bid  = blockIdx.x;
    const int lid  = (bid & 7) * 128 + (bid >> 3);
    const int brow = (lid >> 3) * 128;
    const int bcol = (lid & 7) * 128;
    const int z    = blockIdx.y;

    const unsigned short* Wh = z ? Whv : Whk;
    const float* bias        = z ? bv  : bk;

    const int wr = w >> 1, wc = w & 1;

    const int   srow = lane >> 2;
    const int   scol = (lane & 3) * 8;
    const size_t gA0 = (size_t)(brow + w * 32 + srow) * D_ + scol;
    const size_t gA1 = gA0 + (size_t)16 * D_;
    const size_t gB0 = (size_t)(bcol + w * 32 + srow) * D_ + scol;
    const size_t gB1 = gB0 + (size_t)16 * D_;
    const int   l0   = (w * 32 +  0) * 32;
    const int   l1   = (w * 32 + 16) * 32;

    f32x4 acc[4][4];
#pragma unroll
    for (int m = 0; m < 4; ++m)
#pragma unroll
        for (int n = 0; n < 4; ++n) acc[m][n] = (f32x4){0.f, 0.f, 0.f, 0.f};

    const int frow = lane & 15;
    const int fko  = (lane >> 4) * 8;

    for (int k0 = 0; k0 < D_; k0 += 32) {
        GLD16(Ah + gA0 + k0, &AT[l0]);
        GLD16(Ah + gA1 + k0, &AT[l1]);
        GLD16(Wh + gB0 + k0, &BT[l0]);
        GLD16(Wh + gB1 + k0, &BT[l1]);
        __syncthreads();
        short8 bf[4];
#pragma unroll
        for (int n = 0; n < 4; ++n)
            bf[n] = *(const short8*)&BT[(wc * 64 + n * 16 + frow) * 32 + fko];
#pragma unroll
        for (int m = 0; m < 4; ++m) {
            short8 a = *(const short8*)&AT[(wr * 64 + m * 16 + frow) * 32 + fko];
#pragma unroll
            for (int n = 0; n < 4; ++n)
                acc[m][n] = __builtin_amdgcn_mfma_f32_16x16x32_bf16(a, bf[n], acc[m][n], 0, 0, 0);
        }
        __syncthreads();
    }

    if (z == 0) {
#pragma unroll
        for (int n = 0; n < 4; ++n) {
            int col = bcol + wc * 64 + n * 16 + frow;
            float bsv = bias[col];
#pragma unroll
            for (int m = 0; m < 4; ++m) {
                int rbase = brow + wr * 64 + m * 16 + (lane >> 4) * 4;
#pragma unroll
                for (int r = 0; r < 4; ++r)
                    Kb[(size_t)(rbase + r) * D_ + col] = f2bf(acc[m][n][r] + bsv);
            }
        }
    } else {
        // transposed store: Vt[(b*16+h)*64+d][token], 4 consecutive tokens -> ushort4
#pragma unroll
        for (int n = 0; n < 4; ++n) {
            int col = bcol + wc * 64 + n * 16 + frow;
            int h   = col >> 6, d = col & 63;
            float bsv = bias[col];
#pragma unroll
            for (int m = 0; m < 4; ++m) {
                int rbase = brow + wr * 64 + m * 16 + (lane >> 4) * 4;
                int b     = rbase >> 13;
                int tok   = rbase & (TK_ - 1);
                ushort4 o;
                o.x = f2bf(acc[m][n][0] + bsv);
                o.y = f2bf(acc[m][n][1] + bsv);
                o.z = f2bf(acc[m][n][2] + bsv);
                o.w = f2bf(acc[m][n][3] + bsv);
                *(ushort4*)&Vt[((size_t)(b * 16 + h) * 64 + d) * TK_ + tok] = o;
            }
        }
    }
}

// ---------------- MFMA flash attention, two groups, split-K ----------------
__device__ __forceinline__ void attn_pass(
    const f32x4 st[4], int jb, int lo, int hi,
    float& mst, float& lst, f32x4 o[4],
    unsigned short* Ps, const unsigned short* Vs,
    int frow, int g, int w)
{
    const int q = w * 16 + frow;
    float pmax = NEG_BIG;
#pragma unroll
    for (int mt = 0; mt < 4; ++mt)
#pragma unroll
        for (int r = 0; r < 4; ++r) {
            int key = jb + mt * 16 + g * 4 + r;
            if (key >= lo && key < hi) pmax = fmaxf(pmax, st[mt][r]);
        }
    pmax = fmaxf(pmax, __shfl_xor(pmax, 16, 64));
    pmax = fmaxf(pmax, __shfl_xor(pmax, 32, 64));
    const float mnew = fmaxf(mst, pmax);
    const float corr = __expf(mst - mnew);

    float p[4][4];
    float psum = 0.f;
#pragma unroll
    for (int mt = 0; mt < 4; ++mt)
#pragma unroll
        for (int r = 0; r < 4; ++r) {
            int key = jb + mt * 16 + g * 4 + r;
            float pv = (key >= lo && key < hi) ? __expf(st[mt][r] - mnew) : 0.f;
            p[mt][r] = pv; psum += pv;
        }
    psum += __shfl_xor(psum, 16, 64);
    psum += __shfl_xor(psum, 32, 64);
    lst = lst * corr + psum;
    mst = mnew;
#pragma unroll
    for (int mt = 0; mt < 4; ++mt) {
        o[mt][0] *= corr; o[mt][1] *= corr; o[mt][2] *= corr; o[mt][3] *= corr;
    }
#pragma unroll
    for (int mt = 0; mt < 4; ++mt) {
        unsigned u0 = (unsigned)f2bf(p[mt][0]) | ((unsigned)f2bf(p[mt][1]) << 16);
        unsigned u1 = (unsigned)f2bf(p[mt][2]) | ((unsigned)f2bf(p[mt][3]) << 16);
        unsigned* dst = (unsigned*)((char*)Ps + q * 144 + (mt * 16 + g * 4) * 2);
        dst[0] = u0; dst[1] = u1;
    }
    __builtin_amdgcn_sched_barrier(0);   // keep PV reads after P writes
#pragma unroll
    for (int mt = 0; mt < 4; ++mt) {
        int row = mt * 16 + frow;
        int rs  = (row & 7) << 4;
#pragma unroll
        for (int ks = 0; ks < 2; ++ks) {
            short8 a = *(const short8*)((const char*)Vs + row * 128 + ((ks * 64 + g * 16) ^ rs));
            short8 bfr = *(const short8*)((const char*)Ps + q * 144 + ks * 64 + g * 16);
            o[mt] = __builtin_amdgcn_mfma_f32_16x16x32_bf16(a, bfr, o[mt], 0, 0, 0);
        }
    }
}

__global__ __launch_bounds__(256)
void sdpca_attn_mfma(const unsigned short* __restrict__ Qb,
                     const unsigned short* __restrict__ Kb,
                     const unsigned short* __restrict__ Vt,
                     const int* __restrict__ nactp,
                     float* __restrict__ pO, float* __restrict__ pM, float* __restrict__ pL)
{
    __shared__ char smem[25600];
    unsigned short* Ks = (unsigned short*)smem;
    unsigned short* Vs = (unsigned short*)(smem + 8192);
    unsigned short* Ps = (unsigned short*)(smem + 16384);
    float*          Ot = (float*)smem;

    const int tid  = threadIdx.x;
    const int l    = tid & 63, w = tid >> 6;
    const int frow = l & 15,  g = l >> 4;
    const int bh   = blockIdx.y, b = bh >> 4, h = bh & 15;
    const int q0   = blockIdx.x * 64;
    const int s    = blockIdx.z;
    const int Na   = *nactp;
    const int ks0  = s * (TK_ / ASPLIT);
    const int nt   = TK_ / ASPLIT / 64;

    short8 qf0, qf1;
    {
        const unsigned short* qp = Qb + (size_t)(b * TQ_ + q0 + w * 16 + frow) * D_ + h * HD_;
        qf0 = *(const short8*)(qp + g * 8);
        qf1 = *(const short8*)(qp + 32 + g * 8);
    }

    float mA = NEG_BIG, lA = 0.f, mI = NEG_BIG, lI = 0.f;
    f32x4 oA[4], oI[4];
#pragma unroll
    for (int mt = 0; mt < 4; ++mt) {
        oA[mt] = (f32x4){0.f, 0.f, 0.f, 0.f};
        oI[mt] = (f32x4){0.f, 0.f, 0.f, 0.f};
    }

    const int srow = tid >> 2;
    const int scb  = (tid & 3) * 32;
    const unsigned short* kg = Kb + (size_t)(b * TK_ + ks0 + srow) * D_ + h * HD_ + (tid & 3) * 16;
    const unsigned short* vg = Vt + ((size_t)bh * HD_ + srow) * TK_ + ks0 + (tid & 3) * 16;
    const int kswz0 = srow * 128 + ((scb +  0) ^ ((srow & 7) << 4));
    const int kswz1 = srow * 128 + ((scb + 16) ^ ((srow & 7) << 4));

    for (int t = 0; t < nt; ++t) {
        const int jb = ks0 + t * 64;
        short8 kr0 = *(const short8*)(kg);
        short8 kr1 = *(const short8*)(kg + 8);
        short8 vr0 = *(const short8*)(vg);
        short8 vr1 = *(const short8*)(vg + 8);
        kg += (size_t)64 * D_;
        vg += 64;
        __syncthreads();
        *(short8*)((char*)Ks + kswz0) = kr0;
        *(short8*)((char*)Ks + kswz1) = kr1;
        *(short8*)((char*)Vs + kswz0) = vr0;
        *(short8*)((char*)Vs + kswz1) = vr1;
        __syncthreads();

        f32x4 st[4];
#pragma unroll
        for (int mt = 0; mt < 4; ++mt) {
            int row = mt * 16 + frow;
            int rs  = (row & 7) << 4;
            short8 a0 = *(const short8*)((const char*)Ks + row * 128 + ((g * 16) ^ rs));
            short8 a1 = *(const short8*)((const char*)Ks + row * 128 + ((64 + g * 16) ^ rs));
            f32x4 acc = (f32x4){0.f, 0.f, 0.f, 0.f};
            acc = __builtin_amdgcn_mfma_f32_16x16x32_bf16(a0, qf0, acc, 0, 0, 0);
            acc = __builtin_amdgcn_mfma_f32_16x16x32_bf16(a1, qf1, acc, 0, 0, 0);
            st[mt] = acc;
        }

        const bool hasA = (jb < Na);
        const bool hasI = (jb + 64 > Na);
        if (hasA) attn_pass(st, jb, 0,  Na,  mA, lA, oA, Ps, Vs, frow, g, w);
        if (hasI) attn_pass(st, jb, Na, TK_, mI, lI, oI, Ps, Vs, frow, g, w);
    }

    const int q = w * 16 + frow;
#pragma unroll
    for (int grp = 0; grp < 2; ++grp) {
        __syncthreads();
        const f32x4* o = grp ? oI : oA;
#pragma unroll
        for (int mt = 0; mt < 4; ++mt)
            *(f32x4*)&Ot[q * 68 + mt * 16 + g * 4] = o[mt];
        if (g == 0) {
            size_t base = ((size_t)((s * 2 + grp) * (B_ * NH_) + bh)) * TQ_ + q0 + q;
            pM[base] = grp ? mI : mA;
            pL[base] = grp ? lI : lA;
        }
        __syncthreads();
        {
            int qr = tid >> 2, dc = (tid & 3) * 16;
            size_t rowbase = ((size_t)((s * 2 + grp) * (B_ * NH_) + bh)) * TQ_ + q0 + qr;
            float* dst = pO + rowbase * HD_ + dc;
#pragma unroll
            for (int u = 0; u < 4; ++u)
                *(float4*)(dst + 4 * u) = *(const float4*)&Ot[qr * 68 + dc + 4 * u];
        }
    }
}

// ---------------- split-K merge over ASPLIT partials, bf16 out ----------------
__global__ __launch_bounds__(256)
void sdpca_combine(const float* __restrict__ pO, const float* __restrict__ pM,
                   const float* __restrict__ pL, const int* __restrict__ nactp,
                   unsigned short* __restrict__ Aob)
{
    int idx = blockIdx.x * 256 + threadIdx.x;
    int d   = idx & (HD_ - 1);
    int q   = (idx >> 6) & (TQ_ - 1);
    int bh  = idx >> 15;
    int b   = bh >> 4, h = bh & 15;
    int Na  = *nactp;
    int Ni  = TK_ - Na;

    float res = 0.f;
#pragma unroll
    for (int gg = 0; gg < 2; ++gg) {
        float M = NEG_BIG;
#pragma unroll
        for (int ss = 0; ss < ASPLIT; ++ss) {
            size_t ii = ((size_t)((ss * 2 + gg) * (B_ * NH_) + bh)) * TQ_ + q;
            M = fmaxf(M, pM[ii]);
        }
        float L = 0.f, O = 0.f;
#pragma unroll
        for (int ss = 0; ss < ASPLIT; ++ss) {
            size_t ii = ((size_t)((ss * 2 + gg) * (B_ * NH_) + bh)) * TQ_ + q;
            float ww = __expf(pM[ii] - M);
            L += pL[ii] * ww;
            O += pO[ii * HD_ + d] * ww;
        }
        float r   = (L > 0.f) ? (O / L) : 0.f;
        int   cnt = (gg == 0) ? Na : Ni;
        float sc  = (cnt > 0) ? rsqrtf((float)cnt) : 0.f;
        res += (gg == 0) ? (sc * r) : (-sc * r);
    }
    Aob[((size_t)(b * TQ_ + q)) * D_ + h * HD_ + d] = f2bf(res);
}

// ---------------- output projection, bf16 MFMA, fp32 out ----------------
__global__ __launch_bounds__(256)
void sdpca_gemm_o(const unsigned short* __restrict__ A, const unsigned short* __restrict__ W,
                  const float* __restrict__ bias, float* __restrict__ C)
{
    __shared__ unsigned short AT[128 * 32];
    __shared__ unsigned short BT[128 * 32];
    const int tid  = threadIdx.x;
    const int lane = tid & 63;
    const int w    = tid >> 6;
    const int brow = blockIdx.y * 128;
    const int bcol = blockIdx.x * 128;
    const int wr = w >> 1, wc = w & 1;

    const int   srow = lane >> 2;
    const int   scol = (lane & 3) * 8;
    const size_t gA0 = (size_t)(brow + w * 32 + srow) * D_ + scol;
    const size_t gA1 = gA0 + (size_t)16 * D_;
    const size_t gB0 = (size_t)(bcol + w * 32 + srow) * D_ + scol;
    const size_t gB1 = gB0 + (size_t)16 * D_;
    const int   l0   = (w * 32 +  0) * 32;
    const int   l1   = (w * 32 + 16) * 32;

    f32x4 acc[4][4];
#pragma unroll
    for (int m = 0; m < 4; ++m)
#pragma unroll
        for (int n = 0; n < 4; ++n) acc[m][n] = (f32x4){0.f, 0.f, 0.f, 0.f};

    const int frow = lane & 15;
    const int fko  = (lane >> 4) * 8;

    for (int k0 = 0; k0 < D_; k0 += 32) {
        GLD16(A + gA0 + k0, &AT[l0]);
        GLD16(A + gA1 + k0, &AT[l1]);
        GLD16(W + gB0 + k0, &BT[l0]);
        GLD16(W + gB1 + k0, &BT[l1]);
        __syncthreads();
        short8 bf[4];
#pragma unroll
        for (int n = 0; n < 4; ++n)
            bf[n] = *(const short8*)&BT[(wc * 64 + n * 16 + frow) * 32 + fko];
#pragma unroll
        for (int m = 0; m < 4; ++m) {
            short8 a = *(const short8*)&AT[(wr * 64 + m * 16 + frow) * 32 + fko];
#pragma unroll
            for (int n = 0; n < 4; ++n)
                acc[m][n] = __builtin_amdgcn_mfma_f32_16x16x32_bf16(a, bf[n], acc[m][n], 0, 0, 0);
        }
        __syncthreads();
    }

#pragma unroll
    for (int n = 0; n < 4; ++n) {
        int col = bcol + wc * 64 + n * 16 + frow;
        float bsv = bias[col];
#pragma unroll
        for (int m = 0; m < 4; ++m) {
            int rbase = brow + wr * 64 + m * 16 + (lane >> 4) * 4;
#pragma unroll
            for (int r = 0; r < 4; ++r)
                C[(size_t)(rbase + r) * D_ + col] = acc[m][n][r] + bsv;
        }
    }
}

extern "C" void kernel_launch(void* const* d_in, const int* in_sizes, int n_in,
                              void* d_out, int out_size, void* d_ws, size_t ws_size,
                              hipStream_t stream) {
    (void)in_sizes; (void)n_in; (void)out_size; (void)ws_size;
    const float* q   = (const float*)d_in[0];
    const float* kv  = (const float*)d_in[1];
    const float* Wq  = (const float*)d_in[2];
    const float* bq  = (const float*)d_in[3];
    const float* Wk  = (const float*)d_in[4];
    const float* bk  = (const float*)d_in[5];
    const float* Wv  = (const float*)d_in[6];
    const float* bv  = (const float*)d_in[7];
    const float* Wo  = (const float*)d_in[8];
    const float* bo  = (const float*)d_in[9];
    const float* ab  = (const float*)d_in[10];
    const float* ib  = (const float*)d_in[11];
    const float* lt  = (const float*)d_in[12];
    const int*   na  = (const int*)d_in[13];

    char* ws = (char*)d_ws;
    const size_t nQ  = (size_t)B_ * TQ_ * D_;    // 1,048,576
    const size_t nKV = (size_t)B_ * TK_ * D_;    // 16,777,216
    const size_t nW  = (size_t)D_ * D_;          // 1,048,576
    const size_t nML = (size_t)ASPLIT * 2 * B_ * NH_ * TQ_;  // 131,072

    unsigned short* Ah  = (unsigned short*)ws;                 // 33.5 MB
    unsigned short* Whk = Ah + nKV;                            // 2 MB
    unsigned short* Whv = Whk + nW;                            // 2 MB
    unsigned short* Kb  = Whv + nW;                            // 33.5 MB
    unsigned short* Vt  = Kb + nKV;                            // 33.5 MB
    unsigned short* Qb  = Vt + nKV;                            // 2 MB
    unsigned short* qbb = Qb + nQ;                             // 2 MB
    unsigned short* Wqb = qbb + nQ;                            // 2 MB
    unsigned short* Wob = Wqb + nW;                            // 2 MB
    unsigned short* Aob = Wob + nW;                            // 2 MB
    float* pM = (float*)(Aob + nQ);                            // 0.5 MB
    float* pL = pM + nML;                                      // 0.5 MB
    // Ah dead after kv_mfma -> reuse for attention partials (exactly 33.5 MB)
    float* pO = (float*)Ah;

    dim3 blk(256);
    split_w           <<<dim3((int)(nQ / 8 / 256)),  blk, 0, stream>>>(q,  qbb);
    split_w           <<<dim3((int)(nW / 8 / 256)),  blk, 0, stream>>>(Wq, Wqb);
    split_w           <<<dim3((int)(nW / 8 / 256)),  blk, 0, stream>>>(Wo, Wob);
    split_kv          <<<dim3((int)(nKV / 8 / 256)), blk, 0, stream>>>(kv, ab, ib, na, Ah);
    split_w           <<<dim3((int)(nW / 8 / 256)),  blk, 0, stream>>>(Wk, Whk);
    split_w           <<<dim3((int)(nW / 8 / 256)),  blk, 0, stream>>>(Wv, Whv);
    sdpca_gemm_q      <<<dim3(8, 8),                 blk, 0, stream>>>(qbb, Wqb, bq, lt, Qb);
    sdpca_gemm_kv_mfma<<<dim3(1024, 2),              blk, 0, stream>>>(Ah, Whk, Whv, bk, bv, Kb, Vt);
    sdpca_attn_mfma   <<<dim3(TQ_ / 64, B_ * NH_, ASPLIT), blk, 0, stream>>>(Qb, Kb, Vt, na, pO, pM, pL);
    sdpca_combine     <<<dim3((B_ * TQ_ * D_) / 256), blk, 0, stream>>>(pO, pM, pL, na, Aob);
    sdpca_gemm_o      <<<dim3(8, 8),                 blk, 0, stream>>>(Aob, Wob, bo, (float*)d_out);
}

// Round 8
// 289.629 us; speedup vs baseline: 10.6366x; 1.0565x over previous
//
#include <hip/hip_runtime.h>
#include <math.h>
#include <stdint.h>

#define B_   2
#define TQ_  512
#define TK_  8192
#define D_   1024
#define NH_  16
#define HD_  64

#define NEG_BIG (-3.0e38f)
#define ASPLIT 8
#define LOG2E 1.4426950408889634f
#define EXP2F(x) __builtin_exp2f(x)

typedef __attribute__((ext_vector_type(8))) short short8;
typedef __attribute__((ext_vector_type(4))) float f32x4;

// ---------------- bf16 helpers (RNE) ----------------
__device__ __forceinline__ unsigned short f2bf(float x) {
    unsigned u = __float_as_uint(x);
    unsigned r = u + 0x7FFFu + ((u >> 16) & 1u);
    return (unsigned short)(r >> 16);
}

#define GLD16(gp, lp)                                                              \
    __builtin_amdgcn_global_load_lds(                                              \
        (const __attribute__((address_space(1))) unsigned int*)(gp),               \
        (__attribute__((address_space(3))) unsigned int*)(lp), 16, 0, 0)

// ---------------- fp32 -> bf16 conversion (generic, n = grid*256*8) ----------------
__global__ __launch_bounds__(256)
void split_w(const float* __restrict__ W, unsigned short* __restrict__ Wh)
{
    size_t i = ((size_t)blockIdx.x * 256 + threadIdx.x) * 8;
    float4 x0 = *(const float4*)(W + i);
    float4 x1 = *(const float4*)(W + i + 4);
    float a[8] = {x0.x, x0.y, x0.z, x0.w, x1.x, x1.y, x1.z, x1.w};
    union { short8 v; unsigned short u[8]; } H;
#pragma unroll
    for (int j = 0; j < 8; ++j) H.u[j] = f2bf(a[j]);
    *(short8*)(Wh + i) = H.v;
}

// ---------------- bf16 conversion of (kv + group bias) ----------------
__global__ __launch_bounds__(256)
void split_kv(const float* __restrict__ kv, const float* __restrict__ ab,
              const float* __restrict__ ib, const int* __restrict__ nactp,
              unsigned short* __restrict__ Ah)
{
    const int Na = *nactp;
    size_t i = ((size_t)blockIdx.x * 256 + threadIdx.x) * 8;
    int row = (int)(i >> 10);
    int col = (int)(i & (D_ - 1));
    const float* bp = ((row & (TK_ - 1)) < Na) ? ab : ib;
    float4 x0 = *(const float4*)(kv + i);
    float4 x1 = *(const float4*)(kv + i + 4);
    float4 b0 = *(const float4*)(bp + col);
    float4 b1 = *(const float4*)(bp + col + 4);
    float a[8] = {x0.x + b0.x, x0.y + b0.y, x0.z + b0.z, x0.w + b0.w,
                  x1.x + b1.x, x1.y + b1.y, x1.z + b1.z, x1.w + b1.w};
    union { short8 v; unsigned short u[8]; } H;
#pragma unroll
    for (int j = 0; j < 8; ++j) H.u[j] = f2bf(a[j]);
    *(short8*)(Ah + i) = H.v;
}

// ---------------- Q projection, bf16 MFMA; scale folds 1/(64*temp) AND log2e ----------------
__global__ __launch_bounds__(256)
void sdpca_gemm_q(const unsigned short* __restrict__ A, const unsigned short* __restrict__ W,
                  const float* __restrict__ bias, const float* __restrict__ log_temp,
                  unsigned short* __restrict__ Qb)
{
    __shared__ unsigned short AT[128 * 32];
    __shared__ unsigned short BT[128 * 32];
    const int tid  = threadIdx.x;
    const int lane = tid & 63;
    const int w    = tid >> 6;
    const int brow = blockIdx.y * 128;
    const int bcol = blockIdx.x * 128;
    const int wr = w >> 1, wc = w & 1;

    const int   srow = lane >> 2;
    const int   scol = (lane & 3) * 8;
    const size_t gA0 = (size_t)(brow + w * 32 + srow) * D_ + scol;
    const size_t gA1 = gA0 + (size_t)16 * D_;
    const size_t gB0 = (size_t)(bcol + w * 32 + srow) * D_ + scol;
    const size_t gB1 = gB0 + (size_t)16 * D_;
    const int   l0   = (w * 32 +  0) * 32;
    const int   l1   = (w * 32 + 16) * 32;

    f32x4 acc[4][4];
#pragma unroll
    for (int m = 0; m < 4; ++m)
#pragma unroll
        for (int n = 0; n < 4; ++n) acc[m][n] = (f32x4){0.f, 0.f, 0.f, 0.f};

    const int frow = lane & 15;
    const int fko  = (lane >> 4) * 8;

    for (int k0 = 0; k0 < D_; k0 += 32) {
        GLD16(A + gA0 + k0, &AT[l0]);
        GLD16(A + gA1 + k0, &AT[l1]);
        GLD16(W + gB0 + k0, &BT[l0]);
        GLD16(W + gB1 + k0, &BT[l1]);
        __syncthreads();
        short8 bf[4];
#pragma unroll
        for (int n = 0; n < 4; ++n)
            bf[n] = *(const short8*)&BT[(wc * 64 + n * 16 + frow) * 32 + fko];
#pragma unroll
        for (int m = 0; m < 4; ++m) {
            short8 a = *(const short8*)&AT[(wr * 64 + m * 16 + frow) * 32 + fko];
#pragma unroll
            for (int n = 0; n < 4; ++n)
                acc[m][n] = __builtin_amdgcn_mfma_f32_16x16x32_bf16(a, bf[n], acc[m][n], 0, 0, 0);
        }
        __syncthreads();
    }

    float lt    = *log_temp;
    float temp  = fminf(fmaxf(expf(lt), 0.1f), 10.0f);
    float scale = LOG2E / (64.0f * temp);   // scores land in log2 domain

#pragma unroll
    for (int n = 0; n < 4; ++n) {
        int col = bcol + wc * 64 + n * 16 + frow;
        float bsv = bias[col];
#pragma unroll
        for (int m = 0; m < 4; ++m) {
            int rbase = brow + wr * 64 + m * 16 + (lane >> 4) * 4;
#pragma unroll
            for (int r = 0; r < 4; ++r)
                Qb[(size_t)(rbase + r) * D_ + col] = f2bf((acc[m][n][r] + bsv) * scale);
        }
    }
}

// ---------------- K/V projection via bf16 MFMA, z picks K or V; V written transposed ----------------
__global__ __launch_bounds__(256)
void sdpca_gemm_kv_mfma(const unsigned short* __restrict__ Ah,
                        const unsigned short* __restrict__ Whk,
                        const unsigned short* __restrict__ Whv,
                        const float* __restrict__ bk, const float* __restrict__ bv,
                        unsigned short* __restrict__ Kb, unsigned short* __restrict__ Vt)
{
    __shared__ unsigned short AT[128 * 32];
    __shared__ unsigned short BT[128 * 32];

    const int tid  = threadIdx.x;
    const int lane = tid & 63;
    const int w    = tid >> 6;
    const int bid  = blockIdx.x;
    const int lid  = (bid & 7) * 128 + (bid >> 3);
    const int brow = (lid >> 3) * 128;
    const int bcol = (lid & 7) * 128;
    const int z    = blockIdx.y;

    const unsigned short* Wh = z ? Whv : Whk;
    const float* bias        = z ? bv  : bk;

    const int wr = w >> 1, wc = w & 1;

    const int   srow = lane >> 2;
    const int   scol = (lane & 3) * 8;
    const size_t gA0 = (size_t)(brow + w * 32 + srow) * D_ + scol;
    const size_t gA1 = gA0 + (size_t)16 * D_;
    const size_t gB0 = (size_t)(bcol + w * 32 + srow) * D_ + scol;
    const size_t gB1 = gB0 + (size_t)16 * D_;
    const int   l0   = (w * 32 +  0) * 32;
    const int   l1   = (w * 32 + 16) * 32;

    f32x4 acc[4][4];
#pragma unroll
    for (int m = 0; m < 4; ++m)
#pragma unroll
        for (int n = 0; n < 4; ++n) acc[m][n] = (f32x4){0.f, 0.f, 0.f, 0.f};

    const int frow = lane & 15;
    const int fko  = (lane >> 4) * 8;

    for (int k0 = 0; k0 < D_; k0 += 32) {
        GLD16(Ah + gA0 + k0, &AT[l0]);
        GLD16(Ah + gA1 + k0, &AT[l1]);
        GLD16(Wh + gB0 + k0, &BT[l0]);
        GLD16(Wh + gB1 + k0, &BT[l1]);
        __syncthreads();
        short8 bf[4];
#pragma unroll
        for (int n = 0; n < 4; ++n)
            bf[n] = *(const short8*)&BT[(wc * 64 + n * 16 + frow) * 32 + fko];
#pragma unroll
        for (int m = 0; m < 4; ++m) {
            short8 a = *(const short8*)&AT[(wr * 64 + m * 16 + frow) * 32 + fko];
#pragma unroll
            for (int n = 0; n < 4; ++n)
                acc[m][n] = __builtin_amdgcn_mfma_f32_16x16x32_bf16(a, bf[n], acc[m][n], 0, 0, 0);
        }
        __syncthreads();
    }

    if (z == 0) {
#pragma unroll
        for (int n = 0; n < 4; ++n) {
            int col = bcol + wc * 64 + n * 16 + frow;
            float bsv = bias[col];
#pragma unroll
            for (int m = 0; m < 4; ++m) {
                int rbase = brow + wr * 64 + m * 16 + (lane >> 4) * 4;
#pragma unroll
                for (int r = 0; r < 4; ++r)
                    Kb[(size_t)(rbase + r) * D_ + col] = f2bf(acc[m][n][r] + bsv);
            }
        }
    } else {
#pragma unroll
        for (int n = 0; n < 4; ++n) {
            int col = bcol + wc * 64 + n * 16 + frow;
            int h   = col >> 6, d = col & 63;
            float bsv = bias[col];
#pragma unroll
            for (int m = 0; m < 4; ++m) {
                int rbase = brow + wr * 64 + m * 16 + (lane >> 4) * 4;
                int b     = rbase >> 13;
                int tok   = rbase & (TK_ - 1);
                ushort4 o;
                o.x = f2bf(acc[m][n][0] + bsv);
                o.y = f2bf(acc[m][n][1] + bsv);
                o.z = f2bf(acc[m][n][2] + bsv);
                o.w = f2bf(acc[m][n][3] + bsv);
                *(ushort4*)&Vt[((size_t)(b * 16 + h) * 64 + d) * TK_ + tok] = o;
            }
        }
    }
}

// ---------------- MFMA flash attention, two groups, split-K ----------------
// log2-domain online softmax (Q pre-scaled by log2e), defer-max THR=8,
// FULL template picks unmasked fast path, P packed via v_cvt_pk_bf16_f32.
template<bool FULL>
__device__ __forceinline__ void attn_pass(
    const f32x4 st[4], int jb, int lo, int hi,
    float& mst, float& lst, f32x4 o[4],
    unsigned short* Ps, const unsigned short* Vs,
    int frow, int g, int w)
{
    const int q = w * 16 + frow;
    float pmax = NEG_BIG;
#pragma unroll
    for (int mt = 0; mt < 4; ++mt)
#pragma unroll
        for (int r = 0; r < 4; ++r) {
            if (FULL) pmax = fmaxf(pmax, st[mt][r]);
            else {
                int key = jb + mt * 16 + g * 4 + r;
                if (key >= lo && key < hi) pmax = fmaxf(pmax, st[mt][r]);
            }
        }
    pmax = fmaxf(pmax, __shfl_xor(pmax, 16, 64));
    pmax = fmaxf(pmax, __shfl_xor(pmax, 32, 64));

    if (!__all(pmax - mst <= 8.0f)) {       // defer-max: rescale only when needed
        const float mnew = fmaxf(mst, pmax);
        const float corr = EXP2F(mst - mnew);
        lst *= corr;
#pragma unroll
        for (int mt = 0; mt < 4; ++mt) {
            o[mt][0] *= corr; o[mt][1] *= corr; o[mt][2] *= corr; o[mt][3] *= corr;
        }
        mst = mnew;
    }

    float p[4][4];
    float psum = 0.f;
#pragma unroll
    for (int mt = 0; mt < 4; ++mt)
#pragma unroll
        for (int r = 0; r < 4; ++r) {
            float pv;
            if (FULL) pv = EXP2F(st[mt][r] - mst);
            else {
                int key = jb + mt * 16 + g * 4 + r;
                pv = (key >= lo && key < hi) ? EXP2F(st[mt][r] - mst) : 0.f;
            }
            p[mt][r] = pv; psum += pv;
        }
    psum += __shfl_xor(psum, 16, 64);
    psum += __shfl_xor(psum, 32, 64);
    lst += psum;

#pragma unroll
    for (int mt = 0; mt < 4; ++mt) {
        unsigned u0, u1;
        asm("v_cvt_pk_bf16_f32 %0, %1, %2" : "=v"(u0) : "v"(p[mt][0]), "v"(p[mt][1]));
        asm("v_cvt_pk_bf16_f32 %0, %1, %2" : "=v"(u1) : "v"(p[mt][2]), "v"(p[mt][3]));
        unsigned* dst = (unsigned*)((char*)Ps + q * 144 + (mt * 16 + g * 4) * 2);
        dst[0] = u0; dst[1] = u1;
    }
    __builtin_amdgcn_sched_barrier(0);   // keep PV reads after P writes
#pragma unroll
    for (int mt = 0; mt < 4; ++mt) {
        int row = mt * 16 + frow;
        int rs  = (row & 7) << 4;
#pragma unroll
        for (int ks = 0; ks < 2; ++ks) {
            short8 a = *(const short8*)((const char*)Vs + row * 128 + ((ks * 64 + g * 16) ^ rs));
            short8 bfr = *(const short8*)((const char*)Ps + q * 144 + ks * 64 + g * 16);
            o[mt] = __builtin_amdgcn_mfma_f32_16x16x32_bf16(a, bfr, o[mt], 0, 0, 0);
        }
    }
}

__global__ __launch_bounds__(256)
void sdpca_attn_mfma(const unsigned short* __restrict__ Qb,
                     const unsigned short* __restrict__ Kb,
                     const unsigned short* __restrict__ Vt,
                     const int* __restrict__ nactp,
                     float* __restrict__ pO, float* __restrict__ pM, float* __restrict__ pL)
{
    __shared__ char smem[25600];
    unsigned short* Ks = (unsigned short*)smem;
    unsigned short* Vs = (unsigned short*)(smem + 8192);
    unsigned short* Ps = (unsigned short*)(smem + 16384);
    float*          Ot = (float*)smem;

    const int tid  = threadIdx.x;
    const int l    = tid & 63, w = tid >> 6;
    const int frow = l & 15,  g = l >> 4;

    // XCD-swizzled flat grid (2048 blocks, 2048%8==0): the 8 q0-blocks sharing
    // one (bh,s) K/V panel are consecutive in lid -> same XCD's L2.
    const int bid = blockIdx.x;
    const int lid = (bid & 7) * 256 + (bid >> 3);
    const int q0  = (lid & 7) * 64;
    const int bh  = (lid >> 3) & 31;
    const int s   = lid >> 8;
    const int b   = bh >> 4, h = bh & 15;

    const int Na   = *nactp;
    const int ks0  = s * (TK_ / ASPLIT);
    const int nt   = TK_ / ASPLIT / 64;

    short8 qf0, qf1;
    {
        const unsigned short* qp = Qb + (size_t)(b * TQ_ + q0 + w * 16 + frow) * D_ + h * HD_;
        qf0 = *(const short8*)(qp + g * 8);
        qf1 = *(const short8*)(qp + 32 + g * 8);
    }

    float mA = NEG_BIG, lA = 0.f, mI = NEG_BIG, lI = 0.f;
    f32x4 oA[4], oI[4];
#pragma unroll
    for (int mt = 0; mt < 4; ++mt) {
        oA[mt] = (f32x4){0.f, 0.f, 0.f, 0.f};
        oI[mt] = (f32x4){0.f, 0.f, 0.f, 0.f};
    }

    const int srow = tid >> 2;
    const int scb  = (tid & 3) * 32;
    const unsigned short* kg = Kb + (size_t)(b * TK_ + ks0 + srow) * D_ + h * HD_ + (tid & 3) * 16;
    const unsigned short* vg = Vt + ((size_t)bh * HD_ + srow) * TK_ + ks0 + (tid & 3) * 16;
    const int kswz0 = srow * 128 + ((scb +  0) ^ ((srow & 7) << 4));
    const int kswz1 = srow * 128 + ((scb + 16) ^ ((srow & 7) << 4));

    for (int t = 0; t < nt; ++t) {
        const int jb = ks0 + t * 64;
        short8 kr0 = *(const short8*)(kg);
        short8 kr1 = *(const short8*)(kg + 8);
        short8 vr0 = *(const short8*)(vg);
        short8 vr1 = *(const short8*)(vg + 8);
        kg += (size_t)64 * D_;
        vg += 64;
        __syncthreads();
        *(short8*)((char*)Ks + kswz0) = kr0;
        *(short8*)((char*)Ks + kswz1) = kr1;
        *(short8*)((char*)Vs + kswz0) = vr0;
        *(short8*)((char*)Vs + kswz1) = vr1;
        __syncthreads();

        f32x4 st[4];
#pragma unroll
        for (int mt = 0; mt < 4; ++mt) {
            int row = mt * 16 + frow;
            int rs  = (row & 7) << 4;
            short8 a0 = *(const short8*)((const char*)Ks + row * 128 + ((g * 16) ^ rs));
            short8 a1 = *(const short8*)((const char*)Ks + row * 128 + ((64 + g * 16) ^ rs));
            f32x4 acc = (f32x4){0.f, 0.f, 0.f, 0.f};
            acc = __builtin_amdgcn_mfma_f32_16x16x32_bf16(a0, qf0, acc, 0, 0, 0);
            acc = __builtin_amdgcn_mfma_f32_16x16x32_bf16(a1, qf1, acc, 0, 0, 0);
            st[mt] = acc;
        }

        const bool hasA = (jb < Na);
        const bool hasI = (jb + 64 > Na);
        if (hasA) {
            if (jb + 64 <= Na) attn_pass<true >(st, jb, 0, Na, mA, lA, oA, Ps, Vs, frow, g, w);
            else               attn_pass<false>(st, jb, 0, Na, mA, lA, oA, Ps, Vs, frow, g, w);
        }
        if (hasI) {
            if (jb >= Na)      attn_pass<true >(st, jb, Na, TK_, mI, lI, oI, Ps, Vs, frow, g, w);
            else               attn_pass<false>(st, jb, Na, TK_, mI, lI, oI, Ps, Vs, frow, g, w);
        }
    }

    const int q = w * 16 + frow;
#pragma unroll
    for (int grp = 0; grp < 2; ++grp) {
        __syncthreads();
        const f32x4* o = grp ? oI : oA;
#pragma unroll
        for (int mt = 0; mt < 4; ++mt)
            *(f32x4*)&Ot[q * 68 + mt * 16 + g * 4] = o[mt];
        if (g == 0) {
            size_t base = ((size_t)((s * 2 + grp) * (B_ * NH_) + bh)) * TQ_ + q0 + q;
            pM[base] = grp ? mI : mA;
            pL[base] = grp ? lI : lA;
        }
        __syncthreads();
        {
            int qr = tid >> 2, dc = (tid & 3) * 16;
            size_t rowbase = ((size_t)((s * 2 + grp) * (B_ * NH_) + bh)) * TQ_ + q0 + qr;
            float* dst = pO + rowbase * HD_ + dc;
#pragma unroll
            for (int u = 0; u < 4; ++u)
                *(float4*)(dst + 4 * u) = *(const float4*)&Ot[qr * 68 + dc + 4 * u];
        }
    }
}

// ---------------- split-K merge over ASPLIT partials (log2 domain), bf16 out ----------------
__global__ __launch_bounds__(256)
void sdpca_combine(const float* __restrict__ pO, const float* __restrict__ pM,
                   const float* __restrict__ pL, const int* __restrict__ nactp,
                   unsigned short* __restrict__ Aob)
{
    int idx = blockIdx.x * 256 + threadIdx.x;
    int d   = idx & (HD_ - 1);
    int q   = (idx >> 6) & (TQ_ - 1);
    int bh  = idx >> 15;
    int b   = bh >> 4, h = bh & 15;
    int Na  = *nactp;
    int Ni  = TK_ - Na;

    float res = 0.f;
#pragma unroll
    for (int gg = 0; gg < 2; ++gg) {
        float M = NEG_BIG;
#pragma unroll
        for (int ss = 0; ss < ASPLIT; ++ss) {
            size_t ii = ((size_t)((ss * 2 + gg) * (B_ * NH_) + bh)) * TQ_ + q;
            M = fmaxf(M, pM[ii]);
        }
        float L = 0.f, O = 0.f;
#pragma unroll
        for (int ss = 0; ss < ASPLIT; ++ss) {
            size_t ii = ((size_t)((ss * 2 + gg) * (B_ * NH_) + bh)) * TQ_ + q;
            float ww = EXP2F(pM[ii] - M);
            L += pL[ii] * ww;
            O += pO[ii * HD_ + d] * ww;
        }
        float r   = (L > 0.f) ? (O / L) : 0.f;
        int   cnt = (gg == 0) ? Na : Ni;
        float sc  = (cnt > 0) ? rsqrtf((float)cnt) : 0.f;
        res += (gg == 0) ? (sc * r) : (-sc * r);
    }
    Aob[((size_t)(b * TQ_ + q)) * D_ + h * HD_ + d] = f2bf(res);
}

// ---------------- output projection, bf16 MFMA, fp32 out ----------------
__global__ __launch_bounds__(256)
void sdpca_gemm_o(const unsigned short* __restrict__ A, const unsigned short* __restrict__ W,
                  const float* __restrict__ bias, float* __restrict__ C)
{
    __shared__ unsigned short AT[128 * 32];
    __shared__ unsigned short BT[128 * 32];
    const int tid  = threadIdx.x;
    const int lane = tid & 63;
    const int w    = tid >> 6;
    const int brow = blockIdx.y * 128;
    const int bcol = blockIdx.x * 128;
    const int wr = w >> 1, wc = w & 1;

    const int   srow = lane >> 2;
    const int   scol = (lane & 3) * 8;
    const size_t gA0 = (size_t)(brow + w * 32 + srow) * D_ + scol;
    const size_t gA1 = gA0 + (size_t)16 * D_;
    const size_t gB0 = (size_t)(bcol + w * 32 + srow) * D_ + scol;
    const size_t gB1 = gB0 + (size_t)16 * D_;
    const int   l0   = (w * 32 +  0) * 32;
    const int   l1   = (w * 32 + 16) * 32;

    f32x4 acc[4][4];
#pragma unroll
    for (int m = 0; m < 4; ++m)
#pragma unroll
        for (int n = 0; n < 4; ++n) acc[m][n] = (f32x4){0.f, 0.f, 0.f, 0.f};

    const int frow = lane & 15;
    const int fko  = (lane >> 4) * 8;

    for (int k0 = 0; k0 < D_; k0 += 32) {
        GLD16(A + gA0 + k0, &AT[l0]);
        GLD16(A + gA1 + k0, &AT[l1]);
        GLD16(W + gB0 + k0, &BT[l0]);
        GLD16(W + gB1 + k0, &BT[l1]);
        __syncthreads();
        short8 bf[4];
#pragma unroll
        for (int n = 0; n < 4; ++n)
            bf[n] = *(const short8*)&BT[(wc * 64 + n * 16 + frow) * 32 + fko];
#pragma unroll
        for (int m = 0; m < 4; ++m) {
            short8 a = *(const short8*)&AT[(wr * 64 + m * 16 + frow) * 32 + fko];
#pragma unroll
            for (int n = 0; n < 4; ++n)
                acc[m][n] = __builtin_amdgcn_mfma_f32_16x16x32_bf16(a, bf[n], acc[m][n], 0, 0, 0);
        }
        __syncthreads();
    }

#pragma unroll
    for (int n = 0; n < 4; ++n) {
        int col = bcol + wc * 64 + n * 16 + frow;
        float bsv = bias[col];
#pragma unroll
        for (int m = 0; m < 4; ++m) {
            int rbase = brow + wr * 64 + m * 16 + (lane >> 4) * 4;
#pragma unroll
            for (int r = 0; r < 4; ++r)
                C[(size_t)(rbase + r) * D_ + col] = acc[m][n][r] + bsv;
        }
    }
}

extern "C" void kernel_launch(void* const* d_in, const int* in_sizes, int n_in,
                              void* d_out, int out_size, void* d_ws, size_t ws_size,
                              hipStream_t stream) {
    (void)in_sizes; (void)n_in; (void)out_size; (void)ws_size;
    const float* q   = (const float*)d_in[0];
    const float* kv  = (const float*)d_in[1];
    const float* Wq  = (const float*)d_in[2];
    const float* bq  = (const float*)d_in[3];
    const float* Wk  = (const float*)d_in[4];
    const float* bk  = (const float*)d_in[5];
    const float* Wv  = (const float*)d_in[6];
    const float* bv  = (const float*)d_in[7];
    const float* Wo  = (const float*)d_in[8];
    const float* bo  = (const float*)d_in[9];
    const float* ab  = (const float*)d_in[10];
    const float* ib  = (const float*)d_in[11];
    const float* lt  = (const float*)d_in[12];
    const int*   na  = (const int*)d_in[13];

    char* ws = (char*)d_ws;
    const size_t nQ  = (size_t)B_ * TQ_ * D_;    // 1,048,576
    const size_t nKV = (size_t)B_ * TK_ * D_;    // 16,777,216
    const size_t nW  = (size_t)D_ * D_;          // 1,048,576
    const size_t nML = (size_t)ASPLIT * 2 * B_ * NH_ * TQ_;  // 262,144

    unsigned short* Ah  = (unsigned short*)ws;                 // 33.5 MB
    unsigned short* Whk = Ah + nKV;                            // 2 MB
    unsigned short* Whv = Whk + nW;                            // 2 MB
    unsigned short* Kb  = Whv + nW;                            // 33.5 MB
    unsigned short* Vt  = Kb + nKV;                            // 33.5 MB
    unsigned short* Qb  = Vt + nKV;                            // 2 MB
    unsigned short* qbb = Qb + nQ;                             // 2 MB
    unsigned short* Wqb = qbb + nQ;                            // 2 MB
    unsigned short* Wob = Wqb + nW;                            // 2 MB
    unsigned short* Aob = Wob + nW;                            // 2 MB
    float* pM = (float*)(Aob + nQ);                            // 1 MB
    float* pL = pM + nML;                                      // 1 MB
    float* pO = pL + nML;                                      // ASPLIT*2*nQ fp32 = 67 MB
    // total ~182 MB (round 3 proved >= 213 MB available)

    dim3 blk(256);
    split_w           <<<dim3((int)(nQ / 8 / 256)),  blk, 0, stream>>>(q,  qbb);
    split_w           <<<dim3((int)(nW / 8 / 256)),  blk, 0, stream>>>(Wq, Wqb);
    split_w           <<<dim3((int)(nW / 8 / 256)),  blk, 0, stream>>>(Wo, Wob);
    split_kv          <<<dim3((int)(nKV / 8 / 256)), blk, 0, stream>>>(kv, ab, ib, na, Ah);
    split_w           <<<dim3((int)(nW / 8 / 256)),  blk, 0, stream>>>(Wk, Whk);
    split_w           <<<dim3((int)(nW / 8 / 256)),  blk, 0, stream>>>(Wv, Whv);
    sdpca_gemm_q      <<<dim3(8, 8),                 blk, 0, stream>>>(qbb, Wqb, bq, lt, Qb);
    sdpca_gemm_kv_mfma<<<dim3(1024, 2),              blk, 0, stream>>>(Ah, Whk, Whv, bk, bv, Kb, Vt);
    sdpca_attn_mfma   <<<dim3(2048),                 blk, 0, stream>>>(Qb, Kb, Vt, na, pO, pM, pL);
    sdpca_combine     <<<dim3((B_ * TQ_ * D_) / 256), blk, 0, stream>>>(pO, pM, pL, na, Aob);
    sdpca_gemm_o      <<<dim3(8, 8),                 blk, 0, stream>>>(Aob, Wob, bo, (float*)d_out);
}

// Round 9
// 261.321 us; speedup vs baseline: 11.7889x; 1.1083x over previous
//
#include <hip/hip_runtime.h>
#include <math.h>
#include <stdint.h>

#define B_   2
#define TQ_  512
#define TK_  8192
#define D_   1024
#define NH_  16
#define HD_  64

#define NEG_BIG (-3.0e38f)
#define ASPLIT 8
#define LOG2E 1.4426950408889634f
#define EXP2F(x) __builtin_exp2f(x)

typedef __attribute__((ext_vector_type(8))) short short8;
typedef __attribute__((ext_vector_type(4))) float f32x4;

// ---------------- bf16 helpers (RNE) ----------------
__device__ __forceinline__ unsigned short f2bf(float x) {
    unsigned u = __float_as_uint(x);
    unsigned r = u + 0x7FFFu + ((u >> 16) & 1u);
    return (unsigned short)(r >> 16);
}

#define GLD16(gp, lp)                                                              \
    __builtin_amdgcn_global_load_lds(                                              \
        (const __attribute__((address_space(1))) unsigned int*)(gp),               \
        (__attribute__((address_space(3))) unsigned int*)(lp), 16, 0, 0)

// ---------------- fp32 -> bf16 conversion (generic, n = grid*256*8) ----------------
__global__ __launch_bounds__(256)
void split_w(const float* __restrict__ W, unsigned short* __restrict__ Wh)
{
    size_t i = ((size_t)blockIdx.x * 256 + threadIdx.x) * 8;
    float4 x0 = *(const float4*)(W + i);
    float4 x1 = *(const float4*)(W + i + 4);
    float a[8] = {x0.x, x0.y, x0.z, x0.w, x1.x, x1.y, x1.z, x1.w};
    union { short8 v; unsigned short u[8]; } H;
#pragma unroll
    for (int j = 0; j < 8; ++j) H.u[j] = f2bf(a[j]);
    *(short8*)(Wh + i) = H.v;
}

// ---------------- bf16 conversion of (kv + group bias) ----------------
__global__ __launch_bounds__(256)
void split_kv(const float* __restrict__ kv, const float* __restrict__ ab,
              const float* __restrict__ ib, const int* __restrict__ nactp,
              unsigned short* __restrict__ Ah)
{
    const int Na = *nactp;
    size_t i = ((size_t)blockIdx.x * 256 + threadIdx.x) * 8;
    int row = (int)(i >> 10);
    int col = (int)(i & (D_ - 1));
    const float* bp = ((row & (TK_ - 1)) < Na) ? ab : ib;
    float4 x0 = *(const float4*)(kv + i);
    float4 x1 = *(const float4*)(kv + i + 4);
    float4 b0 = *(const float4*)(bp + col);
    float4 b1 = *(const float4*)(bp + col + 4);
    float a[8] = {x0.x + b0.x, x0.y + b0.y, x0.z + b0.z, x0.w + b0.w,
                  x1.x + b1.x, x1.y + b1.y, x1.z + b1.z, x1.w + b1.w};
    union { short8 v; unsigned short u[8]; } H;
#pragma unroll
    for (int j = 0; j < 8; ++j) H.u[j] = f2bf(a[j]);
    *(short8*)(Ah + i) = H.v;
}

// ---------------- Q projection, bf16 MFMA; scale folds 1/(64*temp) AND log2e ----------------
__global__ __launch_bounds__(256)
void sdpca_gemm_q(const unsigned short* __restrict__ A, const unsigned short* __restrict__ W,
                  const float* __restrict__ bias, const float* __restrict__ log_temp,
                  unsigned short* __restrict__ Qb)
{
    __shared__ unsigned short AT[128 * 32];
    __shared__ unsigned short BT[128 * 32];
    const int tid  = threadIdx.x;
    const int lane = tid & 63;
    const int w    = tid >> 6;
    const int brow = blockIdx.y * 128;
    const int bcol = blockIdx.x * 128;
    const int wr = w >> 1, wc = w & 1;

    const int   srow = lane >> 2;
    const int   scol = (lane & 3) * 8;
    const size_t gA0 = (size_t)(brow + w * 32 + srow) * D_ + scol;
    const size_t gA1 = gA0 + (size_t)16 * D_;
    const size_t gB0 = (size_t)(bcol + w * 32 + srow) * D_ + scol;
    const size_t gB1 = gB0 + (size_t)16 * D_;
    const int   l0   = (w * 32 +  0) * 32;
    const int   l1   = (w * 32 + 16) * 32;

    f32x4 acc[4][4];
#pragma unroll
    for (int m = 0; m < 4; ++m)
#pragma unroll
        for (int n = 0; n < 4; ++n) acc[m][n] = (f32x4){0.f, 0.f, 0.f, 0.f};

    const int frow = lane & 15;
    const int fko  = (lane >> 4) * 8;

    for (int k0 = 0; k0 < D_; k0 += 32) {
        GLD16(A + gA0 + k0, &AT[l0]);
        GLD16(A + gA1 + k0, &AT[l1]);
        GLD16(W + gB0 + k0, &BT[l0]);
        GLD16(W + gB1 + k0, &BT[l1]);
        __syncthreads();
        short8 bf[4];
#pragma unroll
        for (int n = 0; n < 4; ++n)
            bf[n] = *(const short8*)&BT[(wc * 64 + n * 16 + frow) * 32 + fko];
#pragma unroll
        for (int m = 0; m < 4; ++m) {
            short8 a = *(const short8*)&AT[(wr * 64 + m * 16 + frow) * 32 + fko];
#pragma unroll
            for (int n = 0; n < 4; ++n)
                acc[m][n] = __builtin_amdgcn_mfma_f32_16x16x32_bf16(a, bf[n], acc[m][n], 0, 0, 0);
        }
        __syncthreads();
    }

    float lt    = *log_temp;
    float temp  = fminf(fmaxf(expf(lt), 0.1f), 10.0f);
    float scale = LOG2E / (64.0f * temp);   // scores land in log2 domain

#pragma unroll
    for (int n = 0; n < 4; ++n) {
        int col = bcol + wc * 64 + n * 16 + frow;
        float bsv = bias[col];
#pragma unroll
        for (int m = 0; m < 4; ++m) {
            int rbase = brow + wr * 64 + m * 16 + (lane >> 4) * 4;
#pragma unroll
            for (int r = 0; r < 4; ++r)
                Qb[(size_t)(rbase + r) * D_ + col] = f2bf((acc[m][n][r] + bsv) * scale);
        }
    }
}

// ---------------- K/V projection via bf16 MFMA, z picks K or V; V written transposed ----------------
__global__ __launch_bounds__(256)
void sdpca_gemm_kv_mfma(const unsigned short* __restrict__ Ah,
                        const unsigned short* __restrict__ Whk,
                        const unsigned short* __restrict__ Whv,
                        const float* __restrict__ bk, const float* __restrict__ bv,
                        unsigned short* __restrict__ Kb, unsigned short* __restrict__ Vt)
{
    __shared__ unsigned short AT[128 * 32];
    __shared__ unsigned short BT[128 * 32];

    const int tid  = threadIdx.x;
    const int lane = tid & 63;
    const int w    = tid >> 6;
    const int bid  = blockIdx.x;
    const int lid  = (bid & 7) * 128 + (bid >> 3);
    const int brow = (lid >> 3) * 128;
    const int bcol = (lid & 7) * 128;
    const int z    = blockIdx.y;

    const unsigned short* Wh = z ? Whv : Whk;
    const float* bias        = z ? bv  : bk;

    const int wr = w >> 1, wc = w & 1;

    const int   srow = lane >> 2;
    const int   scol = (lane & 3) * 8;
    const size_t gA0 = (size_t)(brow + w * 32 + srow) * D_ + scol;
    const size_t gA1 = gA0 + (size_t)16 * D_;
    const size_t gB0 = (size_t)(bcol + w * 32 + srow) * D_ + scol;
    const size_t gB1 = gB0 + (size_t)16 * D_;
    const int   l0   = (w * 32 +  0) * 32;
    const int   l1   = (w * 32 + 16) * 32;

    f32x4 acc[4][4];
#pragma unroll
    for (int m = 0; m < 4; ++m)
#pragma unroll
        for (int n = 0; n < 4; ++n) acc[m][n] = (f32x4){0.f, 0.f, 0.f, 0.f};

    const int frow = lane & 15;
    const int fko  = (lane >> 4) * 8;

    for (int k0 = 0; k0 < D_; k0 += 32) {
        GLD16(Ah + gA0 + k0, &AT[l0]);
        GLD16(Ah + gA1 + k0, &AT[l1]);
        GLD16(Wh + gB0 + k0, &BT[l0]);
        GLD16(Wh + gB1 + k0, &BT[l1]);
        __syncthreads();
        short8 bf[4];
#pragma unroll
        for (int n = 0; n < 4; ++n)
            bf[n] = *(const short8*)&BT[(wc * 64 + n * 16 + frow) * 32 + fko];
#pragma unroll
        for (int m = 0; m < 4; ++m) {
            short8 a = *(const short8*)&AT[(wr * 64 + m * 16 + frow) * 32 + fko];
#pragma unroll
            for (int n = 0; n < 4; ++n)
                acc[m][n] = __builtin_amdgcn_mfma_f32_16x16x32_bf16(a, bf[n], acc[m][n], 0, 0, 0);
        }
        __syncthreads();
    }

    if (z == 0) {
#pragma unroll
        for (int n = 0; n < 4; ++n) {
            int col = bcol + wc * 64 + n * 16 + frow;
            float bsv = bias[col];
#pragma unroll
            for (int m = 0; m < 4; ++m) {
                int rbase = brow + wr * 64 + m * 16 + (lane >> 4) * 4;
#pragma unroll
                for (int r = 0; r < 4; ++r)
                    Kb[(size_t)(rbase + r) * D_ + col] = f2bf(acc[m][n][r] + bsv);
            }
        }
    } else {
#pragma unroll
        for (int n = 0; n < 4; ++n) {
            int col = bcol + wc * 64 + n * 16 + frow;
            int h   = col >> 6, d = col & 63;
            float bsv = bias[col];
#pragma unroll
            for (int m = 0; m < 4; ++m) {
                int rbase = brow + wr * 64 + m * 16 + (lane >> 4) * 4;
                int b     = rbase >> 13;
                int tok   = rbase & (TK_ - 1);
                ushort4 o;
                o.x = f2bf(acc[m][n][0] + bsv);
                o.y = f2bf(acc[m][n][1] + bsv);
                o.z = f2bf(acc[m][n][2] + bsv);
                o.w = f2bf(acc[m][n][3] + bsv);
                *(ushort4*)&Vt[((size_t)(b * 16 + h) * 64 + d) * TK_ + tok] = o;
            }
        }
    }
}

// ---------------- MFMA flash attention, fixed-max (m=0) softmax ----------------
// Scores are structurally tiny (|s*log2e| << 1); softmax is shift-invariant, so
// m=0 is exact math with no overflow risk below |s|~120. No max tracking, no
// cross-lane ops in the loop. l computed on the MFMA pipe via all-ones A-frag
// (every acc row = column-sum of P). P: exp2 -> cvt_pk -> wave-private LDS.
template<bool FULL>
__device__ __forceinline__ void attn_pass(
    const f32x4 st[4], int jb, int lo, int hi,
    f32x4& lacc, f32x4 o[4],
    unsigned short* Ps, const unsigned short* Vs,
    int frow, int g, int w)
{
    const int q = w * 16 + frow;
    const short8 kOnes = {(short)0x3F80, (short)0x3F80, (short)0x3F80, (short)0x3F80,
                          (short)0x3F80, (short)0x3F80, (short)0x3F80, (short)0x3F80};
    float p[4][4];
#pragma unroll
    for (int mt = 0; mt < 4; ++mt)
#pragma unroll
        for (int r = 0; r < 4; ++r) {
            float pv = EXP2F(st[mt][r]);
            if (!FULL) {
                int key = jb + mt * 16 + g * 4 + r;
                if (key < lo || key >= hi) pv = 0.f;
            }
            p[mt][r] = pv;
        }

#pragma unroll
    for (int mt = 0; mt < 4; ++mt) {
        unsigned u0, u1;
        asm("v_cvt_pk_bf16_f32 %0, %1, %2" : "=v"(u0) : "v"(p[mt][0]), "v"(p[mt][1]));
        asm("v_cvt_pk_bf16_f32 %0, %1, %2" : "=v"(u1) : "v"(p[mt][2]), "v"(p[mt][3]));
        unsigned* dst = (unsigned*)((char*)Ps + q * 144 + (mt * 16 + g * 4) * 2);
        dst[0] = u0; dst[1] = u1;
    }
    __builtin_amdgcn_sched_barrier(0);   // keep PV reads after P writes

    short8 pb[2];
#pragma unroll
    for (int ks = 0; ks < 2; ++ks)
        pb[ks] = *(const short8*)((const char*)Ps + q * 144 + ks * 64 + g * 16);
#pragma unroll
    for (int mt = 0; mt < 4; ++mt) {
        int row = mt * 16 + frow;
        int rs  = (row & 7) << 4;
#pragma unroll
        for (int ks = 0; ks < 2; ++ks) {
            short8 a = *(const short8*)((const char*)Vs + row * 128 + ((ks * 64 + g * 16) ^ rs));
            o[mt] = __builtin_amdgcn_mfma_f32_16x16x32_bf16(a, pb[ks], o[mt], 0, 0, 0);
        }
    }
#pragma unroll
    for (int ks = 0; ks < 2; ++ks)
        lacc = __builtin_amdgcn_mfma_f32_16x16x32_bf16(kOnes, pb[ks], lacc, 0, 0, 0);
}

__global__ __launch_bounds__(256)
void sdpca_attn_mfma(const unsigned short* __restrict__ Qb,
                     const unsigned short* __restrict__ Kb,
                     const unsigned short* __restrict__ Vt,
                     const int* __restrict__ nactp,
                     float* __restrict__ pO, float* __restrict__ pL)
{
    __shared__ char smem[25600];
    unsigned short* Ks = (unsigned short*)smem;
    unsigned short* Vs = (unsigned short*)(smem + 8192);
    unsigned short* Ps = (unsigned short*)(smem + 16384);
    float*          Ot = (float*)smem;

    const int tid  = threadIdx.x;
    const int l    = tid & 63, w = tid >> 6;
    const int frow = l & 15,  g = l >> 4;

    // XCD-swizzled flat grid (2048 blocks, 2048%8==0): the 8 q0-blocks sharing
    // one (bh,s) K/V panel are consecutive in lid -> same XCD's L2.
    const int bid = blockIdx.x;
    const int lid = (bid & 7) * 256 + (bid >> 3);
    const int q0  = (lid & 7) * 64;
    const int bh  = (lid >> 3) & 31;
    const int s   = lid >> 8;
    const int b   = bh >> 4, h = bh & 15;

    const int Na   = *nactp;
    const int ks0  = s * (TK_ / ASPLIT);
    const int nt   = TK_ / ASPLIT / 64;

    short8 qf0, qf1;
    {
        const unsigned short* qp = Qb + (size_t)(b * TQ_ + q0 + w * 16 + frow) * D_ + h * HD_;
        qf0 = *(const short8*)(qp + g * 8);
        qf1 = *(const short8*)(qp + 32 + g * 8);
    }

    f32x4 lA4 = (f32x4){0.f, 0.f, 0.f, 0.f};
    f32x4 lI4 = (f32x4){0.f, 0.f, 0.f, 0.f};
    f32x4 oA[4], oI[4];
#pragma unroll
    for (int mt = 0; mt < 4; ++mt) {
        oA[mt] = (f32x4){0.f, 0.f, 0.f, 0.f};
        oI[mt] = (f32x4){0.f, 0.f, 0.f, 0.f};
    }

    const int srow = tid >> 2;
    const int scb  = (tid & 3) * 32;
    const unsigned short* kg = Kb + (size_t)(b * TK_ + ks0 + srow) * D_ + h * HD_ + (tid & 3) * 16;
    const unsigned short* vg = Vt + ((size_t)bh * HD_ + srow) * TK_ + ks0 + (tid & 3) * 16;
    const int kswz0 = srow * 128 + ((scb +  0) ^ ((srow & 7) << 4));
    const int kswz1 = srow * 128 + ((scb + 16) ^ ((srow & 7) << 4));

    for (int t = 0; t < nt; ++t) {
        const int jb = ks0 + t * 64;
        short8 kr0 = *(const short8*)(kg);
        short8 kr1 = *(const short8*)(kg + 8);
        short8 vr0 = *(const short8*)(vg);
        short8 vr1 = *(const short8*)(vg + 8);
        kg += (size_t)64 * D_;
        vg += 64;
        __syncthreads();
        *(short8*)((char*)Ks + kswz0) = kr0;
        *(short8*)((char*)Ks + kswz1) = kr1;
        *(short8*)((char*)Vs + kswz0) = vr0;
        *(short8*)((char*)Vs + kswz1) = vr1;
        __syncthreads();

        f32x4 st[4];
#pragma unroll
        for (int mt = 0; mt < 4; ++mt) {
            int row = mt * 16 + frow;
            int rs  = (row & 7) << 4;
            short8 a0 = *(const short8*)((const char*)Ks + row * 128 + ((g * 16) ^ rs));
            short8 a1 = *(const short8*)((const char*)Ks + row * 128 + ((64 + g * 16) ^ rs));
            f32x4 acc = (f32x4){0.f, 0.f, 0.f, 0.f};
            acc = __builtin_amdgcn_mfma_f32_16x16x32_bf16(a0, qf0, acc, 0, 0, 0);
            acc = __builtin_amdgcn_mfma_f32_16x16x32_bf16(a1, qf1, acc, 0, 0, 0);
            st[mt] = acc;
        }

        const bool hasA = (jb < Na);
        const bool hasI = (jb + 64 > Na);
        if (hasA) {
            if (jb + 64 <= Na) attn_pass<true >(st, jb, 0, Na, lA4, oA, Ps, Vs, frow, g, w);
            else               attn_pass<false>(st, jb, 0, Na, lA4, oA, Ps, Vs, frow, g, w);
        }
        if (hasI) {
            if (jb >= Na)      attn_pass<true >(st, jb, Na, TK_, lI4, oI, Ps, Vs, frow, g, w);
            else               attn_pass<false>(st, jb, Na, TK_, lI4, oI, Ps, Vs, frow, g, w);
        }
    }

    const int q = w * 16 + frow;
#pragma unroll
    for (int grp = 0; grp < 2; ++grp) {
        __syncthreads();
        const f32x4* o = grp ? oI : oA;
#pragma unroll
        for (int mt = 0; mt < 4; ++mt)
            *(f32x4*)&Ot[q * 68 + mt * 16 + g * 4] = o[mt];
        if (g == 0) {
            size_t base = ((size_t)((s * 2 + grp) * (B_ * NH_) + bh)) * TQ_ + q0 + q;
            pL[base] = grp ? lI4[0] : lA4[0];
        }
        __syncthreads();
        {
            int qr = tid >> 2, dc = (tid & 3) * 16;
            size_t rowbase = ((size_t)((s * 2 + grp) * (B_ * NH_) + bh)) * TQ_ + q0 + qr;
            float* dst = pO + rowbase * HD_ + dc;
#pragma unroll
            for (int u = 0; u < 4; ++u)
                *(float4*)(dst + 4 * u) = *(const float4*)&Ot[qr * 68 + dc + 4 * u];
        }
    }
}

// ---------------- split-K merge: plain sums (shared m=0), bf16 out ----------------
__global__ __launch_bounds__(256)
void sdpca_combine(const float* __restrict__ pO, const float* __restrict__ pL,
                   const int* __restrict__ nactp, unsigned short* __restrict__ Aob)
{
    int idx = blockIdx.x * 256 + threadIdx.x;
    int d   = idx & (HD_ - 1);
    int q   = (idx >> 6) & (TQ_ - 1);
    int bh  = idx >> 15;
    int b   = bh >> 4, h = bh & 15;
    int Na  = *nactp;
    int Ni  = TK_ - Na;

    float res = 0.f;
#pragma unroll
    for (int gg = 0; gg < 2; ++gg) {
        float L = 0.f, O = 0.f;
#pragma unroll
        for (int ss = 0; ss < ASPLIT; ++ss) {
            size_t ii = ((size_t)((ss * 2 + gg) * (B_ * NH_) + bh)) * TQ_ + q;
            L += pL[ii];
            O += pO[ii * HD_ + d];
        }
        float r   = (L > 0.f) ? (O / L) : 0.f;
        int   cnt = (gg == 0) ? Na : Ni;
        float sc  = (cnt > 0) ? rsqrtf((float)cnt) : 0.f;
        res += (gg == 0) ? (sc * r) : (-sc * r);
    }
    Aob[((size_t)(b * TQ_ + q)) * D_ + h * HD_ + d] = f2bf(res);
}

// ---------------- output projection, bf16 MFMA, fp32 out ----------------
__global__ __launch_bounds__(256)
void sdpca_gemm_o(const unsigned short* __restrict__ A, const unsigned short* __restrict__ W,
                  const float* __restrict__ bias, float* __restrict__ C)
{
    __shared__ unsigned short AT[128 * 32];
    __shared__ unsigned short BT[128 * 32];
    const int tid  = threadIdx.x;
    const int lane = tid & 63;
    const int w    = tid >> 6;
    const int brow = blockIdx.y * 128;
    const int bcol = blockIdx.x * 128;
    const int wr = w >> 1, wc = w & 1;

    const int   srow = lane >> 2;
    const int   scol = (lane & 3) * 8;
    const size_t gA0 = (size_t)(brow + w * 32 + srow) * D_ + scol;
    const size_t gA1 = gA0 + (size_t)16 * D_;
    const size_t gB0 = (size_t)(bcol + w * 32 + srow) * D_ + scol;
    const size_t gB1 = gB0 + (size_t)16 * D_;
    const int   l0   = (w * 32 +  0) * 32;
    const int   l1   = (w * 32 + 16) * 32;

    f32x4 acc[4][4];
#pragma unroll
    for (int m = 0; m < 4; ++m)
#pragma unroll
        for (int n = 0; n < 4; ++n) acc[m][n] = (f32x4){0.f, 0.f, 0.f, 0.f};

    const int frow = lane & 15;
    const int fko  = (lane >> 4) * 8;

    for (int k0 = 0; k0 < D_; k0 += 32) {
        GLD16(A + gA0 + k0, &AT[l0]);
        GLD16(A + gA1 + k0, &AT[l1]);
        GLD16(W + gB0 + k0, &BT[l0]);
        GLD16(W + gB1 + k0, &BT[l1]);
        __syncthreads();
        short8 bf[4];
#pragma unroll
        for (int n = 0; n < 4; ++n)
            bf[n] = *(const short8*)&BT[(wc * 64 + n * 16 + frow) * 32 + fko];
#pragma unroll
        for (int m = 0; m < 4; ++m) {
            short8 a = *(const short8*)&AT[(wr * 64 + m * 16 + frow) * 32 + fko];
#pragma unroll
            for (int n = 0; n < 4; ++n)
                acc[m][n] = __builtin_amdgcn_mfma_f32_16x16x32_bf16(a, bf[n], acc[m][n], 0, 0, 0);
        }
        __syncthreads();
    }

#pragma unroll
    for (int n = 0; n < 4; ++n) {
        int col = bcol + wc * 64 + n * 16 + frow;
        float bsv = bias[col];
#pragma unroll
        for (int m = 0; m < 4; ++m) {
            int rbase = brow + wr * 64 + m * 16 + (lane >> 4) * 4;
#pragma unroll
            for (int r = 0; r < 4; ++r)
                C[(size_t)(rbase + r) * D_ + col] = acc[m][n][r] + bsv;
        }
    }
}

extern "C" void kernel_launch(void* const* d_in, const int* in_sizes, int n_in,
                              void* d_out, int out_size, void* d_ws, size_t ws_size,
                              hipStream_t stream) {
    (void)in_sizes; (void)n_in; (void)out_size; (void)ws_size;
    const float* q   = (const float*)d_in[0];
    const float* kv  = (const float*)d_in[1];
    const float* Wq  = (const float*)d_in[2];
    const float* bq  = (const float*)d_in[3];
    const float* Wk  = (const float*)d_in[4];
    const float* bk  = (const float*)d_in[5];
    const float* Wv  = (const float*)d_in[6];
    const float* bv  = (const float*)d_in[7];
    const float* Wo  = (const float*)d_in[8];
    const float* bo  = (const float*)d_in[9];
    const float* ab  = (const float*)d_in[10];
    const float* ib  = (const float*)d_in[11];
    const float* lt  = (const float*)d_in[12];
    const int*   na  = (const int*)d_in[13];

    char* ws = (char*)d_ws;
    const size_t nQ  = (size_t)B_ * TQ_ * D_;    // 1,048,576
    const size_t nKV = (size_t)B_ * TK_ * D_;    // 16,777,216
    const size_t nW  = (size_t)D_ * D_;          // 1,048,576
    const size_t nML = (size_t)ASPLIT * 2 * B_ * NH_ * TQ_;  // 262,144

    unsigned short* Ah  = (unsigned short*)ws;                 // 33.5 MB
    unsigned short* Whk = Ah + nKV;                            // 2 MB
    unsigned short* Whv = Whk + nW;                            // 2 MB
    unsigned short* Kb  = Whv + nW;                            // 33.5 MB
    unsigned short* Vt  = Kb + nKV;                            // 33.5 MB
    unsigned short* Qb  = Vt + nKV;                            // 2 MB
    unsigned short* qbb = Qb + nQ;                             // 2 MB
    unsigned short* Wqb = qbb + nQ;                            // 2 MB
    unsigned short* Wob = Wqb + nW;                            // 2 MB
    unsigned short* Aob = Wob + nW;                            // 2 MB
    float* pL = (float*)(Aob + nQ);                            // 1 MB
    float* pO = pL + nML;                                      // 67 MB
    // total ~180 MB (round 3 proved >= 213 MB available)

    dim3 blk(256);
    split_w           <<<dim3((int)(nQ / 8 / 256)),  blk, 0, stream>>>(q,  qbb);
    split_w           <<<dim3((int)(nW / 8 / 256)),  blk, 0, stream>>>(Wq, Wqb);
    split_w           <<<dim3((int)(nW / 8 / 256)),  blk, 0, stream>>>(Wo, Wob);
    split_kv          <<<dim3((int)(nKV / 8 / 256)), blk, 0, stream>>>(kv, ab, ib, na, Ah);
    split_w           <<<dim3((int)(nW / 8 / 256)),  blk, 0, stream>>>(Wk, Whk);
    split_w           <<<dim3((int)(nW / 8 / 256)),  blk, 0, stream>>>(Wv, Whv);
    sdpca_gemm_q      <<<dim3(8, 8),                 blk, 0, stream>>>(qbb, Wqb, bq, lt, Qb);
    sdpca_gemm_kv_mfma<<<dim3(1024, 2),              blk, 0, stream>>>(Ah, Whk, Whv, bk, bv, Kb, Vt);
    sdpca_attn_mfma   <<<dim3(2048),                 blk, 0, stream>>>(Qb, Kb, Vt, na, pO, pL);
    sdpca_combine     <<<dim3((B_ * TQ_ * D_) / 256), blk, 0, stream>>>(pO, pL, na, Aob);
    sdpca_gemm_o      <<<dim3(8, 8),                 blk, 0, stream>>>(Aob, Wob, bo, (float*)d_out);
}

// Round 10
// 255.565 us; speedup vs baseline: 12.0544x; 1.0225x over previous
//
#include <hip/hip_runtime.h>
#include <math.h>
#include <stdint.h>

#define B_   2
#define TQ_  512
#define TK_  8192
#define D_   1024
#define NH_  16
#define HD_  64

#define NEG_BIG (-3.0e38f)
#define ASPLIT 8
#define LOG2E 1.4426950408889634f
#define EXP2F(x) __builtin_exp2f(x)

typedef __attribute__((ext_vector_type(8))) short short8;
typedef __attribute__((ext_vector_type(4))) float f32x4;

// ---------------- bf16 helpers (RNE) ----------------
__device__ __forceinline__ unsigned short f2bf(float x) {
    unsigned u = __float_as_uint(x);
    unsigned r = u + 0x7FFFu + ((u >> 16) & 1u);
    return (unsigned short)(r >> 16);
}

#define GLD16(gp, lp)                                                              \
    __builtin_amdgcn_global_load_lds(                                              \
        (const __attribute__((address_space(1))) unsigned int*)(gp),               \
        (__attribute__((address_space(3))) unsigned int*)(lp), 16, 0, 0)

// LDS chunk swizzle for [128][32]-bf16 GEMM tiles (64B rows):
//   LDS[r][c] holds global[r][c ^ ((r>>1)&3)]  (c = 16B chunk, 0..3)
// write side: pre-swizzled global source col; read side: same XOR. Quarter-wave
// bank spread goes 2 banks (8-way conflict) -> 8 bank-bases (2-way, free).

// ---------------- fp32 -> bf16 conversion (generic, n = grid*256*8) ----------------
__global__ __launch_bounds__(256)
void split_w(const float* __restrict__ W, unsigned short* __restrict__ Wh)
{
    size_t i = ((size_t)blockIdx.x * 256 + threadIdx.x) * 8;
    float4 x0 = *(const float4*)(W + i);
    float4 x1 = *(const float4*)(W + i + 4);
    float a[8] = {x0.x, x0.y, x0.z, x0.w, x1.x, x1.y, x1.z, x1.w};
    union { short8 v; unsigned short u[8]; } H;
#pragma unroll
    for (int j = 0; j < 8; ++j) H.u[j] = f2bf(a[j]);
    *(short8*)(Wh + i) = H.v;
}

// ---------------- bf16 conversion of (kv + group bias) ----------------
__global__ __launch_bounds__(256)
void split_kv(const float* __restrict__ kv, const float* __restrict__ ab,
              const float* __restrict__ ib, const int* __restrict__ nactp,
              unsigned short* __restrict__ Ah)
{
    const int Na = *nactp;
    size_t i = ((size_t)blockIdx.x * 256 + threadIdx.x) * 8;
    int row = (int)(i >> 10);
    int col = (int)(i & (D_ - 1));
    const float* bp = ((row & (TK_ - 1)) < Na) ? ab : ib;
    float4 x0 = *(const float4*)(kv + i);
    float4 x1 = *(const float4*)(kv + i + 4);
    float4 b0 = *(const float4*)(bp + col);
    float4 b1 = *(const float4*)(bp + col + 4);
    float a[8] = {x0.x + b0.x, x0.y + b0.y, x0.z + b0.z, x0.w + b0.w,
                  x1.x + b1.x, x1.y + b1.y, x1.z + b1.z, x1.w + b1.w};
    union { short8 v; unsigned short u[8]; } H;
#pragma unroll
    for (int j = 0; j < 8; ++j) H.u[j] = f2bf(a[j]);
    *(short8*)(Ah + i) = H.v;
}

// ---------------- Q projection, bf16 MFMA; scale folds 1/(64*temp) AND log2e ----------------
__global__ __launch_bounds__(256)
void sdpca_gemm_q(const unsigned short* __restrict__ A, const unsigned short* __restrict__ W,
                  const float* __restrict__ bias, const float* __restrict__ log_temp,
                  unsigned short* __restrict__ Qb)
{
    __shared__ unsigned short AT[128 * 32];
    __shared__ unsigned short BT[128 * 32];
    const int tid  = threadIdx.x;
    const int lane = tid & 63;
    const int w    = tid >> 6;
    const int brow = blockIdx.y * 128;
    const int bcol = blockIdx.x * 128;
    const int wr = w >> 1, wc = w & 1;

    const int   srow = lane >> 2;
    const int   scol = (((lane & 3) ^ ((lane >> 3) & 3)) * 8);   // swizzled source chunk
    const size_t gA0 = (size_t)(brow + w * 32 + srow) * D_ + scol;
    const size_t gA1 = gA0 + (size_t)16 * D_;
    const size_t gB0 = (size_t)(bcol + w * 32 + srow) * D_ + scol;
    const size_t gB1 = gB0 + (size_t)16 * D_;
    const int   l0   = (w * 32 +  0) * 32;
    const int   l1   = (w * 32 + 16) * 32;

    f32x4 acc[4][4];
#pragma unroll
    for (int m = 0; m < 4; ++m)
#pragma unroll
        for (int n = 0; n < 4; ++n) acc[m][n] = (f32x4){0.f, 0.f, 0.f, 0.f};

    const int frow = lane & 15;
    const int fko  = (((lane >> 4) ^ ((frow >> 1) & 3)) * 8);    // swizzled read chunk

    for (int k0 = 0; k0 < D_; k0 += 32) {
        GLD16(A + gA0 + k0, &AT[l0]);
        GLD16(A + gA1 + k0, &AT[l1]);
        GLD16(W + gB0 + k0, &BT[l0]);
        GLD16(W + gB1 + k0, &BT[l1]);
        __syncthreads();
        short8 bf[4];
#pragma unroll
        for (int n = 0; n < 4; ++n)
            bf[n] = *(const short8*)&BT[(wc * 64 + n * 16 + frow) * 32 + fko];
#pragma unroll
        for (int m = 0; m < 4; ++m) {
            short8 a = *(const short8*)&AT[(wr * 64 + m * 16 + frow) * 32 + fko];
#pragma unroll
            for (int n = 0; n < 4; ++n)
                acc[m][n] = __builtin_amdgcn_mfma_f32_16x16x32_bf16(a, bf[n], acc[m][n], 0, 0, 0);
        }
        __syncthreads();
    }

    float lt    = *log_temp;
    float temp  = fminf(fmaxf(expf(lt), 0.1f), 10.0f);
    float scale = LOG2E / (64.0f * temp);   // scores land in log2 domain

#pragma unroll
    for (int n = 0; n < 4; ++n) {
        int col = bcol + wc * 64 + n * 16 + frow;
        float bsv = bias[col];
#pragma unroll
        for (int m = 0; m < 4; ++m) {
            int rbase = brow + wr * 64 + m * 16 + (lane >> 4) * 4;
#pragma unroll
            for (int r = 0; r < 4; ++r)
                Qb[(size_t)(rbase + r) * D_ + col] = f2bf((acc[m][n][r] + bsv) * scale);
        }
    }
}

// ---------------- K/V projection via bf16 MFMA, z picks K or V; V written transposed ----------------
__global__ __launch_bounds__(256)
void sdpca_gemm_kv_mfma(const unsigned short* __restrict__ Ah,
                        const unsigned short* __restrict__ Whk,
                        const unsigned short* __restrict__ Whv,
                        const float* __restrict__ bk, const float* __restrict__ bv,
                        unsigned short* __restrict__ Kb, unsigned short* __restrict__ Vt)
{
    __shared__ unsigned short AT[128 * 32];
    __shared__ unsigned short BT[128 * 32];

    const int tid  = threadIdx.x;
    const int lane = tid & 63;
    const int w    = tid >> 6;
    const int bid  = blockIdx.x;
    const int lid  = (bid & 7) * 128 + (bid >> 3);
    const int brow = (lid >> 3) * 128;
    const int bcol = (lid & 7) * 128;
    const int z    = blockIdx.y;

    const unsigned short* Wh = z ? Whv : Whk;
    const float* bias        = z ? bv  : bk;

    const int wr = w >> 1, wc = w & 1;

    const int   srow = lane >> 2;
    const int   scol = (((lane & 3) ^ ((lane >> 3) & 3)) * 8);   // swizzled source chunk
    const size_t gA0 = (size_t)(brow + w * 32 + srow) * D_ + scol;
    const size_t gA1 = gA0 + (size_t)16 * D_;
    const size_t gB0 = (size_t)(bcol + w * 32 + srow) * D_ + scol;
    const size_t gB1 = gB0 + (size_t)16 * D_;
    const int   l0   = (w * 32 +  0) * 32;
    const int   l1   = (w * 32 + 16) * 32;

    f32x4 acc[4][4];
#pragma unroll
    for (int m = 0; m < 4; ++m)
#pragma unroll
        for (int n = 0; n < 4; ++n) acc[m][n] = (f32x4){0.f, 0.f, 0.f, 0.f};

    const int frow = lane & 15;
    const int fko  = (((lane >> 4) ^ ((frow >> 1) & 3)) * 8);    // swizzled read chunk

    for (int k0 = 0; k0 < D_; k0 += 32) {
        GLD16(Ah + gA0 + k0, &AT[l0]);
        GLD16(Ah + gA1 + k0, &AT[l1]);
        GLD16(Wh + gB0 + k0, &BT[l0]);
        GLD16(Wh + gB1 + k0, &BT[l1]);
        __syncthreads();
        short8 bf[4];
#pragma unroll
        for (int n = 0; n < 4; ++n)
            bf[n] = *(const short8*)&BT[(wc * 64 + n * 16 + frow) * 32 + fko];
#pragma unroll
        for (int m = 0; m < 4; ++m) {
            short8 a = *(const short8*)&AT[(wr * 64 + m * 16 + frow) * 32 + fko];
#pragma unroll
            for (int n = 0; n < 4; ++n)
                acc[m][n] = __builtin_amdgcn_mfma_f32_16x16x32_bf16(a, bf[n], acc[m][n], 0, 0, 0);
        }
        __syncthreads();
    }

    if (z == 0) {
#pragma unroll
        for (int n = 0; n < 4; ++n) {
            int col = bcol + wc * 64 + n * 16 + frow;
            float bsv = bias[col];
#pragma unroll
            for (int m = 0; m < 4; ++m) {
                int rbase = brow + wr * 64 + m * 16 + (lane >> 4) * 4;
#pragma unroll
                for (int r = 0; r < 4; ++r)
                    Kb[(size_t)(rbase + r) * D_ + col] = f2bf(acc[m][n][r] + bsv);
            }
        }
    } else {
#pragma unroll
        for (int n = 0; n < 4; ++n) {
            int col = bcol + wc * 64 + n * 16 + frow;
            int h   = col >> 6, d = col & 63;
            float bsv = bias[col];
#pragma unroll
            for (int m = 0; m < 4; ++m) {
                int rbase = brow + wr * 64 + m * 16 + (lane >> 4) * 4;
                int b     = rbase >> 13;
                int tok   = rbase & (TK_ - 1);
                ushort4 o;
                o.x = f2bf(acc[m][n][0] + bsv);
                o.y = f2bf(acc[m][n][1] + bsv);
                o.z = f2bf(acc[m][n][2] + bsv);
                o.w = f2bf(acc[m][n][3] + bsv);
                *(ushort4*)&Vt[((size_t)(b * 16 + h) * 64 + d) * TK_ + tok] = o;
            }
        }
    }
}

// ---------------- MFMA flash attention, fixed-max (m=0) softmax ----------------
template<bool FULL>
__device__ __forceinline__ void attn_pass(
    const f32x4 st[4], int jb, int lo, int hi,
    f32x4& lacc, f32x4 o[4],
    unsigned short* Ps, const unsigned short* Vs,
    int frow, int g, int w)
{
    const int q = w * 16 + frow;
    const short8 kOnes = {(short)0x3F80, (short)0x3F80, (short)0x3F80, (short)0x3F80,
                          (short)0x3F80, (short)0x3F80, (short)0x3F80, (short)0x3F80};
    float p[4][4];
#pragma unroll
    for (int mt = 0; mt < 4; ++mt)
#pragma unroll
        for (int r = 0; r < 4; ++r) {
            float pv = EXP2F(st[mt][r]);
            if (!FULL) {
                int key = jb + mt * 16 + g * 4 + r;
                if (key < lo || key >= hi) pv = 0.f;
            }
            p[mt][r] = pv;
        }

#pragma unroll
    for (int mt = 0; mt < 4; ++mt) {
        unsigned u0, u1;
        asm("v_cvt_pk_bf16_f32 %0, %1, %2" : "=v"(u0) : "v"(p[mt][0]), "v"(p[mt][1]));
        asm("v_cvt_pk_bf16_f32 %0, %1, %2" : "=v"(u1) : "v"(p[mt][2]), "v"(p[mt][3]));
        unsigned* dst = (unsigned*)((char*)Ps + q * 144 + (mt * 16 + g * 4) * 2);
        dst[0] = u0; dst[1] = u1;
    }
    __builtin_amdgcn_sched_barrier(0);   // keep PV reads after P writes

    short8 pb[2];
#pragma unroll
    for (int ks = 0; ks < 2; ++ks)
        pb[ks] = *(const short8*)((const char*)Ps + q * 144 + ks * 64 + g * 16);
#pragma unroll
    for (int mt = 0; mt < 4; ++mt) {
        int row = mt * 16 + frow;
        int rs  = (row & 7) << 4;
#pragma unroll
        for (int ks = 0; ks < 2; ++ks) {
            short8 a = *(const short8*)((const char*)Vs + row * 128 + ((ks * 64 + g * 16) ^ rs));
            o[mt] = __builtin_amdgcn_mfma_f32_16x16x32_bf16(a, pb[ks], o[mt], 0, 0, 0);
        }
    }
#pragma unroll
    for (int ks = 0; ks < 2; ++ks)
        lacc = __builtin_amdgcn_mfma_f32_16x16x32_bf16(kOnes, pb[ks], lacc, 0, 0, 0);
}

__global__ __launch_bounds__(256)
void sdpca_attn_mfma(const unsigned short* __restrict__ Qb,
                     const unsigned short* __restrict__ Kb,
                     const unsigned short* __restrict__ Vt,
                     const int* __restrict__ nactp,
                     float* __restrict__ pO, float* __restrict__ pL)
{
    __shared__ char smem[25600];
    unsigned short* Ks = (unsigned short*)smem;
    unsigned short* Vs = (unsigned short*)(smem + 8192);
    unsigned short* Ps = (unsigned short*)(smem + 16384);
    float*          Ot = (float*)smem;

    const int tid  = threadIdx.x;
    const int l    = tid & 63, w = tid >> 6;
    const int frow = l & 15,  g = l >> 4;

    const int bid = blockIdx.x;
    const int lid = (bid & 7) * 256 + (bid >> 3);
    const int q0  = (lid & 7) * 64;
    const int bh  = (lid >> 3) & 31;
    const int s   = lid >> 8;
    const int b   = bh >> 4, h = bh & 15;

    const int Na   = *nactp;
    const int ks0  = s * (TK_ / ASPLIT);
    const int nt   = TK_ / ASPLIT / 64;

    short8 qf0, qf1;
    {
        const unsigned short* qp = Qb + (size_t)(b * TQ_ + q0 + w * 16 + frow) * D_ + h * HD_;
        qf0 = *(const short8*)(qp + g * 8);
        qf1 = *(const short8*)(qp + 32 + g * 8);
    }

    f32x4 lA4 = (f32x4){0.f, 0.f, 0.f, 0.f};
    f32x4 lI4 = (f32x4){0.f, 0.f, 0.f, 0.f};
    f32x4 oA[4], oI[4];
#pragma unroll
    for (int mt = 0; mt < 4; ++mt) {
        oA[mt] = (f32x4){0.f, 0.f, 0.f, 0.f};
        oI[mt] = (f32x4){0.f, 0.f, 0.f, 0.f};
    }

    const int srow = tid >> 2;
    const int scb  = (tid & 3) * 32;
    const unsigned short* kg = Kb + (size_t)(b * TK_ + ks0 + srow) * D_ + h * HD_ + (tid & 3) * 16;
    const unsigned short* vg = Vt + ((size_t)bh * HD_ + srow) * TK_ + ks0 + (tid & 3) * 16;
    const int kswz0 = srow * 128 + ((scb +  0) ^ ((srow & 7) << 4));
    const int kswz1 = srow * 128 + ((scb + 16) ^ ((srow & 7) << 4));

    for (int t = 0; t < nt; ++t) {
        const int jb = ks0 + t * 64;
        short8 kr0 = *(const short8*)(kg);
        short8 kr1 = *(const short8*)(kg + 8);
        short8 vr0 = *(const short8*)(vg);
        short8 vr1 = *(const short8*)(vg + 8);
        kg += (size_t)64 * D_;
        vg += 64;
        __syncthreads();
        *(short8*)((char*)Ks + kswz0) = kr0;
        *(short8*)((char*)Ks + kswz1) = kr1;
        *(short8*)((char*)Vs + kswz0) = vr0;
        *(short8*)((char*)Vs + kswz1) = vr1;
        __syncthreads();

        f32x4 st[4];
#pragma unroll
        for (int mt = 0; mt < 4; ++mt) {
            int row = mt * 16 + frow;
            int rs  = (row & 7) << 4;
            short8 a0 = *(const short8*)((const char*)Ks + row * 128 + ((g * 16) ^ rs));
            short8 a1 = *(const short8*)((const char*)Ks + row * 128 + ((64 + g * 16) ^ rs));
            f32x4 acc = (f32x4){0.f, 0.f, 0.f, 0.f};
            acc = __builtin_amdgcn_mfma_f32_16x16x32_bf16(a0, qf0, acc, 0, 0, 0);
            acc = __builtin_amdgcn_mfma_f32_16x16x32_bf16(a1, qf1, acc, 0, 0, 0);
            st[mt] = acc;
        }

        const bool hasA = (jb < Na);
        const bool hasI = (jb + 64 > Na);
        if (hasA) {
            if (jb + 64 <= Na) attn_pass<true >(st, jb, 0, Na, lA4, oA, Ps, Vs, frow, g, w);
            else               attn_pass<false>(st, jb, 0, Na, lA4, oA, Ps, Vs, frow, g, w);
        }
        if (hasI) {
            if (jb >= Na)      attn_pass<true >(st, jb, Na, TK_, lI4, oI, Ps, Vs, frow, g, w);
            else               attn_pass<false>(st, jb, Na, TK_, lI4, oI, Ps, Vs, frow, g, w);
        }
    }

    const int q = w * 16 + frow;
#pragma unroll
    for (int grp = 0; grp < 2; ++grp) {
        __syncthreads();
        const f32x4* o = grp ? oI : oA;
#pragma unroll
        for (int mt = 0; mt < 4; ++mt)
            *(f32x4*)&Ot[q * 68 + mt * 16 + g * 4] = o[mt];
        if (g == 0) {
            size_t base = ((size_t)((s * 2 + grp) * (B_ * NH_) + bh)) * TQ_ + q0 + q;
            pL[base] = grp ? lI4[0] : lA4[0];
        }
        __syncthreads();
        {
            int qr = tid >> 2, dc = (tid & 3) * 16;
            size_t rowbase = ((size_t)((s * 2 + grp) * (B_ * NH_) + bh)) * TQ_ + q0 + qr;
            float* dst = pO + rowbase * HD_ + dc;
#pragma unroll
            for (int u = 0; u < 4; ++u)
                *(float4*)(dst + 4 * u) = *(const float4*)&Ot[qr * 68 + dc + 4 * u];
        }
    }
}

// ---------------- split-K merge: plain sums (shared m=0), bf16 out ----------------
__global__ __launch_bounds__(256)
void sdpca_combine(const float* __restrict__ pO, const float* __restrict__ pL,
                   const int* __restrict__ nactp, unsigned short* __restrict__ Aob)
{
    int idx = blockIdx.x * 256 + threadIdx.x;
    int d   = idx & (HD_ - 1);
    int q   = (idx >> 6) & (TQ_ - 1);
    int bh  = idx >> 15;
    int b   = bh >> 4, h = bh & 15;
    int Na  = *nactp;
    int Ni  = TK_ - Na;

    float res = 0.f;
#pragma unroll
    for (int gg = 0; gg < 2; ++gg) {
        float L = 0.f, O = 0.f;
#pragma unroll
        for (int ss = 0; ss < ASPLIT; ++ss) {
            size_t ii = ((size_t)((ss * 2 + gg) * (B_ * NH_) + bh)) * TQ_ + q;
            L += pL[ii];
            O += pO[ii * HD_ + d];
        }
        float r   = (L > 0.f) ? (O / L) : 0.f;
        int   cnt = (gg == 0) ? Na : Ni;
        float sc  = (cnt > 0) ? rsqrtf((float)cnt) : 0.f;
        res += (gg == 0) ? (sc * r) : (-sc * r);
    }
    Aob[((size_t)(b * TQ_ + q)) * D_ + h * HD_ + d] = f2bf(res);
}

// ---------------- output projection, bf16 MFMA, fp32 out ----------------
__global__ __launch_bounds__(256)
void sdpca_gemm_o(const unsigned short* __restrict__ A, const unsigned short* __restrict__ W,
                  const float* __restrict__ bias, float* __restrict__ C)
{
    __shared__ unsigned short AT[128 * 32];
    __shared__ unsigned short BT[128 * 32];
    const int tid  = threadIdx.x;
    const int lane = tid & 63;
    const int w    = tid >> 6;
    const int brow = blockIdx.y * 128;
    const int bcol = blockIdx.x * 128;
    const int wr = w >> 1, wc = w & 1;

    const int   srow = lane >> 2;
    const int   scol = (((lane & 3) ^ ((lane >> 3) & 3)) * 8);   // swizzled source chunk
    const size_t gA0 = (size_t)(brow + w * 32 + srow) * D_ + scol;
    const size_t gA1 = gA0 + (size_t)16 * D_;
    const size_t gB0 = (size_t)(bcol + w * 32 + srow) * D_ + scol;
    const size_t gB1 = gB0 + (size_t)16 * D_;
    const int   l0   = (w * 32 +  0) * 32;
    const int   l1   = (w * 32 + 16) * 32;

    f32x4 acc[4][4];
#pragma unroll
    for (int m = 0; m < 4; ++m)
#pragma unroll
        for (int n = 0; n < 4; ++n) acc[m][n] = (f32x4){0.f, 0.f, 0.f, 0.f};

    const int frow = lane & 15;
    const int fko  = (((lane >> 4) ^ ((frow >> 1) & 3)) * 8);    // swizzled read chunk

    for (int k0 = 0; k0 < D_; k0 += 32) {
        GLD16(A + gA0 + k0, &AT[l0]);
        GLD16(A + gA1 + k0, &AT[l1]);
        GLD16(W + gB0 + k0, &BT[l0]);
        GLD16(W + gB1 + k0, &BT[l1]);
        __syncthreads();
        short8 bf[4];
#pragma unroll
        for (int n = 0; n < 4; ++n)
            bf[n] = *(const short8*)&BT[(wc * 64 + n * 16 + frow) * 32 + fko];
#pragma unroll
        for (int m = 0; m < 4; ++m) {
            short8 a = *(const short8*)&AT[(wr * 64 + m * 16 + frow) * 32 + fko];
#pragma unroll
            for (int n = 0; n < 4; ++n)
                acc[m][n] = __builtin_amdgcn_mfma_f32_16x16x32_bf16(a, bf[n], acc[m][n], 0, 0, 0);
        }
        __syncthreads();
    }

#pragma unroll
    for (int n = 0; n < 4; ++n) {
        int col = bcol + wc * 64 + n * 16 + frow;
        float bsv = bias[col];
#pragma unroll
        for (int m = 0; m < 4; ++m) {
            int rbase = brow + wr * 64 + m * 16 + (lane >> 4) * 4;
#pragma unroll
            for (int r = 0; r < 4; ++r)
                C[(size_t)(rbase + r) * D_ + col] = acc[m][n][r] + bsv;
        }
    }
}

extern "C" void kernel_launch(void* const* d_in, const int* in_sizes, int n_in,
                              void* d_out, int out_size, void* d_ws, size_t ws_size,
                              hipStream_t stream) {
    (void)in_sizes; (void)n_in; (void)out_size; (void)ws_size;
    const float* q   = (const float*)d_in[0];
    const float* kv  = (const float*)d_in[1];
    const float* Wq  = (const float*)d_in[2];
    const float* bq  = (const float*)d_in[3];
    const float* Wk  = (const float*)d_in[4];
    const float* bk  = (const float*)d_in[5];
    const float* Wv  = (const float*)d_in[6];
    const float* bv  = (const float*)d_in[7];
    const float* Wo  = (const float*)d_in[8];
    const float* bo  = (const float*)d_in[9];
    const float* ab  = (const float*)d_in[10];
    const float* ib  = (const float*)d_in[11];
    const float* lt  = (const float*)d_in[12];
    const int*   na  = (const int*)d_in[13];

    char* ws = (char*)d_ws;
    const size_t nQ  = (size_t)B_ * TQ_ * D_;    // 1,048,576
    const size_t nKV = (size_t)B_ * TK_ * D_;    // 16,777,216
    const size_t nW  = (size_t)D_ * D_;          // 1,048,576
    const size_t nML = (size_t)ASPLIT * 2 * B_ * NH_ * TQ_;  // 262,144

    unsigned short* Ah  = (unsigned short*)ws;                 // 33.5 MB
    unsigned short* Whk = Ah + nKV;                            // 2 MB
    unsigned short* Whv = Whk + nW;                            // 2 MB
    unsigned short* Kb  = Whv + nW;                            // 33.5 MB
    unsigned short* Vt  = Kb + nKV;                            // 33.5 MB
    unsigned short* Qb  = Vt + nKV;                            // 2 MB
    unsigned short* qbb = Qb + nQ;                             // 2 MB
    unsigned short* Wqb = qbb + nQ;                            // 2 MB
    unsigned short* Wob = Wqb + nW;                            // 2 MB
    unsigned short* Aob = Wob + nW;                            // 2 MB
    float* pL = (float*)(Aob + nQ);                            // 1 MB
    float* pO = pL + nML;                                      // 67 MB
    // total ~180 MB (round 3 proved >= 213 MB available)

    dim3 blk(256);
    split_w           <<<dim3((int)(nQ / 8 / 256)),  blk, 0, stream>>>(q,  qbb);
    split_w           <<<dim3((int)(nW / 8 / 256)),  blk, 0, stream>>>(Wq, Wqb);
    split_w           <<<dim3((int)(nW / 8 / 256)),  blk, 0, stream>>>(Wo, Wob);
    split_kv          <<<dim3((int)(nKV / 8 / 256)), blk, 0, stream>>>(kv, ab, ib, na, Ah);
    split_w           <<<dim3((int)(nW / 8 / 256)),  blk, 0, stream>>>(Wk, Whk);
    split_w           <<<dim3((int)(nW / 8 / 256)),  blk, 0, stream>>>(Wv, Whv);
    sdpca_gemm_q      <<<dim3(8, 8),                 blk, 0, stream>>>(qbb, Wqb, bq, lt, Qb);
    sdpca_gemm_kv_mfma<<<dim3(1024, 2),              blk, 0, stream>>>(Ah, Whk, Whv, bk, bv, Kb, Vt);
    sdpca_attn_mfma   <<<dim3(2048),                 blk, 0, stream>>>(Qb, Kb, Vt, na, pO, pL);
    sdpca_combine     <<<dim3((B_ * TQ_ * D_) / 256), blk, 0, stream>>>(pO, pL, na, Aob);
    sdpca_gemm_o      <<<dim3(8, 8),                 blk, 0, stream>>>(Aob, Wob, bo, (float*)d_out);
}